// Round 6
// baseline (605.763 us; speedup 1.0000x reference)
//
#include <hip/hip_runtime.h>

#define N_USERS    50000
#define N_ENTITIES 150000
#define N_NODES_C  200000
#define BATCH_C    4096
#define N_EDGES_C  3200000

#define NB 391                  // ceil(200000/512) scan blocks

typedef __attribute__((ext_vector_type(2))) _Float16 h2;
typedef __attribute__((ext_vector_type(8))) _Float16 half8;
typedef __attribute__((ext_vector_type(2))) __fp16 fp16x2_s;   // builtin return type
typedef __attribute__((ext_vector_type(4))) float float4v;

// Workspace (~66 MB; proven safe < 76.8 MB):
//   row_ptr : int [200001+pad]      0.80 MB
//   ncnt    : int [200000]          0.80 MB   (per-node degree histogram)
//   nodecur : int [200000]          0.80 MB   (placement cursors)
//   bsum    : int [512]             2 KB      (per-scan-block sums)
//   boff    : int [512]             2 KB      (scan-block exclusive offsets)
//   edges   : uint [3.2M]          12.8 MB    (nb<<14 | val_q14, node-sorted CSR)
//   fb16    : ushort[200000*64]    25.6 MB    (f16 node features)
//   h1      : f16  [200000*64]     25.6 MB    (layer-1 output)
// CSR build — single-level, node-exact, NO supergroups, NO tmp2 round-trip:
//   zero_k  : ncnt = 0
//   hist_k  : atomicAdd(&ncnt[target[e]], 1)          (no-return, pipelined)
//   bsum_k  : per-512-node block sums
//   bscan_k : 391-elem scan -> boff, row_ptr[N]
//   rowptr_k: 512-elem block scan + boff -> row_ptr, nodecur
//   place_k : pos = atomicAdd(&nodecur[t]); edges[pos] = packed
//   (intra-row order is atomic-arbitrary — aggregation is a sum, so OK)

__device__ __forceinline__ h2 u2h(unsigned u) {
    union { unsigned u; h2 h; } x; x.u = u; return x.h;
}
__device__ __forceinline__ unsigned pk2h(float a, float b) {
    union { fp16x2_s h; unsigned u; } x;
    x.h = __builtin_amdgcn_cvt_pkrtz(a, b);
    return x.u;
}

// ---------- f16 node-feature table ----------
__global__ __launch_bounds__(256) void tof16_k(const float* __restrict__ uw,
                                               const float* __restrict__ ew,
                                               unsigned short* __restrict__ fb)
{
    int idx = blockIdx.x * 256 + threadIdx.x;
    if (idx >= N_NODES_C * 64) return;
    const int split = N_USERS * 64;
    float x = (idx < split) ? uw[idx] : ew[idx - split];
    _Float16 hx = (_Float16)x;
    fb[idx] = *(unsigned short*)&hx;
}

// ---------- CSR build ----------
__global__ __launch_bounds__(512) void zero_k(int* __restrict__ ncnt)
{
    int i = blockIdx.x * 512 + threadIdx.x;
    if (i < N_NODES_C) ncnt[i] = 0;
}

__global__ __launch_bounds__(256) void hist_k(const int* __restrict__ target,
                                              int* __restrict__ ncnt, int n_edges)
{
    int i = blockIdx.x * 256 + threadIdx.x;
    int stride = gridDim.x * 256;
    for (; i < n_edges; i += stride)
        atomicAdd(&ncnt[target[i]], 1);
}

__global__ __launch_bounds__(512) void bsum_k(const int* __restrict__ ncnt,
                                              int* __restrict__ bsum)
{
    __shared__ int ws[8];
    int node = blockIdx.x * 512 + threadIdx.x;
    int v = (node < N_NODES_C) ? ncnt[node] : 0;
    #pragma unroll
    for (int m = 1; m < 64; m <<= 1) v += __shfl_xor(v, m);
    if ((threadIdx.x & 63) == 0) ws[threadIdx.x >> 6] = v;
    __syncthreads();
    if (threadIdx.x == 0) {
        int s = 0;
        #pragma unroll
        for (int i = 0; i < 8; i++) s += ws[i];
        bsum[blockIdx.x] = s;
    }
}

__global__ __launch_bounds__(512) void bscan_k(const int* __restrict__ bsum,
                                               int* __restrict__ boff,
                                               int* __restrict__ row_ptr)
{
    __shared__ int part[512];
    int t = threadIdx.x;
    int v = (t < NB) ? bsum[t] : 0;
    part[t] = v;
    __syncthreads();
    for (int off = 1; off < 512; off <<= 1) {
        int w = (t >= off) ? part[t - off] : 0;
        __syncthreads();
        part[t] += w;
        __syncthreads();
    }
    if (t < NB) boff[t] = part[t] - v;               // exclusive
    if (t == NB - 1) { boff[NB] = part[t]; row_ptr[N_NODES_C] = part[t]; }
}

__global__ __launch_bounds__(512) void rowptr_k(const int* __restrict__ ncnt,
                                                const int* __restrict__ boff,
                                                int* __restrict__ row_ptr,
                                                int* __restrict__ nodecur)
{
    __shared__ int c[512];
    __shared__ int rp[512];
    int b = blockIdx.x;
    int node = b * 512 + threadIdx.x;
    int v = (node < N_NODES_C) ? ncnt[node] : 0;
    c[threadIdx.x] = v;
    __syncthreads();
    if (threadIdx.x < 64) {                 // wave-0 exclusive scan of c[512]
        int l = threadIdx.x;
        int s0 = l * 8;
        int vals[8];
        int sum = 0;
        #pragma unroll
        for (int i = 0; i < 8; i++) { vals[i] = c[s0 + i]; sum += vals[i]; }
        int run = sum;
        #pragma unroll
        for (int o = 1; o < 64; o <<= 1) { int w = __shfl_up(run, o); if (l >= o) run += w; }
        int excl = run - sum;
        #pragma unroll
        for (int i = 0; i < 8; i++) { rp[s0 + i] = excl; excl += vals[i]; }
    }
    __syncthreads();
    if (node < N_NODES_C) {
        int s = boff[b] + rp[threadIdx.x];
        row_ptr[node] = s;
        nodecur[node] = s;
    }
}

__global__ __launch_bounds__(256) void place_k(const int* __restrict__ target,
                                               const int* __restrict__ neighbor,
                                               const float* __restrict__ values,
                                               int* __restrict__ nodecur,
                                               unsigned* __restrict__ edges, int n_edges)
{
    int i = blockIdx.x * 256 + threadIdx.x;
    int stride = gridDim.x * 256;
    for (; i < n_edges; i += stride) {
        int t = target[i];
        unsigned q = (unsigned)fminf(values[i] * 16384.f + 0.5f, 16383.f);
        unsigned w = ((unsigned)neighbor[i] << 14) | q;
        int pos = atomicAdd(&nodecur[t], 1);
        edges[pos] = w;
    }
}

// ---------- layer 1: quad-node gather pull (f16 pk_fma) + MFMA f16 transform ----------
// SPS=136 REQUIRED: each row holds 128 f16 k-values (64 sum + 64 product path).
#define SPS 136
__global__ __launch_bounds__(512, 6) void layer1_pull_k(
    const unsigned short* __restrict__ fb,
    const int* __restrict__ row_ptr, const unsigned int* __restrict__ edges,
    const float* __restrict__ W1, const float* __restrict__ b1,
    const float* __restrict__ W2, const float* __restrict__ b2,
    _Float16* __restrict__ h1out, int n_nodes)
{
    __shared__ __align__(16) short wt[64 * SPS];    // 17.4 KB
    __shared__ __align__(16) short sp[128 * SPS];   // 34.8 KB
    __shared__ float sbias[64];

    for (int idx = threadIdx.x; idx < 64 * 64; idx += 512) {
        int kp = idx >> 6;
        int n  = idx & 63;
        int k0 = kp * 2, k1 = k0 + 1;
        float w0 = (k0 < 64) ? W1[k0 * 64 + n] : W2[(k0 - 64) * 64 + n];
        float w1 = (k1 < 64) ? W1[k1 * 64 + n] : W2[(k1 - 64) * 64 + n];
        *(unsigned*)&wt[n * SPS + k0] = pk2h(w0, w1);
    }
    if (threadIdx.x < 64) sbias[threadIdx.x] = b1[threadIdx.x] + b2[threadIdx.x];
    __syncthreads();

    int wv   = threadIdx.x >> 6;
    int lane = threadIdx.x & 63;
    int g    = lane >> 4;
    int q    = lane & 15;
    const uint2* fb2 = (const uint2*)fb;

    int nb0 = blockIdx.x * 128;
    const float QS = 1.f / 16384.f;

    for (int i = 0; i < 16; i += 4) {
        int mA = wv * 16 + i;
        int nodeBase = nb0 + mA;

        int es0 = 0, ee0 = 0, es1 = 0, ee1 = 0, es2 = 0, ee2 = 0, es3 = 0, ee3 = 0;
        if (nodeBase     < n_nodes) { es0 = row_ptr[nodeBase];     ee0 = row_ptr[nodeBase + 1]; }
        if (nodeBase + 1 < n_nodes) { es1 = row_ptr[nodeBase + 1]; ee1 = row_ptr[nodeBase + 2]; }
        if (nodeBase + 2 < n_nodes) { es2 = row_ptr[nodeBase + 2]; ee2 = row_ptr[nodeBase + 3]; }
        if (nodeBase + 3 < n_nodes) { es3 = row_ptr[nodeBase + 3]; ee3 = row_ptr[nodeBase + 4]; }

        h2 aLo0 = (h2){0, 0}, aHi0 = (h2){0, 0};
        h2 aLo1 = (h2){0, 0}, aHi1 = (h2){0, 0};
        h2 aLo2 = (h2){0, 0}, aHi2 = (h2){0, 0};
        h2 aLo3 = (h2){0, 0}, aHi3 = (h2){0, 0};

        int b0 = es0, b1c = es1, b2c = es2, b3c = es3;
        while (b0 < ee0 || b1c < ee1 || b2c < ee2 || b3c < ee3) {
            int c0 = ee0 - b0;  c0 = c0 < 0 ? 0 : (c0 > 64 ? 64 : c0);
            int c1 = ee1 - b1c; c1 = c1 < 0 ? 0 : (c1 > 64 ? 64 : c1);
            int c2 = ee2 - b2c; c2 = c2 < 0 ? 0 : (c2 > 64 ? 64 : c2);
            int c3 = ee3 - b3c; c3 = c3 < 0 ? 0 : (c3 > 64 ? 64 : c3);
            unsigned ev0 = (lane < c0) ? edges[b0 + lane]  : 0u;
            unsigned ev1 = (lane < c1) ? edges[b1c + lane] : 0u;
            unsigned ev2 = (lane < c2) ? edges[b2c + lane] : 0u;
            unsigned ev3 = (lane < c3) ? edges[b3c + lane] : 0u;
            int jm0 = (c0 + 3) >> 2;
            int jm1 = (c1 + 3) >> 2;
            int jm2 = (c2 + 3) >> 2;
            int jm3 = (c3 + 3) >> 2;
            int jm = max(max(jm0, jm1), max(jm2, jm3));
            #pragma unroll 4
            for (int j = 0; j < jm; j++) {
                // lanes beyond a stream's count loaded 0 -> shfl yields w=0 -> v=0
                unsigned w0 = (unsigned)__shfl((int)ev0, j * 4 + g);
                unsigned w1 = (unsigned)__shfl((int)ev1, j * 4 + g);
                unsigned w2 = (unsigned)__shfl((int)ev2, j * 4 + g);
                unsigned w3 = (unsigned)__shfl((int)ev3, j * 4 + g);
                uint2 d0 = fb2[(size_t)(w0 >> 14) * 16 + q];
                uint2 d1 = fb2[(size_t)(w1 >> 14) * 16 + q];
                uint2 d2 = fb2[(size_t)(w2 >> 14) * 16 + q];
                uint2 d3 = fb2[(size_t)(w3 >> 14) * 16 + q];
                _Float16 v0 = (_Float16)((float)(w0 & 16383u) * QS);
                _Float16 v1 = (_Float16)((float)(w1 & 16383u) * QS);
                _Float16 v2 = (_Float16)((float)(w2 & 16383u) * QS);
                _Float16 v3 = (_Float16)((float)(w3 & 16383u) * QS);
                h2 vv0 = (h2){v0, v0};
                h2 vv1 = (h2){v1, v1};
                h2 vv2 = (h2){v2, v2};
                h2 vv3 = (h2){v3, v3};
                aLo0 += u2h(d0.x) * vv0;  aHi0 += u2h(d0.y) * vv0;
                aLo1 += u2h(d1.x) * vv1;  aHi1 += u2h(d1.y) * vv1;
                aLo2 += u2h(d2.x) * vv2;  aHi2 += u2h(d2.y) * vv2;
                aLo3 += u2h(d3.x) * vv3;  aHi3 += u2h(d3.y) * vv3;
            }
            b0 += 64; b1c += 64; b2c += 64; b3c += 64;
        }

        float ac[4][4];
        ac[0][0] = (float)aLo0.x; ac[0][1] = (float)aLo0.y; ac[0][2] = (float)aHi0.x; ac[0][3] = (float)aHi0.y;
        ac[1][0] = (float)aLo1.x; ac[1][1] = (float)aLo1.y; ac[1][2] = (float)aHi1.x; ac[1][3] = (float)aHi1.y;
        ac[2][0] = (float)aLo2.x; ac[2][1] = (float)aLo2.y; ac[2][2] = (float)aHi2.x; ac[2][3] = (float)aHi2.y;
        ac[3][0] = (float)aLo3.x; ac[3][1] = (float)aLo3.y; ac[3][2] = (float)aHi3.x; ac[3][3] = (float)aHi3.y;
        // reduce across the 4 lane-groups (bits 4,5 of lane id) in f32
        #pragma unroll
        for (int s = 0; s < 4; s++)
            #pragma unroll
            for (int c = 0; c < 4; c++) {
                ac[s][c] += __shfl_xor(ac[s][c], 16);
                ac[s][c] += __shfl_xor(ac[s][c], 32);
            }

        // epilogue: g pairs -> (row-pair, sum/product path); all 4 groups busy
        int hseg = g >> 1;
        int prod = g & 1;
        int r0 = mA + (hseg << 1);
        int r1 = r0 + 1;
        int nd0 = nb0 + r0, nd1 = nb0 + r1;
        uint2 d0 = make_uint2(0u, 0u), d1 = make_uint2(0u, 0u);
        if (nd0 < n_nodes) d0 = fb2[(size_t)nd0 * 16 + q];
        if (nd1 < n_nodes) d1 = fb2[(size_t)nd1 * 16 + q];
        float a00 = hseg ? ac[2][0] : ac[0][0];
        float a01 = hseg ? ac[2][1] : ac[0][1];
        float a02 = hseg ? ac[2][2] : ac[0][2];
        float a03 = hseg ? ac[2][3] : ac[0][3];
        float a10 = hseg ? ac[3][0] : ac[1][0];
        float a11 = hseg ? ac[3][1] : ac[1][1];
        float a12 = hseg ? ac[3][2] : ac[1][2];
        float a13 = hseg ? ac[3][3] : ac[1][3];
        h2 s0l = u2h(d0.x), s0h = u2h(d0.y);
        h2 s1l = u2h(d1.x), s1h = u2h(d1.y);
        float f00 = (float)s0l.x, f01 = (float)s0l.y, f02 = (float)s0h.x, f03 = (float)s0h.y;
        float f10 = (float)s1l.x, f11 = (float)s1l.y, f12 = (float)s1h.x, f13 = (float)s1h.y;
        float x00 = prod ? f00 * a00 : f00 + a00;
        float x01 = prod ? f01 * a01 : f01 + a01;
        float x02 = prod ? f02 * a02 : f02 + a02;
        float x03 = prod ? f03 * a03 : f03 + a03;
        float x10 = prod ? f10 * a10 : f10 + a10;
        float x11 = prod ? f11 * a11 : f11 + a11;
        float x12 = prod ? f12 * a12 : f12 + a12;
        float x13 = prod ? f13 * a13 : f13 + a13;
        uint2 pk;
        pk.x = pk2h(x00, x01);
        pk.y = pk2h(x02, x03);
        *(uint2*)&sp[r0 * SPS + prod * 64 + q * 4] = pk;
        pk.x = pk2h(x10, x11);
        pk.y = pk2h(x12, x13);
        *(uint2*)&sp[r1 * SPS + prod * 64 + q * 4] = pk;
    }

    // sp rows are wave-private: drain this wave's LDS writes only (no block barrier)
    __builtin_amdgcn_wave_barrier();
    asm volatile("s_waitcnt lgkmcnt(0)" ::: "memory");
    __builtin_amdgcn_wave_barrier();

    float4v c0, c1, c2, c3;
    {
        float bv0 = sbias[q];
        float bv1 = sbias[16 + q];
        float bv2 = sbias[32 + q];
        float bv3 = sbias[48 + q];
        c0 = (float4v){bv0, bv0, bv0, bv0};
        c1 = (float4v){bv1, bv1, bv1, bv1};
        c2 = (float4v){bv2, bv2, bv2, bv2};
        c3 = (float4v){bv3, bv3, bv3, bv3};
    }
    #pragma unroll
    for (int kk = 0; kk < 4; kk++) {
        int ko = kk * 32 + g * 8;
        half8 a   = *(const half8*)&sp[(wv * 16 + q) * SPS + ko];
        half8 bb0 = *(const half8*)&wt[(q)      * SPS + ko];
        half8 bb1 = *(const half8*)&wt[(16 + q) * SPS + ko];
        half8 bb2 = *(const half8*)&wt[(32 + q) * SPS + ko];
        half8 bb3 = *(const half8*)&wt[(48 + q) * SPS + ko];
        c0 = __builtin_amdgcn_mfma_f32_16x16x32_f16(a, bb0, c0, 0, 0, 0);
        c1 = __builtin_amdgcn_mfma_f32_16x16x32_f16(a, bb1, c1, 0, 0, 0);
        c2 = __builtin_amdgcn_mfma_f32_16x16x32_f16(a, bb2, c2, 0, 0, 0);
        c3 = __builtin_amdgcn_mfma_f32_16x16x32_f16(a, bb3, c3, 0, 0, 0);
    }

    float ss[4];
    #pragma unroll
    for (int r = 0; r < 4; r++) {
        c0[r] = (c0[r] > 0.f) ? c0[r] : 0.01f * c0[r];
        c1[r] = (c1[r] > 0.f) ? c1[r] : 0.01f * c1[r];
        c2[r] = (c2[r] > 0.f) ? c2[r] : 0.01f * c2[r];
        c3[r] = (c3[r] > 0.f) ? c3[r] : 0.01f * c3[r];
        ss[r] = c0[r]*c0[r] + c1[r]*c1[r] + c2[r]*c2[r] + c3[r]*c3[r];
        #pragma unroll
        for (int mm = 1; mm < 16; mm <<= 1) ss[r] += __shfl_xor(ss[r], mm);
        ss[r] = 1.f / fmaxf(sqrtf(ss[r]), 1e-12f);
    }
    #pragma unroll
    for (int r = 0; r < 4; r++) {
        int node_r = nb0 + wv * 16 + g * 4 + r;
        if (node_r >= n_nodes) continue;
        size_t row = (size_t)node_r * 64;
        h1out[row +      q] = (_Float16)(c0[r] * ss[r]);
        h1out[row + 16 + q] = (_Float16)(c1[r] * ss[r]);
        h1out[row + 32 + q] = (_Float16)(c2[r] * ss[r]);
        h1out[row + 48 + q] = (_Float16)(c3[r] * ss[r]);
    }
}

// ---------- inline layer2 (64->32) for one node ----------
__device__ __forceinline__ float layer2_row(
    const _Float16* __restrict__ h1,
    const int* __restrict__ row_ptr, const unsigned int* __restrict__ edges,
    const float* sW1, const float* sW2, const float* sb,
    int node, int lane)
{
    int es = row_ptr[node];
    int ee = row_ptr[node + 1];
    const float QS = 1.f / 16384.f;
    float g = 0.f;
    for (int base = es; base < ee; base += 64) {
        int cnt = min(64, ee - base);
        unsigned ev = (lane < cnt) ? edges[base + lane] : 0u;
        int j = 0;
        for (; j + 4 <= cnt; j += 4) {
            unsigned e0 = (unsigned)__shfl((int)ev, j);
            unsigned e1 = (unsigned)__shfl((int)ev, j + 1);
            unsigned e2 = (unsigned)__shfl((int)ev, j + 2);
            unsigned e3 = (unsigned)__shfl((int)ev, j + 3);
            float f0 = (float)h1[(size_t)(e0 >> 14) * 64 + lane];
            float f1 = (float)h1[(size_t)(e1 >> 14) * 64 + lane];
            float f2 = (float)h1[(size_t)(e2 >> 14) * 64 + lane];
            float f3 = (float)h1[(size_t)(e3 >> 14) * 64 + lane];
            g += (float)(e0 & 16383u) * QS * f0 + (float)(e1 & 16383u) * QS * f1
               + (float)(e2 & 16383u) * QS * f2 + (float)(e3 & 16383u) * QS * f3;
        }
        for (; j < cnt; j++) {
            unsigned e0 = (unsigned)__shfl((int)ev, j);
            float f0 = (float)h1[(size_t)(e0 >> 14) * 64 + lane];
            g += (float)(e0 & 16383u) * QS * f0;
        }
    }
    float f = (float)h1[(size_t)node * 64 + lane];
    float s = f + g;
    float p = f * g;
    int j = lane & 31;
    float acc = sb[j];
    #pragma unroll
    for (int k = 0; k < 64; k++) {
        float sk = __shfl(s, k);
        float pk = __shfl(p, k);
        acc += sk * sW1[k * 32 + j] + pk * sW2[k * 32 + j];
    }
    acc = (acc > 0.f) ? acc : 0.01f * acc;
    float sq = acc * acc;
    #pragma unroll
    for (int m = 1; m < 32; m <<= 1) sq += __shfl_xor(sq, m);
    return acc / fmaxf(sqrtf(sq), 1e-12f);
}

__global__ __launch_bounds__(256) void score_k(
    const float* __restrict__ uw, const float* __restrict__ ew,
    const _Float16* __restrict__ h1,
    const int* __restrict__ row_ptr, const unsigned int* __restrict__ edges,
    const float* __restrict__ W1b, const float* __restrict__ b1b,
    const float* __restrict__ W2b, const float* __restrict__ b2b,
    const int* __restrict__ uid, const int* __restrict__ pid,
    const int* __restrict__ nid, float* __restrict__ out)
{
    __shared__ float sW1[64 * 32];
    __shared__ float sW2[64 * 32];
    __shared__ float sb[32];
    for (int i = threadIdx.x; i < 64 * 32; i += 256) { sW1[i] = W1b[i]; sW2[i] = W2b[i]; }
    if (threadIdx.x < 32) sb[threadIdx.x] = b1b[threadIdx.x] + b2b[threadIdx.x];
    __syncthreads();

    int wave = threadIdx.x >> 6;
    int lane = threadIdx.x & 63;
    int i = blockIdx.x * 4 + wave;
    if (i >= BATCH_C) return;

    int un = uid[i];
    int pe = pid[i];
    int ne = nid[i];
    int pn = N_USERS + pe;
    int nn = N_USERS + ne;

    float acc01p, acc01n;
    {
        float u  = uw[(size_t)un * 64 + lane];
        float pv = ew[(size_t)pe * 64 + lane];
        float nv = ew[(size_t)ne * 64 + lane];
        acc01p = u * pv;
        acc01n = u * nv;
        float u1 = (float)h1[(size_t)un * 64 + lane];
        acc01p += u1 * (float)h1[(size_t)pn * 64 + lane];
        acc01n += u1 * (float)h1[(size_t)nn * 64 + lane];
    }

    float h2u = layer2_row(h1, row_ptr, edges, sW1, sW2, sb, un, lane);
    float h2p = layer2_row(h1, row_ptr, edges, sW1, sW2, sb, pn, lane);
    float h2n = layer2_row(h1, row_ptr, edges, sW1, sW2, sb, nn, lane);
    float p2 = h2u * h2p;
    float n2 = h2u * h2n;
    #pragma unroll
    for (int m = 1; m < 32; m <<= 1) { p2 += __shfl_xor(p2, m); n2 += __shfl_xor(n2, m); }

    #pragma unroll
    for (int m = 1; m < 64; m <<= 1) { acc01p += __shfl_xor(acc01p, m); acc01n += __shfl_xor(acc01n, m); }

    if (lane == 0) {
        out[i]           = acc01p + p2;
        out[BATCH_C + i] = acc01n + n2;
    }
}

extern "C" void kernel_launch(void* const* d_in, const int* in_sizes, int n_in,
                              void* d_out, int out_size, void* d_ws, size_t ws_size,
                              hipStream_t stream) {
    const float* uw   = (const float*)d_in[0];
    const float* ew   = (const float*)d_in[1];
    const float* W1a  = (const float*)d_in[2];
    const float* b1a  = (const float*)d_in[3];
    const float* W2a  = (const float*)d_in[4];
    const float* b2a  = (const float*)d_in[5];
    const float* W1b  = (const float*)d_in[6];
    const float* b1b  = (const float*)d_in[7];
    const float* W2b  = (const float*)d_in[8];
    const float* b2b  = (const float*)d_in[9];
    const float* values   = (const float*)d_in[10];
    const int*   target   = (const int*)d_in[11];
    const int*   neighbor = (const int*)d_in[12];
    const int*   uid  = (const int*)d_in[13];
    const int*   pid  = (const int*)d_in[14];
    const int*   nid  = (const int*)d_in[15];

    const int n_edges = in_sizes[10];

    char* ws = (char*)d_ws;
    int*  row_ptr    = (int*)ws;   ws += 801792;
    int*  ncnt       = (int*)ws;   ws += 800768;          // 200000*4 = 800000
    int*  nodecur    = (int*)ws;   ws += 800768;
    int*  bsum       = (int*)ws;   ws += 2048;
    int*  boff       = (int*)ws;   ws += 2048;
    unsigned int*   edges = (unsigned int*)ws;   ws += (size_t)N_EDGES_C * 4;      // 12.8 MB
    unsigned short* fb    = (unsigned short*)ws; ws += (size_t)N_NODES_C * 64 * 2; // 25.6 MB
    _Float16*       h1    = (_Float16*)ws;                // 25.6 MB

    const int layer_blocks = (N_NODES_C + 127) / 128;     // 1563
    const int conv_blocks  = (N_NODES_C * 64 + 255) / 256;
    const int edge_blocks  = 2048;                        // grid-stride over edges

    // ----- f16 feature table -----
    tof16_k<<<conv_blocks, 256, 0, stream>>>(uw, ew, fb);

    // ----- CSR build: node-level histogram + 2-level scan + direct placement -----
    zero_k<<<NB, 512, 0, stream>>>(ncnt);
    hist_k<<<edge_blocks, 256, 0, stream>>>(target, ncnt, n_edges);
    bsum_k<<<NB, 512, 0, stream>>>(ncnt, bsum);
    bscan_k<<<1, 512, 0, stream>>>(bsum, boff, row_ptr);
    rowptr_k<<<NB, 512, 0, stream>>>(ncnt, boff, row_ptr, nodecur);
    place_k<<<edge_blocks, 256, 0, stream>>>(target, neighbor, values, nodecur, edges, n_edges);

    // ----- layer 1 (quad-node pull + MFMA transform, f16) -----
    layer1_pull_k<<<layer_blocks, 512, 0, stream>>>(fb, row_ptr, edges,
                                                    W1a, b1a, W2a, b2a, h1, N_NODES_C);

    // ----- scoring (layer-2 aggregation + transform inline, ~12K nodes) -----
    score_k<<<BATCH_C / 4, 256, 0, stream>>>(uw, ew, h1, row_ptr, edges,
                                             W1b, b1b, W2b, b2b,
                                             uid, pid, nid, (float*)d_out);
}

// Round 7
// 457.155 us; speedup vs baseline: 1.3251x; 1.3251x over previous
//
#include <hip/hip_runtime.h>

#define N_USERS    50000
#define N_ENTITIES 150000
#define N_NODES_C  200000
#define BATCH_C    4096
#define N_EDGES_C  3200000

// edge sort params
#define CHUNK   7168            // edges per scatter block (LDS 57.3 KB buf)
#define SG_SH   9               // supergroup = 512 nodes
#define NSG     391             // ceil(200000/512)

typedef __attribute__((ext_vector_type(2))) _Float16 h2;
typedef __attribute__((ext_vector_type(8))) _Float16 half8;
typedef __attribute__((ext_vector_type(2))) __fp16 fp16x2_s;   // builtin return type
typedef __attribute__((ext_vector_type(4))) float float4v;

// Workspace (~66 MB; proven safe < 76.8 MB):
//   row_ptr : int [200001+pad]      0.80 MB
//   sgtot   : int [512]             2 KB      (global per-sg edge totals, atomics)
//   sgoff   : int [512]             2 KB      (supergroup global starts)
//   sgcur   : int [512]             2 KB      (allocation cursor per sg)
//   edges   : uint [3.2M]          12.8 MB    (nb<<14 | val_q14, node-sorted CSR)
//   fb16    : ushort[200000*64]    25.6 MB    (f16 node features)
//   region  : 25.69 MB — tmp2 (uint2 sg-sorted edges) then h1 (f16 layer-1 out)
// Sort flow: two-stage staging is REQUIRED for write coalescing — round-6
// lesson: direct scattered 4B placement amplifies 16x (WRITE_SIZE 203MB for
// a 12.8MB write). LDS sg-sort keeps global writes in ~144B runs.

__device__ __forceinline__ h2 u2h(unsigned u) {
    union { unsigned u; h2 h; } x; x.u = u; return x.h;
}
__device__ __forceinline__ unsigned pk2h(float a, float b) {
    union { fp16x2_s h; unsigned u; } x;
    x.h = __builtin_amdgcn_cvt_pkrtz(a, b);
    return x.u;
}

// ---------- f16 node-feature table ----------
__global__ __launch_bounds__(256) void tof16_k(const float* __restrict__ uw,
                                               const float* __restrict__ ew,
                                               unsigned short* __restrict__ fb)
{
    int idx = blockIdx.x * 256 + threadIdx.x;
    if (idx >= N_NODES_C * 64) return;
    const int split = N_USERS * 64;
    float x = (idx < split) ? uw[idx] : ew[idx - split];
    _Float16 hx = (_Float16)x;
    fb[idx] = *(unsigned short*)&hx;
}

// ---------- zero the global sg totals ----------
__global__ __launch_bounds__(512) void zero_k(int* __restrict__ sgtot)
{
    if (threadIdx.x < NSG + 1) sgtot[threadIdx.x] = 0;
}

// ---------- pass A: per-chunk histogram -> global totals ----------
__global__ __launch_bounds__(256) void cnt_k(const int* __restrict__ target,
                                             int* __restrict__ sgtot, int n_edges)
{
    __shared__ int cnt[NSG];
    int c = blockIdx.x;
    int base = c * CHUNK;
    int ccount = min(CHUNK, n_edges - base);
    for (int i = threadIdx.x; i < NSG; i += 256) cnt[i] = 0;
    __syncthreads();
    for (int i = threadIdx.x; i < ccount; i += 256)
        atomicAdd(&cnt[target[base + i] >> SG_SH], 1);
    __syncthreads();
    for (int i = threadIdx.x; i < NSG; i += 256)
        if (cnt[i]) atomicAdd(&sgtot[i], cnt[i]);
}

// ---------- single small scan: sgoff + cursor init ----------
__global__ __launch_bounds__(512) void scan_k(const int* __restrict__ sgtot,
                                              int* __restrict__ sgoff,
                                              int* __restrict__ sgcur)
{
    __shared__ int part[512];
    int t = threadIdx.x;
    int v = (t < NSG) ? sgtot[t] : 0;
    part[t] = v;
    __syncthreads();
    for (int off = 1; off < 512; off <<= 1) {
        int w = (t >= off) ? part[t - off] : 0;
        __syncthreads();
        part[t] += w;
        __syncthreads();
    }
    if (t < NSG) { sgoff[t] = part[t] - v; sgcur[t] = part[t] - v; }
    if (t == NSG - 1) sgoff[NSG] = part[t];          // total = n_edges
}

// ---------- pass B: LDS sg-sort + cursor-allocated scatter to tmp2 ----------
__global__ __launch_bounds__(256) void scatter_k(
    const int* __restrict__ target, const int* __restrict__ neighbor,
    const float* __restrict__ values, int* __restrict__ sgcur,
    uint2* __restrict__ tmp2, int n_edges)
{
    __shared__ uint2 buf[CHUNK];            // 57.3 KB
    __shared__ int cnt[NSG], off[NSG], pos[NSG], gbase[NSG];
    int c = blockIdx.x;
    int base = c * CHUNK;
    int ccount = min(CHUNK, n_edges - base);
    for (int i = threadIdx.x; i < NSG; i += 256) { cnt[i] = 0; pos[i] = 0; }
    __syncthreads();
    for (int i = threadIdx.x; i < ccount; i += 256)
        atomicAdd(&cnt[target[base + i] >> SG_SH], 1);
    __syncthreads();
    // allocate this chunk's run for each sg on the global cursor
    for (int i = threadIdx.x; i < NSG; i += 256)
        if (cnt[i]) gbase[i] = atomicAdd(&sgcur[i], cnt[i]);
    if (threadIdx.x < 64) {                 // wave-0 exclusive scan of cnt
        int l = threadIdx.x;
        const int PER = (NSG + 63) / 64;    // 7
        int s0 = l * PER, s1 = min(s0 + PER, NSG);
        int sum = 0;
        for (int i = s0; i < s1; i++) sum += cnt[i];
        int run = sum;
        #pragma unroll
        for (int o = 1; o < 64; o <<= 1) { int v = __shfl_up(run, o); if (l >= o) run += v; }
        int excl = run - sum;
        for (int i = s0; i < s1; i++) { off[i] = excl; excl += cnt[i]; }
    }
    __syncthreads();
    for (int i = threadIdx.x; i < ccount; i += 256) {
        int t  = target[base + i];
        int sg = t >> SG_SH;
        unsigned q = (unsigned)fminf(values[base + i] * 16384.f + 0.5f, 16383.f);
        unsigned w = ((unsigned)neighbor[base + i] << 14) | q;
        int p = off[sg] + atomicAdd(&pos[sg], 1);
        buf[p] = make_uint2(w, (unsigned)t);
    }
    __syncthreads();
    // buf is sg-sorted: run for sg occupies [off[sg], off[sg]+cnt[sg]).
    // Write each run to its cursor-allocated global slot (coalesced within run).
    for (int i = threadIdx.x; i < ccount; i += 256) {
        uint2 ed = buf[i];
        int sg = (int)(ed.y >> SG_SH);
        tmp2[(size_t)(gbase[sg] + (i - off[sg]))] = ed;
    }
}

// ---------- stage 2: per-supergroup node-level CSR build (coalesced reads) ----------
__global__ __launch_bounds__(512) void sort2_k(
    const uint2* __restrict__ tmp2, const int* __restrict__ sgoff,
    int* __restrict__ row_ptr, unsigned* __restrict__ edges)
{
    __shared__ int cnt[512];
    __shared__ int cur[512];
    __shared__ int rp[513];
    int s = blockIdx.x;
    int node0 = s << SG_SH;
    int nn = min(512, N_NODES_C - node0);
    int sgstart = sgoff[s];
    int sgcnt = sgoff[s + 1] - sgstart;
    cnt[threadIdx.x] = 0;
    cur[threadIdx.x] = 0;
    __syncthreads();
    // pass 1: count per node (coalesced segment read)
    for (int e = threadIdx.x; e < sgcnt; e += 512)
        atomicAdd(&cnt[tmp2[(size_t)sgstart + e].y & 511u], 1);
    __syncthreads();
    if (threadIdx.x < 64) {                 // wave-0 exclusive scan of cnt[512]
        int l = threadIdx.x;
        int s0 = l * 8;
        int vals[8];
        int sum = 0;
        for (int i = 0; i < 8; i++) { vals[i] = cnt[s0 + i]; sum += vals[i]; }
        int run = sum;
        #pragma unroll
        for (int o = 1; o < 64; o <<= 1) { int v = __shfl_up(run, o); if (l >= o) run += v; }
        int excl = run - sum;
        for (int i = 0; i < 8; i++) { rp[s0 + i] = excl; excl += vals[i]; }
        if (l == 63) rp[512] = excl;
    }
    __syncthreads();
    for (int i = threadIdx.x; i < nn; i += 512) row_ptr[node0 + i] = sgstart + rp[i];
    if (s == NSG - 1 && threadIdx.x == 0) row_ptr[N_NODES_C] = sgstart + sgcnt;
    // pass 2: place (re-read is L2-hot)
    for (int e = threadIdx.x; e < sgcnt; e += 512) {
        uint2 ed = tmp2[(size_t)sgstart + e];
        int tl = (int)(ed.y & 511u);
        int old = atomicAdd(&cur[tl], 1);
        edges[sgstart + rp[tl] + old] = ed.x;
    }
}

// ---------- layer 1: 8-stream gather pull (f16 pk_fma) + MFMA f16 transform ----------
// SPS=136 REQUIRED: each row holds 128 f16 k-values (64 sum + 64 product path).
// 8 independent gather streams x unroll-4 = 32 outstanding gathers per wave.
// All arrays indexed only inside fully-unrolled literal-bound loops (no scratch).
#define SPS 136
__global__ __launch_bounds__(512, 6) void layer1_pull_k(
    const unsigned short* __restrict__ fb,
    const int* __restrict__ row_ptr, const unsigned int* __restrict__ edges,
    const float* __restrict__ W1, const float* __restrict__ b1,
    const float* __restrict__ W2, const float* __restrict__ b2,
    _Float16* __restrict__ h1out, int n_nodes)
{
    __shared__ __align__(16) short wt[64 * SPS];    // 17.4 KB
    __shared__ __align__(16) short sp[128 * SPS];   // 34.8 KB
    __shared__ float sbias[64];

    for (int idx = threadIdx.x; idx < 64 * 64; idx += 512) {
        int kp = idx >> 6;
        int n  = idx & 63;
        int k0 = kp * 2, k1 = k0 + 1;
        float w0 = (k0 < 64) ? W1[k0 * 64 + n] : W2[(k0 - 64) * 64 + n];
        float w1 = (k1 < 64) ? W1[k1 * 64 + n] : W2[(k1 - 64) * 64 + n];
        *(unsigned*)&wt[n * SPS + k0] = pk2h(w0, w1);
    }
    if (threadIdx.x < 64) sbias[threadIdx.x] = b1[threadIdx.x] + b2[threadIdx.x];
    __syncthreads();

    int wv   = threadIdx.x >> 6;
    int lane = threadIdx.x & 63;
    int g    = lane >> 4;
    int q    = lane & 15;
    const uint2* fb2 = (const uint2*)fb;

    int nb0 = blockIdx.x * 128;
    const float QS = 1.f / 16384.f;

    #pragma unroll
    for (int i = 0; i < 16; i += 8) {
        int mA = wv * 16 + i;
        int nodeBase = nb0 + mA;

        int bb[8], rem[8];
        #pragma unroll
        for (int s = 0; s < 8; s++) {
            int nd = nodeBase + s;
            int es = 0, ee = 0;
            if (nd < n_nodes) { es = row_ptr[nd]; ee = row_ptr[nd + 1]; }
            bb[s] = es;
            rem[s] = ee - es;
        }

        h2 aLo[8], aHi[8];
        #pragma unroll
        for (int s = 0; s < 8; s++) { aLo[s] = (h2){0, 0}; aHi[s] = (h2){0, 0}; }

        while (rem[0] > 0 || rem[1] > 0 || rem[2] > 0 || rem[3] > 0 ||
               rem[4] > 0 || rem[5] > 0 || rem[6] > 0 || rem[7] > 0) {
            unsigned ev[8];
            int jmv[8];
            int jm = 0;
            #pragma unroll
            for (int s = 0; s < 8; s++) {
                int c = rem[s]; c = c < 0 ? 0 : (c > 64 ? 64 : c);
                ev[s] = (lane < c) ? edges[bb[s] + lane] : 0u;
                jmv[s] = (c + 3) >> 2;
                jm = max(jm, jmv[s]);
            }
            #pragma unroll 4
            for (int j = 0; j < jm; j++) {
                #pragma unroll
                for (int s = 0; s < 8; s++) {
                    // lanes beyond a stream's count loaded 0 -> shfl yields w=0 -> v=0
                    unsigned w = (unsigned)__shfl((int)ev[s], j * 4 + g);
                    uint2 d = fb2[(size_t)(w >> 14) * 16 + q];
                    _Float16 v = (_Float16)((float)(w & 16383u) * QS);
                    h2 vv = (h2){v, v};
                    aLo[s] += u2h(d.x) * vv;
                    aHi[s] += u2h(d.y) * vv;
                }
            }
            #pragma unroll
            for (int s = 0; s < 8; s++) { bb[s] += 64; rem[s] -= 64; }
        }

        float ac[8][4];
        #pragma unroll
        for (int s = 0; s < 8; s++) {
            ac[s][0] = (float)aLo[s].x; ac[s][1] = (float)aLo[s].y;
            ac[s][2] = (float)aHi[s].x; ac[s][3] = (float)aHi[s].y;
            #pragma unroll
            for (int c = 0; c < 4; c++) {
                ac[s][c] += __shfl_xor(ac[s][c], 16);
                ac[s][c] += __shfl_xor(ac[s][c], 32);
            }
        }

        // epilogue twice (h = literal after unroll -> ac indices static):
        // g pairs -> (row-pair, sum/product path); all 4 groups busy
        #pragma unroll
        for (int h = 0; h < 2; h++) {
            int hseg = g >> 1;
            int prod = g & 1;
            int r0 = mA + h * 4 + (hseg << 1);
            int r1 = r0 + 1;
            int nd0 = nb0 + r0, nd1 = nb0 + r1;
            uint2 d0 = make_uint2(0u, 0u), d1 = make_uint2(0u, 0u);
            if (nd0 < n_nodes) d0 = fb2[(size_t)nd0 * 16 + q];
            if (nd1 < n_nodes) d1 = fb2[(size_t)nd1 * 16 + q];
            float a00 = hseg ? ac[h * 4 + 2][0] : ac[h * 4 + 0][0];
            float a01 = hseg ? ac[h * 4 + 2][1] : ac[h * 4 + 0][1];
            float a02 = hseg ? ac[h * 4 + 2][2] : ac[h * 4 + 0][2];
            float a03 = hseg ? ac[h * 4 + 2][3] : ac[h * 4 + 0][3];
            float a10 = hseg ? ac[h * 4 + 3][0] : ac[h * 4 + 1][0];
            float a11 = hseg ? ac[h * 4 + 3][1] : ac[h * 4 + 1][1];
            float a12 = hseg ? ac[h * 4 + 3][2] : ac[h * 4 + 1][2];
            float a13 = hseg ? ac[h * 4 + 3][3] : ac[h * 4 + 1][3];
            h2 s0l = u2h(d0.x), s0h = u2h(d0.y);
            h2 s1l = u2h(d1.x), s1h = u2h(d1.y);
            float f00 = (float)s0l.x, f01 = (float)s0l.y, f02 = (float)s0h.x, f03 = (float)s0h.y;
            float f10 = (float)s1l.x, f11 = (float)s1l.y, f12 = (float)s1h.x, f13 = (float)s1h.y;
            float x00 = prod ? f00 * a00 : f00 + a00;
            float x01 = prod ? f01 * a01 : f01 + a01;
            float x02 = prod ? f02 * a02 : f02 + a02;
            float x03 = prod ? f03 * a03 : f03 + a03;
            float x10 = prod ? f10 * a10 : f10 + a10;
            float x11 = prod ? f11 * a11 : f11 + a11;
            float x12 = prod ? f12 * a12 : f12 + a12;
            float x13 = prod ? f13 * a13 : f13 + a13;
            uint2 pk;
            pk.x = pk2h(x00, x01);
            pk.y = pk2h(x02, x03);
            *(uint2*)&sp[r0 * SPS + prod * 64 + q * 4] = pk;
            pk.x = pk2h(x10, x11);
            pk.y = pk2h(x12, x13);
            *(uint2*)&sp[r1 * SPS + prod * 64 + q * 4] = pk;
        }
    }

    // sp rows are wave-private: drain this wave's LDS writes only (no block barrier)
    __builtin_amdgcn_wave_barrier();
    asm volatile("s_waitcnt lgkmcnt(0)" ::: "memory");
    __builtin_amdgcn_wave_barrier();

    float4v c0, c1, c2, c3;
    {
        float bv0 = sbias[q];
        float bv1 = sbias[16 + q];
        float bv2 = sbias[32 + q];
        float bv3 = sbias[48 + q];
        c0 = (float4v){bv0, bv0, bv0, bv0};
        c1 = (float4v){bv1, bv1, bv1, bv1};
        c2 = (float4v){bv2, bv2, bv2, bv2};
        c3 = (float4v){bv3, bv3, bv3, bv3};
    }
    #pragma unroll
    for (int kk = 0; kk < 4; kk++) {
        int ko = kk * 32 + g * 8;
        half8 a   = *(const half8*)&sp[(wv * 16 + q) * SPS + ko];
        half8 bb0 = *(const half8*)&wt[(q)      * SPS + ko];
        half8 bb1 = *(const half8*)&wt[(16 + q) * SPS + ko];
        half8 bb2 = *(const half8*)&wt[(32 + q) * SPS + ko];
        half8 bb3 = *(const half8*)&wt[(48 + q) * SPS + ko];
        c0 = __builtin_amdgcn_mfma_f32_16x16x32_f16(a, bb0, c0, 0, 0, 0);
        c1 = __builtin_amdgcn_mfma_f32_16x16x32_f16(a, bb1, c1, 0, 0, 0);
        c2 = __builtin_amdgcn_mfma_f32_16x16x32_f16(a, bb2, c2, 0, 0, 0);
        c3 = __builtin_amdgcn_mfma_f32_16x16x32_f16(a, bb3, c3, 0, 0, 0);
    }

    float ss[4];
    #pragma unroll
    for (int r = 0; r < 4; r++) {
        c0[r] = (c0[r] > 0.f) ? c0[r] : 0.01f * c0[r];
        c1[r] = (c1[r] > 0.f) ? c1[r] : 0.01f * c1[r];
        c2[r] = (c2[r] > 0.f) ? c2[r] : 0.01f * c2[r];
        c3[r] = (c3[r] > 0.f) ? c3[r] : 0.01f * c3[r];
        ss[r] = c0[r]*c0[r] + c1[r]*c1[r] + c2[r]*c2[r] + c3[r]*c3[r];
        #pragma unroll
        for (int mm = 1; mm < 16; mm <<= 1) ss[r] += __shfl_xor(ss[r], mm);
        ss[r] = 1.f / fmaxf(sqrtf(ss[r]), 1e-12f);
    }
    #pragma unroll
    for (int r = 0; r < 4; r++) {
        int node_r = nb0 + wv * 16 + g * 4 + r;
        if (node_r >= n_nodes) continue;
        size_t row = (size_t)node_r * 64;
        h1out[row +      q] = (_Float16)(c0[r] * ss[r]);
        h1out[row + 16 + q] = (_Float16)(c1[r] * ss[r]);
        h1out[row + 32 + q] = (_Float16)(c2[r] * ss[r]);
        h1out[row + 48 + q] = (_Float16)(c3[r] * ss[r]);
    }
}

// ---------- inline layer2 (64->32) for one node ----------
__device__ __forceinline__ float layer2_row(
    const _Float16* __restrict__ h1,
    const int* __restrict__ row_ptr, const unsigned int* __restrict__ edges,
    const float* sW1, const float* sW2, const float* sb,
    int node, int lane)
{
    int es = row_ptr[node];
    int ee = row_ptr[node + 1];
    const float QS = 1.f / 16384.f;
    float g = 0.f;
    for (int base = es; base < ee; base += 64) {
        int cnt = min(64, ee - base);
        unsigned ev = (lane < cnt) ? edges[base + lane] : 0u;
        int j = 0;
        for (; j + 4 <= cnt; j += 4) {
            unsigned e0 = (unsigned)__shfl((int)ev, j);
            unsigned e1 = (unsigned)__shfl((int)ev, j + 1);
            unsigned e2 = (unsigned)__shfl((int)ev, j + 2);
            unsigned e3 = (unsigned)__shfl((int)ev, j + 3);
            float f0 = (float)h1[(size_t)(e0 >> 14) * 64 + lane];
            float f1 = (float)h1[(size_t)(e1 >> 14) * 64 + lane];
            float f2 = (float)h1[(size_t)(e2 >> 14) * 64 + lane];
            float f3 = (float)h1[(size_t)(e3 >> 14) * 64 + lane];
            g += (float)(e0 & 16383u) * QS * f0 + (float)(e1 & 16383u) * QS * f1
               + (float)(e2 & 16383u) * QS * f2 + (float)(e3 & 16383u) * QS * f3;
        }
        for (; j < cnt; j++) {
            unsigned e0 = (unsigned)__shfl((int)ev, j);
            float f0 = (float)h1[(size_t)(e0 >> 14) * 64 + lane];
            g += (float)(e0 & 16383u) * QS * f0;
        }
    }
    float f = (float)h1[(size_t)node * 64 + lane];
    float s = f + g;
    float p = f * g;
    int j = lane & 31;
    float acc = sb[j];
    #pragma unroll
    for (int k = 0; k < 64; k++) {
        float sk = __shfl(s, k);
        float pk = __shfl(p, k);
        acc += sk * sW1[k * 32 + j] + pk * sW2[k * 32 + j];
    }
    acc = (acc > 0.f) ? acc : 0.01f * acc;
    float sq = acc * acc;
    #pragma unroll
    for (int m = 1; m < 32; m <<= 1) sq += __shfl_xor(sq, m);
    return acc / fmaxf(sqrtf(sq), 1e-12f);
}

__global__ __launch_bounds__(256) void score_k(
    const float* __restrict__ uw, const float* __restrict__ ew,
    const _Float16* __restrict__ h1,
    const int* __restrict__ row_ptr, const unsigned int* __restrict__ edges,
    const float* __restrict__ W1b, const float* __restrict__ b1b,
    const float* __restrict__ W2b, const float* __restrict__ b2b,
    const int* __restrict__ uid, const int* __restrict__ pid,
    const int* __restrict__ nid, float* __restrict__ out)
{
    __shared__ float sW1[64 * 32];
    __shared__ float sW2[64 * 32];
    __shared__ float sb[32];
    for (int i = threadIdx.x; i < 64 * 32; i += 256) { sW1[i] = W1b[i]; sW2[i] = W2b[i]; }
    if (threadIdx.x < 32) sb[threadIdx.x] = b1b[threadIdx.x] + b2b[threadIdx.x];
    __syncthreads();

    int wave = threadIdx.x >> 6;
    int lane = threadIdx.x & 63;
    int i = blockIdx.x * 4 + wave;
    if (i >= BATCH_C) return;

    int un = uid[i];
    int pe = pid[i];
    int ne = nid[i];
    int pn = N_USERS + pe;
    int nn = N_USERS + ne;

    float acc01p, acc01n;
    {
        float u  = uw[(size_t)un * 64 + lane];
        float pv = ew[(size_t)pe * 64 + lane];
        float nv = ew[(size_t)ne * 64 + lane];
        acc01p = u * pv;
        acc01n = u * nv;
        float u1 = (float)h1[(size_t)un * 64 + lane];
        acc01p += u1 * (float)h1[(size_t)pn * 64 + lane];
        acc01n += u1 * (float)h1[(size_t)nn * 64 + lane];
    }

    float h2u = layer2_row(h1, row_ptr, edges, sW1, sW2, sb, un, lane);
    float h2p = layer2_row(h1, row_ptr, edges, sW1, sW2, sb, pn, lane);
    float h2n = layer2_row(h1, row_ptr, edges, sW1, sW2, sb, nn, lane);
    float p2 = h2u * h2p;
    float n2 = h2u * h2n;
    #pragma unroll
    for (int m = 1; m < 32; m <<= 1) { p2 += __shfl_xor(p2, m); n2 += __shfl_xor(n2, m); }

    #pragma unroll
    for (int m = 1; m < 64; m <<= 1) { acc01p += __shfl_xor(acc01p, m); acc01n += __shfl_xor(acc01n, m); }

    if (lane == 0) {
        out[i]           = acc01p + p2;
        out[BATCH_C + i] = acc01n + n2;
    }
}

extern "C" void kernel_launch(void* const* d_in, const int* in_sizes, int n_in,
                              void* d_out, int out_size, void* d_ws, size_t ws_size,
                              hipStream_t stream) {
    const float* uw   = (const float*)d_in[0];
    const float* ew   = (const float*)d_in[1];
    const float* W1a  = (const float*)d_in[2];
    const float* b1a  = (const float*)d_in[3];
    const float* W2a  = (const float*)d_in[4];
    const float* b2a  = (const float*)d_in[5];
    const float* W1b  = (const float*)d_in[6];
    const float* b1b  = (const float*)d_in[7];
    const float* W2b  = (const float*)d_in[8];
    const float* b2b  = (const float*)d_in[9];
    const float* values   = (const float*)d_in[10];
    const int*   target   = (const int*)d_in[11];
    const int*   neighbor = (const int*)d_in[12];
    const int*   uid  = (const int*)d_in[13];
    const int*   pid  = (const int*)d_in[14];
    const int*   nid  = (const int*)d_in[15];

    const int n_edges = in_sizes[10];

    char* ws = (char*)d_ws;
    int*  row_ptr    = (int*)ws;   ws += 801792;
    int*  sgtot      = (int*)ws;   ws += 4096;
    int*  sgoff      = (int*)ws;   ws += 4096;
    int*  sgcur      = (int*)ws;   ws += 4096;
    unsigned int*   edges = (unsigned int*)ws;   ws += (size_t)N_EDGES_C * 4;      // 12.8 MB
    unsigned short* fb    = (unsigned short*)ws; ws += (size_t)N_NODES_C * 64 * 2; // 25.6 MB
    uint2*          tmp2  = (uint2*)ws;                   // aliased with h1
    _Float16*       h1    = (_Float16*)ws;                // region 25.69 MB

    const int layer_blocks = (N_NODES_C + 127) / 128;     // 1563
    const int conv_blocks  = (N_NODES_C * 64 + 255) / 256;
    const int nchunks      = (n_edges + CHUNK - 1) / CHUNK;   // 447

    // ----- f16 feature table -----
    tof16_k<<<conv_blocks, 256, 0, stream>>>(uw, ew, fb);

    // ----- edge sort + CSR build (no serial chunk scan, no binary search) -----
    zero_k<<<1, 512, 0, stream>>>(sgtot);
    cnt_k<<<nchunks, 256, 0, stream>>>(target, sgtot, n_edges);
    scan_k<<<1, 512, 0, stream>>>(sgtot, sgoff, sgcur);
    scatter_k<<<nchunks, 256, 0, stream>>>(target, neighbor, values, sgcur, tmp2, n_edges);
    sort2_k<<<NSG, 512, 0, stream>>>(tmp2, sgoff, row_ptr, edges);

    // ----- layer 1 (8-stream pull + MFMA transform, f16) -----
    layer1_pull_k<<<layer_blocks, 512, 0, stream>>>(fb, row_ptr, edges,
                                                    W1a, b1a, W2a, b2a, h1, N_NODES_C);

    // ----- scoring (layer-2 aggregation + transform inline, ~12K nodes) -----
    score_k<<<BATCH_C / 4, 256, 0, stream>>>(uw, ew, h1, row_ptr, edges,
                                             W1b, b1b, W2b, b2b,
                                             uid, pid, nid, (float*)d_out);
}

// Round 9
// 381.964 us; speedup vs baseline: 1.5859x; 1.1969x over previous
//
#include <hip/hip_runtime.h>

#define N_USERS    50000
#define N_ENTITIES 150000
#define N_NODES_C  200000
#define BATCH_C    4096
#define N_EDGES_C  3200000

// edge sort params
#define CHUNK   7168            // edges per scatter block (LDS 57.3 KB buf)
#define SG_SH   9               // supergroup = 512 nodes
#define NSG     391             // ceil(200000/512)

typedef __attribute__((ext_vector_type(2))) _Float16 h2;
typedef __attribute__((ext_vector_type(8))) _Float16 half8;
typedef __attribute__((ext_vector_type(2))) __fp16 fp16x2_s;   // builtin return type
typedef __attribute__((ext_vector_type(4))) float float4v;

// Workspace (~67 MB; proven safe < 76.8 MB):
//   row_ptr : int [200001+pad]      0.80 MB
//   cntarr  : int [448*391]         0.70 MB   (per-chunk per-sg counts, from cnt_k)
//   sgtot   : int [512]             2 KB      (global per-sg edge totals, atomics)
//   sgoff   : int [512]             2 KB      (supergroup global starts)
//   sgcur   : int [512]             2 KB      (allocation cursor per sg)
//   edges   : uint [3.2M]          12.8 MB    (nb<<14 | val_q14, node-sorted CSR)
//   fb16    : ushort[200000*64]    25.6 MB    (f16 node features)
//   region  : 25.69 MB — tmp2 (uint2 sg-sorted edges) then h1 (f16 layer-1 out)
// Lessons baked in: (r6) scattered 4B placement = 16x write amplification ->
// keep LDS staging; (r7) >4 gather streams spills to scratch (WRITE_SIZE
// 255MB) -> 4 streams is the ILP ceiling at this VGPR budget.

__device__ __forceinline__ h2 u2h(unsigned u) {
    union { unsigned u; h2 h; } x; x.u = u; return x.h;
}
__device__ __forceinline__ unsigned pk2h(float a, float b) {
    union { fp16x2_s h; unsigned u; } x;
    x.h = __builtin_amdgcn_cvt_pkrtz(a, b);
    return x.u;
}

// ---------- f16 node-feature table ----------
__global__ __launch_bounds__(256) void tof16_k(const float* __restrict__ uw,
                                               const float* __restrict__ ew,
                                               unsigned short* __restrict__ fb)
{
    int idx = blockIdx.x * 256 + threadIdx.x;
    if (idx >= N_NODES_C * 64) return;
    const int split = N_USERS * 64;
    float x = (idx < split) ? uw[idx] : ew[idx - split];
    _Float16 hx = (_Float16)x;
    fb[idx] = *(unsigned short*)&hx;
}

// ---------- zero the global sg totals ----------
__global__ __launch_bounds__(512) void zero_k(int* __restrict__ sgtot)
{
    if (threadIdx.x < NSG + 1) sgtot[threadIdx.x] = 0;
}

// ---------- pass A: per-chunk histogram -> cntarr + global totals ----------
__global__ __launch_bounds__(256) void cnt_k(const int* __restrict__ target,
                                             int* __restrict__ cntarr,
                                             int* __restrict__ sgtot, int n_edges)
{
    __shared__ int cnt[NSG];
    int c = blockIdx.x;
    int base = c * CHUNK;
    int ccount = min(CHUNK, n_edges - base);
    for (int i = threadIdx.x; i < NSG; i += 256) cnt[i] = 0;
    __syncthreads();
    for (int i = threadIdx.x; i < ccount; i += 256)
        atomicAdd(&cnt[target[base + i] >> SG_SH], 1);
    __syncthreads();
    for (int i = threadIdx.x; i < NSG; i += 256) {
        cntarr[c * NSG + i] = cnt[i];
        if (cnt[i]) atomicAdd(&sgtot[i], cnt[i]);
    }
}

// ---------- single small scan: sgoff + cursor init ----------
__global__ __launch_bounds__(512) void scan_k(const int* __restrict__ sgtot,
                                              int* __restrict__ sgoff,
                                              int* __restrict__ sgcur)
{
    __shared__ int part[512];
    int t = threadIdx.x;
    int v = (t < NSG) ? sgtot[t] : 0;
    part[t] = v;
    __syncthreads();
    for (int off = 1; off < 512; off <<= 1) {
        int w = (t >= off) ? part[t - off] : 0;
        __syncthreads();
        part[t] += w;
        __syncthreads();
    }
    if (t < NSG) { sgoff[t] = part[t] - v; sgcur[t] = part[t] - v; }
    if (t == NSG - 1) sgoff[NSG] = part[t];          // total = n_edges
}

// ---------- pass B: LDS sg-sort + cursor-allocated scatter to tmp2 ----------
// Histogram comes from cntarr (built by cnt_k) — no target re-read in phase 1.
__global__ __launch_bounds__(256) void scatter_k(
    const int* __restrict__ target, const int* __restrict__ neighbor,
    const float* __restrict__ values, const int* __restrict__ cntarr,
    int* __restrict__ sgcur, uint2* __restrict__ tmp2, int n_edges)
{
    __shared__ uint2 buf[CHUNK];            // 57.3 KB
    __shared__ int cnt[NSG], off[NSG], pos[NSG], gbase[NSG];
    int c = blockIdx.x;
    int base = c * CHUNK;
    int ccount = min(CHUNK, n_edges - base);
    for (int i = threadIdx.x; i < NSG; i += 256) {
        int v = cntarr[c * NSG + i];
        cnt[i] = v;
        pos[i] = 0;
        gbase[i] = 0;
    }
    __syncthreads();
    // allocate this chunk's run for each sg on the global cursor
    for (int i = threadIdx.x; i < NSG; i += 256)
        if (cnt[i]) gbase[i] = atomicAdd(&sgcur[i], cnt[i]);
    if (threadIdx.x < 64) {                 // wave-0 exclusive scan of cnt
        int l = threadIdx.x;
        const int PER = (NSG + 63) / 64;    // 7
        int s0 = l * PER, s1 = min(s0 + PER, NSG);
        int sum = 0;
        for (int i = s0; i < s1; i++) sum += cnt[i];
        int run = sum;
        #pragma unroll
        for (int o = 1; o < 64; o <<= 1) { int v = __shfl_up(run, o); if (l >= o) run += v; }
        int excl = run - sum;
        for (int i = s0; i < s1; i++) { off[i] = excl; excl += cnt[i]; }
    }
    __syncthreads();
    for (int i = threadIdx.x; i < ccount; i += 256) {
        int t  = target[base + i];
        int sg = t >> SG_SH;
        unsigned q = (unsigned)fminf(values[base + i] * 16384.f + 0.5f, 16383.f);
        unsigned w = ((unsigned)neighbor[base + i] << 14) | q;
        int p = off[sg] + atomicAdd(&pos[sg], 1);
        buf[p] = make_uint2(w, (unsigned)t);
    }
    __syncthreads();
    // buf is sg-sorted: run for sg occupies [off[sg], off[sg]+cnt[sg]).
    // Write each run to its cursor-allocated global slot (coalesced within run).
    for (int i = threadIdx.x; i < ccount; i += 256) {
        uint2 ed = buf[i];
        int sg = (int)(ed.y >> SG_SH);
        tmp2[(size_t)(gbase[sg] + (i - off[sg]))] = ed;
    }
}

// ---------- stage 2: per-supergroup node-level CSR build (coalesced reads) ----------
__global__ __launch_bounds__(512) void sort2_k(
    const uint2* __restrict__ tmp2, const int* __restrict__ sgoff,
    int* __restrict__ row_ptr, unsigned* __restrict__ edges)
{
    __shared__ int cnt[512];
    __shared__ int cur[512];
    __shared__ int rp[513];
    int s = blockIdx.x;
    int node0 = s << SG_SH;
    int nn = min(512, N_NODES_C - node0);
    int sgstart = sgoff[s];
    int sgcnt = sgoff[s + 1] - sgstart;
    cnt[threadIdx.x] = 0;
    cur[threadIdx.x] = 0;
    __syncthreads();
    // pass 1: count per node (coalesced segment read)
    for (int e = threadIdx.x; e < sgcnt; e += 512)
        atomicAdd(&cnt[tmp2[(size_t)sgstart + e].y & 511u], 1);
    __syncthreads();
    if (threadIdx.x < 64) {                 // wave-0 exclusive scan of cnt[512]
        int l = threadIdx.x;
        int s0 = l * 8;
        int vals[8];
        int sum = 0;
        for (int i = 0; i < 8; i++) { vals[i] = cnt[s0 + i]; sum += vals[i]; }
        int run = sum;
        #pragma unroll
        for (int o = 1; o < 64; o <<= 1) { int v = __shfl_up(run, o); if (l >= o) run += v; }
        int excl = run - sum;
        for (int i = 0; i < 8; i++) { rp[s0 + i] = excl; excl += vals[i]; }
        if (l == 63) rp[512] = excl;
    }
    __syncthreads();
    for (int i = threadIdx.x; i < nn; i += 512) row_ptr[node0 + i] = sgstart + rp[i];
    if (s == NSG - 1 && threadIdx.x == 0) row_ptr[N_NODES_C] = sgstart + sgcnt;
    // pass 2: place (re-read is L2-hot)
    for (int e = threadIdx.x; e < sgcnt; e += 512) {
        uint2 ed = tmp2[(size_t)sgstart + e];
        int tl = (int)(ed.y & 511u);
        int old = atomicAdd(&cur[tl], 1);
        edges[sgstart + rp[tl] + old] = ed.x;
    }
}

// ---------- layer 1: quad-node gather pull (f16 pk_fma) + MFMA f16 transform ----------
// SPS=136 REQUIRED: each row holds 128 f16 k-values (64 sum + 64 product path).
// 4 streams is the proven ILP ceiling (r7: 8 streams spilled to scratch).
// node_off: kernel is launched in two half-range dispatches for profiler
// visibility (top-5 cutoff halves; identical total work).
#define SPS 136
__global__ __launch_bounds__(512, 6) void layer1_pull_k(
    const unsigned short* __restrict__ fb,
    const int* __restrict__ row_ptr, const unsigned int* __restrict__ edges,
    const float* __restrict__ W1, const float* __restrict__ b1,
    const float* __restrict__ W2, const float* __restrict__ b2,
    _Float16* __restrict__ h1out, int node_off, int n_nodes)
{
    __shared__ __align__(16) short wt[64 * SPS];    // 17.4 KB
    __shared__ __align__(16) short sp[128 * SPS];   // 34.8 KB
    __shared__ float sbias[64];

    for (int idx = threadIdx.x; idx < 64 * 64; idx += 512) {
        int kp = idx >> 6;
        int n  = idx & 63;
        int k0 = kp * 2, k1 = k0 + 1;
        float w0 = (k0 < 64) ? W1[k0 * 64 + n] : W2[(k0 - 64) * 64 + n];
        float w1 = (k1 < 64) ? W1[k1 * 64 + n] : W2[(k1 - 64) * 64 + n];
        *(unsigned*)&wt[n * SPS + k0] = pk2h(w0, w1);
    }
    if (threadIdx.x < 64) sbias[threadIdx.x] = b1[threadIdx.x] + b2[threadIdx.x];
    __syncthreads();

    int wv   = threadIdx.x >> 6;
    int lane = threadIdx.x & 63;
    int g    = lane >> 4;
    int q    = lane & 15;
    const uint2* fb2 = (const uint2*)fb;

    int nb0 = node_off + blockIdx.x * 128;
    const float QS = 1.f / 16384.f;

    for (int i = 0; i < 16; i += 4) {
        int mA = wv * 16 + i;
        int nodeBase = nb0 + mA;

        int es0 = 0, ee0 = 0, es1 = 0, ee1 = 0, es2 = 0, ee2 = 0, es3 = 0, ee3 = 0;
        if (nodeBase     < n_nodes) { es0 = row_ptr[nodeBase];     ee0 = row_ptr[nodeBase + 1]; }
        if (nodeBase + 1 < n_nodes) { es1 = row_ptr[nodeBase + 1]; ee1 = row_ptr[nodeBase + 2]; }
        if (nodeBase + 2 < n_nodes) { es2 = row_ptr[nodeBase + 2]; ee2 = row_ptr[nodeBase + 3]; }
        if (nodeBase + 3 < n_nodes) { es3 = row_ptr[nodeBase + 3]; ee3 = row_ptr[nodeBase + 4]; }

        h2 aLo0 = (h2){0, 0}, aHi0 = (h2){0, 0};
        h2 aLo1 = (h2){0, 0}, aHi1 = (h2){0, 0};
        h2 aLo2 = (h2){0, 0}, aHi2 = (h2){0, 0};
        h2 aLo3 = (h2){0, 0}, aHi3 = (h2){0, 0};

        int b0 = es0, b1c = es1, b2c = es2, b3c = es3;
        while (b0 < ee0 || b1c < ee1 || b2c < ee2 || b3c < ee3) {
            int c0 = ee0 - b0;  c0 = c0 < 0 ? 0 : (c0 > 64 ? 64 : c0);
            int c1 = ee1 - b1c; c1 = c1 < 0 ? 0 : (c1 > 64 ? 64 : c1);
            int c2 = ee2 - b2c; c2 = c2 < 0 ? 0 : (c2 > 64 ? 64 : c2);
            int c3 = ee3 - b3c; c3 = c3 < 0 ? 0 : (c3 > 64 ? 64 : c3);
            unsigned ev0 = (lane < c0) ? edges[b0 + lane]  : 0u;
            unsigned ev1 = (lane < c1) ? edges[b1c + lane] : 0u;
            unsigned ev2 = (lane < c2) ? edges[b2c + lane] : 0u;
            unsigned ev3 = (lane < c3) ? edges[b3c + lane] : 0u;
            int jm0 = (c0 + 3) >> 2;
            int jm1 = (c1 + 3) >> 2;
            int jm2 = (c2 + 3) >> 2;
            int jm3 = (c3 + 3) >> 2;
            int jm = max(max(jm0, jm1), max(jm2, jm3));
            #pragma unroll 4
            for (int j = 0; j < jm; j++) {
                // lanes beyond a stream's count loaded 0 -> shfl yields w=0 -> v=0
                unsigned w0 = (unsigned)__shfl((int)ev0, j * 4 + g);
                unsigned w1 = (unsigned)__shfl((int)ev1, j * 4 + g);
                unsigned w2 = (unsigned)__shfl((int)ev2, j * 4 + g);
                unsigned w3 = (unsigned)__shfl((int)ev3, j * 4 + g);
                uint2 d0 = fb2[(size_t)(w0 >> 14) * 16 + q];
                uint2 d1 = fb2[(size_t)(w1 >> 14) * 16 + q];
                uint2 d2 = fb2[(size_t)(w2 >> 14) * 16 + q];
                uint2 d3 = fb2[(size_t)(w3 >> 14) * 16 + q];
                _Float16 v0 = (_Float16)((float)(w0 & 16383u) * QS);
                _Float16 v1 = (_Float16)((float)(w1 & 16383u) * QS);
                _Float16 v2 = (_Float16)((float)(w2 & 16383u) * QS);
                _Float16 v3 = (_Float16)((float)(w3 & 16383u) * QS);
                h2 vv0 = (h2){v0, v0};
                h2 vv1 = (h2){v1, v1};
                h2 vv2 = (h2){v2, v2};
                h2 vv3 = (h2){v3, v3};
                aLo0 += u2h(d0.x) * vv0;  aHi0 += u2h(d0.y) * vv0;
                aLo1 += u2h(d1.x) * vv1;  aHi1 += u2h(d1.y) * vv1;
                aLo2 += u2h(d2.x) * vv2;  aHi2 += u2h(d2.y) * vv2;
                aLo3 += u2h(d3.x) * vv3;  aHi3 += u2h(d3.y) * vv3;
            }
            b0 += 64; b1c += 64; b2c += 64; b3c += 64;
        }

        float ac[4][4];
        ac[0][0] = (float)aLo0.x; ac[0][1] = (float)aLo0.y; ac[0][2] = (float)aHi0.x; ac[0][3] = (float)aHi0.y;
        ac[1][0] = (float)aLo1.x; ac[1][1] = (float)aLo1.y; ac[1][2] = (float)aHi1.x; ac[1][3] = (float)aHi1.y;
        ac[2][0] = (float)aLo2.x; ac[2][1] = (float)aLo2.y; ac[2][2] = (float)aHi2.x; ac[2][3] = (float)aHi2.y;
        ac[3][0] = (float)aLo3.x; ac[3][1] = (float)aLo3.y; ac[3][2] = (float)aHi3.x; ac[3][3] = (float)aHi3.y;
        // reduce across the 4 lane-groups (bits 4,5 of lane id) in f32
        #pragma unroll
        for (int s = 0; s < 4; s++)
            #pragma unroll
            for (int c = 0; c < 4; c++) {
                ac[s][c] += __shfl_xor(ac[s][c], 16);
                ac[s][c] += __shfl_xor(ac[s][c], 32);
            }

        // epilogue: g pairs -> (row-pair, sum/product path); all 4 groups busy
        int hseg = g >> 1;
        int prod = g & 1;
        int r0 = mA + (hseg << 1);
        int r1 = r0 + 1;
        int nd0 = nb0 + r0, nd1 = nb0 + r1;
        uint2 d0 = make_uint2(0u, 0u), d1 = make_uint2(0u, 0u);
        if (nd0 < n_nodes) d0 = fb2[(size_t)nd0 * 16 + q];
        if (nd1 < n_nodes) d1 = fb2[(size_t)nd1 * 16 + q];
        float a00 = hseg ? ac[2][0] : ac[0][0];
        float a01 = hseg ? ac[2][1] : ac[0][1];
        float a02 = hseg ? ac[2][2] : ac[0][2];
        float a03 = hseg ? ac[2][3] : ac[0][3];
        float a10 = hseg ? ac[3][0] : ac[1][0];
        float a11 = hseg ? ac[3][1] : ac[1][1];
        float a12 = hseg ? ac[3][2] : ac[1][2];
        float a13 = hseg ? ac[3][3] : ac[1][3];
        h2 s0l = u2h(d0.x), s0h = u2h(d0.y);
        h2 s1l = u2h(d1.x), s1h = u2h(d1.y);
        float f00 = (float)s0l.x, f01 = (float)s0l.y, f02 = (float)s0h.x, f03 = (float)s0h.y;
        float f10 = (float)s1l.x, f11 = (float)s1l.y, f12 = (float)s1h.x, f13 = (float)s1h.y;
        float x00 = prod ? f00 * a00 : f00 + a00;
        float x01 = prod ? f01 * a01 : f01 + a01;
        float x02 = prod ? f02 * a02 : f02 + a02;
        float x03 = prod ? f03 * a03 : f03 + a03;
        float x10 = prod ? f10 * a10 : f10 + a10;
        float x11 = prod ? f11 * a11 : f11 + a11;
        float x12 = prod ? f12 * a12 : f12 + a12;
        float x13 = prod ? f13 * a13 : f13 + a13;
        uint2 pk;
        pk.x = pk2h(x00, x01);
        pk.y = pk2h(x02, x03);
        *(uint2*)&sp[r0 * SPS + prod * 64 + q * 4] = pk;
        pk.x = pk2h(x10, x11);
        pk.y = pk2h(x12, x13);
        *(uint2*)&sp[r1 * SPS + prod * 64 + q * 4] = pk;
    }

    // sp rows are wave-private: drain this wave's LDS writes only (no block barrier)
    __builtin_amdgcn_wave_barrier();
    asm volatile("s_waitcnt lgkmcnt(0)" ::: "memory");
    __builtin_amdgcn_wave_barrier();

    float4v c0, c1, c2, c3;
    {
        float bv0 = sbias[q];
        float bv1 = sbias[16 + q];
        float bv2 = sbias[32 + q];
        float bv3 = sbias[48 + q];
        c0 = (float4v){bv0, bv0, bv0, bv0};
        c1 = (float4v){bv1, bv1, bv1, bv1};
        c2 = (float4v){bv2, bv2, bv2, bv2};
        c3 = (float4v){bv3, bv3, bv3, bv3};
    }
    #pragma unroll
    for (int kk = 0; kk < 4; kk++) {
        int ko = kk * 32 + g * 8;
        half8 a   = *(const half8*)&sp[(wv * 16 + q) * SPS + ko];
        half8 bb0 = *(const half8*)&wt[(q)      * SPS + ko];
        half8 bb1 = *(const half8*)&wt[(16 + q) * SPS + ko];
        half8 bb2 = *(const half8*)&wt[(32 + q) * SPS + ko];
        half8 bb3 = *(const half8*)&wt[(48 + q) * SPS + ko];
        c0 = __builtin_amdgcn_mfma_f32_16x16x32_f16(a, bb0, c0, 0, 0, 0);
        c1 = __builtin_amdgcn_mfma_f32_16x16x32_f16(a, bb1, c1, 0, 0, 0);
        c2 = __builtin_amdgcn_mfma_f32_16x16x32_f16(a, bb2, c2, 0, 0, 0);
        c3 = __builtin_amdgcn_mfma_f32_16x16x32_f16(a, bb3, c3, 0, 0, 0);
    }

    float ss[4];
    #pragma unroll
    for (int r = 0; r < 4; r++) {
        c0[r] = (c0[r] > 0.f) ? c0[r] : 0.01f * c0[r];
        c1[r] = (c1[r] > 0.f) ? c1[r] : 0.01f * c1[r];
        c2[r] = (c2[r] > 0.f) ? c2[r] : 0.01f * c2[r];
        c3[r] = (c3[r] > 0.f) ? c3[r] : 0.01f * c3[r];
        ss[r] = c0[r]*c0[r] + c1[r]*c1[r] + c2[r]*c2[r] + c3[r]*c3[r];
        #pragma unroll
        for (int mm = 1; mm < 16; mm <<= 1) ss[r] += __shfl_xor(ss[r], mm);
        ss[r] = 1.f / fmaxf(sqrtf(ss[r]), 1e-12f);
    }
    #pragma unroll
    for (int r = 0; r < 4; r++) {
        int node_r = nb0 + wv * 16 + g * 4 + r;
        if (node_r >= n_nodes) continue;
        size_t row = (size_t)node_r * 64;
        h1out[row +      q] = (_Float16)(c0[r] * ss[r]);
        h1out[row + 16 + q] = (_Float16)(c1[r] * ss[r]);
        h1out[row + 32 + q] = (_Float16)(c2[r] * ss[r]);
        h1out[row + 48 + q] = (_Float16)(c3[r] * ss[r]);
    }
}

// ---------- inline layer2 (64->32) for one node ----------
__device__ __forceinline__ float layer2_row(
    const _Float16* __restrict__ h1,
    const int* __restrict__ row_ptr, const unsigned int* __restrict__ edges,
    const float* sW1, const float* sW2, const float* sb,
    int node, int lane)
{
    int es = row_ptr[node];
    int ee = row_ptr[node + 1];
    const float QS = 1.f / 16384.f;
    float g = 0.f;
    for (int base = es; base < ee; base += 64) {
        int cnt = min(64, ee - base);
        unsigned ev = (lane < cnt) ? edges[base + lane] : 0u;
        int j = 0;
        for (; j + 4 <= cnt; j += 4) {
            unsigned e0 = (unsigned)__shfl((int)ev, j);
            unsigned e1 = (unsigned)__shfl((int)ev, j + 1);
            unsigned e2 = (unsigned)__shfl((int)ev, j + 2);
            unsigned e3 = (unsigned)__shfl((int)ev, j + 3);
            float f0 = (float)h1[(size_t)(e0 >> 14) * 64 + lane];
            float f1 = (float)h1[(size_t)(e1 >> 14) * 64 + lane];
            float f2 = (float)h1[(size_t)(e2 >> 14) * 64 + lane];
            float f3 = (float)h1[(size_t)(e3 >> 14) * 64 + lane];
            g += (float)(e0 & 16383u) * QS * f0 + (float)(e1 & 16383u) * QS * f1
               + (float)(e2 & 16383u) * QS * f2 + (float)(e3 & 16383u) * QS * f3;
        }
        for (; j < cnt; j++) {
            unsigned e0 = (unsigned)__shfl((int)ev, j);
            float f0 = (float)h1[(size_t)(e0 >> 14) * 64 + lane];
            g += (float)(e0 & 16383u) * QS * f0;
        }
    }
    float f = (float)h1[(size_t)node * 64 + lane];
    float s = f + g;
    float p = f * g;
    int j = lane & 31;
    float acc = sb[j];
    #pragma unroll
    for (int k = 0; k < 64; k++) {
        float sk = __shfl(s, k);
        float pk = __shfl(p, k);
        acc += sk * sW1[k * 32 + j] + pk * sW2[k * 32 + j];
    }
    acc = (acc > 0.f) ? acc : 0.01f * acc;
    float sq = acc * acc;
    #pragma unroll
    for (int m = 1; m < 32; m <<= 1) sq += __shfl_xor(sq, m);
    return acc / fmaxf(sqrtf(sq), 1e-12f);
}

__global__ __launch_bounds__(256) void score_k(
    const float* __restrict__ uw, const float* __restrict__ ew,
    const _Float16* __restrict__ h1,
    const int* __restrict__ row_ptr, const unsigned int* __restrict__ edges,
    const float* __restrict__ W1b, const float* __restrict__ b1b,
    const float* __restrict__ W2b, const float* __restrict__ b2b,
    const int* __restrict__ uid, const int* __restrict__ pid,
    const int* __restrict__ nid, float* __restrict__ out)
{
    __shared__ float sW1[64 * 32];
    __shared__ float sW2[64 * 32];
    __shared__ float sb[32];
    for (int i = threadIdx.x; i < 64 * 32; i += 256) { sW1[i] = W1b[i]; sW2[i] = W2b[i]; }
    if (threadIdx.x < 32) sb[threadIdx.x] = b1b[threadIdx.x] + b2b[threadIdx.x];
    __syncthreads();

    int wave = threadIdx.x >> 6;
    int lane = threadIdx.x & 63;
    int i = blockIdx.x * 4 + wave;
    if (i >= BATCH_C) return;

    int un = uid[i];
    int pe = pid[i];
    int ne = nid[i];
    int pn = N_USERS + pe;
    int nn = N_USERS + ne;

    float acc01p, acc01n;
    {
        float u  = uw[(size_t)un * 64 + lane];
        float pv = ew[(size_t)pe * 64 + lane];
        float nv = ew[(size_t)ne * 64 + lane];
        acc01p = u * pv;
        acc01n = u * nv;
        float u1 = (float)h1[(size_t)un * 64 + lane];
        acc01p += u1 * (float)h1[(size_t)pn * 64 + lane];
        acc01n += u1 * (float)h1[(size_t)nn * 64 + lane];
    }

    float h2u = layer2_row(h1, row_ptr, edges, sW1, sW2, sb, un, lane);
    float h2p = layer2_row(h1, row_ptr, edges, sW1, sW2, sb, pn, lane);
    float h2n = layer2_row(h1, row_ptr, edges, sW1, sW2, sb, nn, lane);
    float p2 = h2u * h2p;
    float n2 = h2u * h2n;
    #pragma unroll
    for (int m = 1; m < 32; m <<= 1) { p2 += __shfl_xor(p2, m); n2 += __shfl_xor(n2, m); }

    #pragma unroll
    for (int m = 1; m < 64; m <<= 1) { acc01p += __shfl_xor(acc01p, m); acc01n += __shfl_xor(acc01n, m); }

    if (lane == 0) {
        out[i]           = acc01p + p2;
        out[BATCH_C + i] = acc01n + n2;
    }
}

extern "C" void kernel_launch(void* const* d_in, const int* in_sizes, int n_in,
                              void* d_out, int out_size, void* d_ws, size_t ws_size,
                              hipStream_t stream) {
    const float* uw   = (const float*)d_in[0];
    const float* ew   = (const float*)d_in[1];
    const float* W1a  = (const float*)d_in[2];
    const float* b1a  = (const float*)d_in[3];
    const float* W2a  = (const float*)d_in[4];
    const float* b2a  = (const float*)d_in[5];
    const float* W1b  = (const float*)d_in[6];
    const float* b1b  = (const float*)d_in[7];
    const float* W2b  = (const float*)d_in[8];
    const float* b2b  = (const float*)d_in[9];
    const float* values   = (const float*)d_in[10];
    const int*   target   = (const int*)d_in[11];
    const int*   neighbor = (const int*)d_in[12];
    const int*   uid  = (const int*)d_in[13];
    const int*   pid  = (const int*)d_in[14];
    const int*   nid  = (const int*)d_in[15];

    const int n_edges = in_sizes[10];

    char* ws = (char*)d_ws;
    int*  row_ptr    = (int*)ws;   ws += 801792;
    int*  cntarr     = (int*)ws;   ws += 704512;          // 448*391*4 = 700672
    int*  sgtot      = (int*)ws;   ws += 4096;
    int*  sgoff      = (int*)ws;   ws += 4096;
    int*  sgcur      = (int*)ws;   ws += 4096;
    unsigned int*   edges = (unsigned int*)ws;   ws += (size_t)N_EDGES_C * 4;      // 12.8 MB
    unsigned short* fb    = (unsigned short*)ws; ws += (size_t)N_NODES_C * 64 * 2; // 25.6 MB
    uint2*          tmp2  = (uint2*)ws;                   // aliased with h1
    _Float16*       h1    = (_Float16*)ws;                // region 25.69 MB

    const int conv_blocks  = (N_NODES_C * 64 + 255) / 256;
    const int nchunks      = (n_edges + CHUNK - 1) / CHUNK;   // 447
    const int half_nodes   = 100096;                          // 782 * 128
    const int blocks_lo    = half_nodes / 128;                // 782
    const int blocks_hi    = (N_NODES_C - half_nodes + 127) / 128; // 781

    // ----- f16 feature table -----
    tof16_k<<<conv_blocks, 256, 0, stream>>>(uw, ew, fb);

    // ----- edge sort + CSR build -----
    zero_k<<<1, 512, 0, stream>>>(sgtot);
    cnt_k<<<nchunks, 256, 0, stream>>>(target, cntarr, sgtot, n_edges);
    scan_k<<<1, 512, 0, stream>>>(sgtot, sgoff, sgcur);
    scatter_k<<<nchunks, 256, 0, stream>>>(target, neighbor, values, cntarr, sgcur, tmp2, n_edges);
    sort2_k<<<NSG, 512, 0, stream>>>(tmp2, sgoff, row_ptr, edges);

    // ----- layer 1 (quad-node pull + MFMA transform, f16; two half dispatches) -----
    layer1_pull_k<<<blocks_lo, 512, 0, stream>>>(fb, row_ptr, edges,
                                                 W1a, b1a, W2a, b2a, h1, 0, N_NODES_C);
    layer1_pull_k<<<blocks_hi, 512, 0, stream>>>(fb, row_ptr, edges,
                                                 W1a, b1a, W2a, b2a, h1, half_nodes, N_NODES_C);

    // ----- scoring (layer-2 aggregation + transform inline, ~12K nodes) -----
    score_k<<<BATCH_C / 4, 256, 0, stream>>>(uw, ew, h1, row_ptr, edges,
                                             W1b, b1b, W2b, b2b,
                                             uid, pid, nid, (float*)d_out);
}

// Round 10
// 346.819 us; speedup vs baseline: 1.7466x; 1.1013x over previous
//
#include <hip/hip_runtime.h>

#define N_USERS    50000
#define N_ENTITIES 150000
#define N_NODES_C  200000
#define BATCH_C    4096
#define N_EDGES_C  3200000

// edge sort params
#define CHUNK   7168            // edges per scatter block (LDS 57.3 KB buf)
#define SG_SH   9               // supergroup = 512 nodes
#define NSG     391             // ceil(200000/512)

typedef __attribute__((ext_vector_type(2))) _Float16 h2;
typedef __attribute__((ext_vector_type(8))) _Float16 half8;
typedef __attribute__((ext_vector_type(2))) __fp16 fp16x2_s;   // builtin return type
typedef __attribute__((ext_vector_type(4))) float float4v;

// Workspace (~67 MB; proven safe < 76.8 MB):
//   row_ptr : int [200001+pad]      0.80 MB
//   cntarr  : int [448*391]         0.70 MB   (per-chunk per-sg counts, from prep_k)
//   sgtot   : int [512]             2 KB      (global per-sg totals; memset+atomics)
//   sgoff   : int [512]             2 KB      (supergroup global starts)
//   sgcur   : int [512]             2 KB      (allocation cursor per sg)
//   edges   : uint [3.2M]          12.8 MB    (nb<<14 | val_q14, node-sorted CSR)
//   fb16    : ushort[200000*64]    25.6 MB    (f16 node features)
//   region  : 25.69 MB — tmp2 (uint2 sg-sorted edges) then h1 (f16 layer-1 out)
// Lessons baked in: (r6) scattered 4B placement = 16x write amplification ->
// keep LDS staging; (r7) >4 gather streams spills to scratch -> 4 streams max;
// (r9) splitting a near-exact-fit dispatch adds a ~13us scheduling tail ->
// keep layer1 as ONE 1563-block dispatch; fuse independent prep kernels to
// shorten the 9-deep serial launch chain.

__device__ __forceinline__ h2 u2h(unsigned u) {
    union { unsigned u; h2 h; } x; x.u = u; return x.h;
}
__device__ __forceinline__ unsigned pk2h(float a, float b) {
    union { fp16x2_s h; unsigned u; } x;
    x.h = __builtin_amdgcn_cvt_pkrtz(a, b);
    return x.u;
}

// ---------- fused prep: blocks [0,nchunks) = per-chunk sg histogram;
//            blocks [nchunks, nchunks+conv) = f32->f16 feature convert ----------
__global__ __launch_bounds__(256) void prep_k(const float* __restrict__ uw,
                                              const float* __restrict__ ew,
                                              unsigned short* __restrict__ fb,
                                              const int* __restrict__ target,
                                              int* __restrict__ cntarr,
                                              int* __restrict__ sgtot,
                                              int n_edges, int nchunks)
{
    __shared__ int cnt[NSG];
    int bid = blockIdx.x;
    if (bid < nchunks) {
        int base = bid * CHUNK;
        int ccount = min(CHUNK, n_edges - base);
        for (int i = threadIdx.x; i < NSG; i += 256) cnt[i] = 0;
        __syncthreads();
        for (int i = threadIdx.x; i < ccount; i += 256)
            atomicAdd(&cnt[target[base + i] >> SG_SH], 1);
        __syncthreads();
        for (int i = threadIdx.x; i < NSG; i += 256) {
            cntarr[bid * NSG + i] = cnt[i];
            if (cnt[i]) atomicAdd(&sgtot[i], cnt[i]);
        }
    } else {
        int idx = (bid - nchunks) * 256 + threadIdx.x;
        if (idx >= N_NODES_C * 64) return;
        const int split = N_USERS * 64;
        float x = (idx < split) ? uw[idx] : ew[idx - split];
        _Float16 hx = (_Float16)x;
        fb[idx] = *(unsigned short*)&hx;
    }
}

// ---------- single small scan: sgoff + cursor init ----------
__global__ __launch_bounds__(512) void scan_k(const int* __restrict__ sgtot,
                                              int* __restrict__ sgoff,
                                              int* __restrict__ sgcur)
{
    __shared__ int part[512];
    int t = threadIdx.x;
    int v = (t < NSG) ? sgtot[t] : 0;
    part[t] = v;
    __syncthreads();
    for (int off = 1; off < 512; off <<= 1) {
        int w = (t >= off) ? part[t - off] : 0;
        __syncthreads();
        part[t] += w;
        __syncthreads();
    }
    if (t < NSG) { sgoff[t] = part[t] - v; sgcur[t] = part[t] - v; }
    if (t == NSG - 1) sgoff[NSG] = part[t];          // total = n_edges
}

// ---------- pass B: LDS sg-sort + cursor-allocated scatter to tmp2 ----------
// Histogram comes from cntarr (built by prep_k) — no target re-read in phase 1.
__global__ __launch_bounds__(256) void scatter_k(
    const int* __restrict__ target, const int* __restrict__ neighbor,
    const float* __restrict__ values, const int* __restrict__ cntarr,
    int* __restrict__ sgcur, uint2* __restrict__ tmp2, int n_edges)
{
    __shared__ uint2 buf[CHUNK];            // 57.3 KB
    __shared__ int cnt[NSG], off[NSG], pos[NSG], gbase[NSG];
    int c = blockIdx.x;
    int base = c * CHUNK;
    int ccount = min(CHUNK, n_edges - base);
    for (int i = threadIdx.x; i < NSG; i += 256) {
        int v = cntarr[c * NSG + i];
        cnt[i] = v;
        pos[i] = 0;
        gbase[i] = 0;
    }
    __syncthreads();
    // allocate this chunk's run for each sg on the global cursor
    for (int i = threadIdx.x; i < NSG; i += 256)
        if (cnt[i]) gbase[i] = atomicAdd(&sgcur[i], cnt[i]);
    if (threadIdx.x < 64) {                 // wave-0 exclusive scan of cnt
        int l = threadIdx.x;
        const int PER = (NSG + 63) / 64;    // 7
        int s0 = l * PER, s1 = min(s0 + PER, NSG);
        int sum = 0;
        for (int i = s0; i < s1; i++) sum += cnt[i];
        int run = sum;
        #pragma unroll
        for (int o = 1; o < 64; o <<= 1) { int v = __shfl_up(run, o); if (l >= o) run += v; }
        int excl = run - sum;
        for (int i = s0; i < s1; i++) { off[i] = excl; excl += cnt[i]; }
    }
    __syncthreads();
    for (int i = threadIdx.x; i < ccount; i += 256) {
        int t  = target[base + i];
        int sg = t >> SG_SH;
        unsigned q = (unsigned)fminf(values[base + i] * 16384.f + 0.5f, 16383.f);
        unsigned w = ((unsigned)neighbor[base + i] << 14) | q;
        int p = off[sg] + atomicAdd(&pos[sg], 1);
        buf[p] = make_uint2(w, (unsigned)t);
    }
    __syncthreads();
    // buf is sg-sorted: run for sg occupies [off[sg], off[sg]+cnt[sg]).
    // Write each run to its cursor-allocated global slot (coalesced within run).
    for (int i = threadIdx.x; i < ccount; i += 256) {
        uint2 ed = buf[i];
        int sg = (int)(ed.y >> SG_SH);
        tmp2[(size_t)(gbase[sg] + (i - off[sg]))] = ed;
    }
}

// ---------- stage 2: per-supergroup node-level CSR build (coalesced reads) ----------
__global__ __launch_bounds__(512) void sort2_k(
    const uint2* __restrict__ tmp2, const int* __restrict__ sgoff,
    int* __restrict__ row_ptr, unsigned* __restrict__ edges)
{
    __shared__ int cnt[512];
    __shared__ int cur[512];
    __shared__ int rp[513];
    int s = blockIdx.x;
    int node0 = s << SG_SH;
    int nn = min(512, N_NODES_C - node0);
    int sgstart = sgoff[s];
    int sgcnt = sgoff[s + 1] - sgstart;
    cnt[threadIdx.x] = 0;
    cur[threadIdx.x] = 0;
    __syncthreads();
    // pass 1: count per node (coalesced segment read)
    for (int e = threadIdx.x; e < sgcnt; e += 512)
        atomicAdd(&cnt[tmp2[(size_t)sgstart + e].y & 511u], 1);
    __syncthreads();
    if (threadIdx.x < 64) {                 // wave-0 exclusive scan of cnt[512]
        int l = threadIdx.x;
        int s0 = l * 8;
        int vals[8];
        int sum = 0;
        for (int i = 0; i < 8; i++) { vals[i] = cnt[s0 + i]; sum += vals[i]; }
        int run = sum;
        #pragma unroll
        for (int o = 1; o < 64; o <<= 1) { int v = __shfl_up(run, o); if (l >= o) run += v; }
        int excl = run - sum;
        for (int i = 0; i < 8; i++) { rp[s0 + i] = excl; excl += vals[i]; }
        if (l == 63) rp[512] = excl;
    }
    __syncthreads();
    for (int i = threadIdx.x; i < nn; i += 512) row_ptr[node0 + i] = sgstart + rp[i];
    if (s == NSG - 1 && threadIdx.x == 0) row_ptr[N_NODES_C] = sgstart + sgcnt;
    // pass 2: place (re-read is L2-hot)
    for (int e = threadIdx.x; e < sgcnt; e += 512) {
        uint2 ed = tmp2[(size_t)sgstart + e];
        int tl = (int)(ed.y & 511u);
        int old = atomicAdd(&cur[tl], 1);
        edges[sgstart + rp[tl] + old] = ed.x;
    }
}

// ---------- layer 1: quad-node gather pull (f16 pk_fma) + MFMA f16 transform ----------
// SPS=136 REQUIRED: each row holds 128 f16 k-values (64 sum + 64 product path).
// 4 streams is the proven ILP ceiling (r7: 8 streams spilled to scratch).
// ONE dispatch (r9: splitting a near-fit grid adds scheduling tails).
#define SPS 136
__global__ __launch_bounds__(512, 6) void layer1_pull_k(
    const unsigned short* __restrict__ fb,
    const int* __restrict__ row_ptr, const unsigned int* __restrict__ edges,
    const float* __restrict__ W1, const float* __restrict__ b1,
    const float* __restrict__ W2, const float* __restrict__ b2,
    _Float16* __restrict__ h1out, int n_nodes)
{
    __shared__ __align__(16) short wt[64 * SPS];    // 17.4 KB
    __shared__ __align__(16) short sp[128 * SPS];   // 34.8 KB
    __shared__ float sbias[64];

    for (int idx = threadIdx.x; idx < 64 * 64; idx += 512) {
        int kp = idx >> 6;
        int n  = idx & 63;
        int k0 = kp * 2, k1 = k0 + 1;
        float w0 = (k0 < 64) ? W1[k0 * 64 + n] : W2[(k0 - 64) * 64 + n];
        float w1 = (k1 < 64) ? W1[k1 * 64 + n] : W2[(k1 - 64) * 64 + n];
        *(unsigned*)&wt[n * SPS + k0] = pk2h(w0, w1);
    }
    if (threadIdx.x < 64) sbias[threadIdx.x] = b1[threadIdx.x] + b2[threadIdx.x];
    __syncthreads();

    int wv   = threadIdx.x >> 6;
    int lane = threadIdx.x & 63;
    int g    = lane >> 4;
    int q    = lane & 15;
    const uint2* fb2 = (const uint2*)fb;

    int nb0 = blockIdx.x * 128;
    const float QS = 1.f / 16384.f;

    for (int i = 0; i < 16; i += 4) {
        int mA = wv * 16 + i;
        int nodeBase = nb0 + mA;

        int es0 = 0, ee0 = 0, es1 = 0, ee1 = 0, es2 = 0, ee2 = 0, es3 = 0, ee3 = 0;
        if (nodeBase     < n_nodes) { es0 = row_ptr[nodeBase];     ee0 = row_ptr[nodeBase + 1]; }
        if (nodeBase + 1 < n_nodes) { es1 = row_ptr[nodeBase + 1]; ee1 = row_ptr[nodeBase + 2]; }
        if (nodeBase + 2 < n_nodes) { es2 = row_ptr[nodeBase + 2]; ee2 = row_ptr[nodeBase + 3]; }
        if (nodeBase + 3 < n_nodes) { es3 = row_ptr[nodeBase + 3]; ee3 = row_ptr[nodeBase + 4]; }

        h2 aLo0 = (h2){0, 0}, aHi0 = (h2){0, 0};
        h2 aLo1 = (h2){0, 0}, aHi1 = (h2){0, 0};
        h2 aLo2 = (h2){0, 0}, aHi2 = (h2){0, 0};
        h2 aLo3 = (h2){0, 0}, aHi3 = (h2){0, 0};

        int b0 = es0, b1c = es1, b2c = es2, b3c = es3;
        while (b0 < ee0 || b1c < ee1 || b2c < ee2 || b3c < ee3) {
            int c0 = ee0 - b0;  c0 = c0 < 0 ? 0 : (c0 > 64 ? 64 : c0);
            int c1 = ee1 - b1c; c1 = c1 < 0 ? 0 : (c1 > 64 ? 64 : c1);
            int c2 = ee2 - b2c; c2 = c2 < 0 ? 0 : (c2 > 64 ? 64 : c2);
            int c3 = ee3 - b3c; c3 = c3 < 0 ? 0 : (c3 > 64 ? 64 : c3);
            unsigned ev0 = (lane < c0) ? edges[b0 + lane]  : 0u;
            unsigned ev1 = (lane < c1) ? edges[b1c + lane] : 0u;
            unsigned ev2 = (lane < c2) ? edges[b2c + lane] : 0u;
            unsigned ev3 = (lane < c3) ? edges[b3c + lane] : 0u;
            int jm0 = (c0 + 3) >> 2;
            int jm1 = (c1 + 3) >> 2;
            int jm2 = (c2 + 3) >> 2;
            int jm3 = (c3 + 3) >> 2;
            int jm = max(max(jm0, jm1), max(jm2, jm3));
            #pragma unroll 4
            for (int j = 0; j < jm; j++) {
                // lanes beyond a stream's count loaded 0 -> shfl yields w=0 -> v=0
                unsigned w0 = (unsigned)__shfl((int)ev0, j * 4 + g);
                unsigned w1 = (unsigned)__shfl((int)ev1, j * 4 + g);
                unsigned w2 = (unsigned)__shfl((int)ev2, j * 4 + g);
                unsigned w3 = (unsigned)__shfl((int)ev3, j * 4 + g);
                uint2 d0 = fb2[(size_t)(w0 >> 14) * 16 + q];
                uint2 d1 = fb2[(size_t)(w1 >> 14) * 16 + q];
                uint2 d2 = fb2[(size_t)(w2 >> 14) * 16 + q];
                uint2 d3 = fb2[(size_t)(w3 >> 14) * 16 + q];
                _Float16 v0 = (_Float16)((float)(w0 & 16383u) * QS);
                _Float16 v1 = (_Float16)((float)(w1 & 16383u) * QS);
                _Float16 v2 = (_Float16)((float)(w2 & 16383u) * QS);
                _Float16 v3 = (_Float16)((float)(w3 & 16383u) * QS);
                h2 vv0 = (h2){v0, v0};
                h2 vv1 = (h2){v1, v1};
                h2 vv2 = (h2){v2, v2};
                h2 vv3 = (h2){v3, v3};
                aLo0 += u2h(d0.x) * vv0;  aHi0 += u2h(d0.y) * vv0;
                aLo1 += u2h(d1.x) * vv1;  aHi1 += u2h(d1.y) * vv1;
                aLo2 += u2h(d2.x) * vv2;  aHi2 += u2h(d2.y) * vv2;
                aLo3 += u2h(d3.x) * vv3;  aHi3 += u2h(d3.y) * vv3;
            }
            b0 += 64; b1c += 64; b2c += 64; b3c += 64;
        }

        float ac[4][4];
        ac[0][0] = (float)aLo0.x; ac[0][1] = (float)aLo0.y; ac[0][2] = (float)aHi0.x; ac[0][3] = (float)aHi0.y;
        ac[1][0] = (float)aLo1.x; ac[1][1] = (float)aLo1.y; ac[1][2] = (float)aHi1.x; ac[1][3] = (float)aHi1.y;
        ac[2][0] = (float)aLo2.x; ac[2][1] = (float)aLo2.y; ac[2][2] = (float)aHi2.x; ac[2][3] = (float)aHi2.y;
        ac[3][0] = (float)aLo3.x; ac[3][1] = (float)aLo3.y; ac[3][2] = (float)aHi3.x; ac[3][3] = (float)aHi3.y;
        // reduce across the 4 lane-groups (bits 4,5 of lane id) in f32
        #pragma unroll
        for (int s = 0; s < 4; s++)
            #pragma unroll
            for (int c = 0; c < 4; c++) {
                ac[s][c] += __shfl_xor(ac[s][c], 16);
                ac[s][c] += __shfl_xor(ac[s][c], 32);
            }

        // epilogue: g pairs -> (row-pair, sum/product path); all 4 groups busy
        int hseg = g >> 1;
        int prod = g & 1;
        int r0 = mA + (hseg << 1);
        int r1 = r0 + 1;
        int nd0 = nb0 + r0, nd1 = nb0 + r1;
        uint2 d0 = make_uint2(0u, 0u), d1 = make_uint2(0u, 0u);
        if (nd0 < n_nodes) d0 = fb2[(size_t)nd0 * 16 + q];
        if (nd1 < n_nodes) d1 = fb2[(size_t)nd1 * 16 + q];
        float a00 = hseg ? ac[2][0] : ac[0][0];
        float a01 = hseg ? ac[2][1] : ac[0][1];
        float a02 = hseg ? ac[2][2] : ac[0][2];
        float a03 = hseg ? ac[2][3] : ac[0][3];
        float a10 = hseg ? ac[3][0] : ac[1][0];
        float a11 = hseg ? ac[3][1] : ac[1][1];
        float a12 = hseg ? ac[3][2] : ac[1][2];
        float a13 = hseg ? ac[3][3] : ac[1][3];
        h2 s0l = u2h(d0.x), s0h = u2h(d0.y);
        h2 s1l = u2h(d1.x), s1h = u2h(d1.y);
        float f00 = (float)s0l.x, f01 = (float)s0l.y, f02 = (float)s0h.x, f03 = (float)s0h.y;
        float f10 = (float)s1l.x, f11 = (float)s1l.y, f12 = (float)s1h.x, f13 = (float)s1h.y;
        float x00 = prod ? f00 * a00 : f00 + a00;
        float x01 = prod ? f01 * a01 : f01 + a01;
        float x02 = prod ? f02 * a02 : f02 + a02;
        float x03 = prod ? f03 * a03 : f03 + a03;
        float x10 = prod ? f10 * a10 : f10 + a10;
        float x11 = prod ? f11 * a11 : f11 + a11;
        float x12 = prod ? f12 * a12 : f12 + a12;
        float x13 = prod ? f13 * a13 : f13 + a13;
        uint2 pk;
        pk.x = pk2h(x00, x01);
        pk.y = pk2h(x02, x03);
        *(uint2*)&sp[r0 * SPS + prod * 64 + q * 4] = pk;
        pk.x = pk2h(x10, x11);
        pk.y = pk2h(x12, x13);
        *(uint2*)&sp[r1 * SPS + prod * 64 + q * 4] = pk;
    }

    // sp rows are wave-private: drain this wave's LDS writes only (no block barrier)
    __builtin_amdgcn_wave_barrier();
    asm volatile("s_waitcnt lgkmcnt(0)" ::: "memory");
    __builtin_amdgcn_wave_barrier();

    float4v c0, c1, c2, c3;
    {
        float bv0 = sbias[q];
        float bv1 = sbias[16 + q];
        float bv2 = sbias[32 + q];
        float bv3 = sbias[48 + q];
        c0 = (float4v){bv0, bv0, bv0, bv0};
        c1 = (float4v){bv1, bv1, bv1, bv1};
        c2 = (float4v){bv2, bv2, bv2, bv2};
        c3 = (float4v){bv3, bv3, bv3, bv3};
    }
    #pragma unroll
    for (int kk = 0; kk < 4; kk++) {
        int ko = kk * 32 + g * 8;
        half8 a   = *(const half8*)&sp[(wv * 16 + q) * SPS + ko];
        half8 bb0 = *(const half8*)&wt[(q)      * SPS + ko];
        half8 bb1 = *(const half8*)&wt[(16 + q) * SPS + ko];
        half8 bb2 = *(const half8*)&wt[(32 + q) * SPS + ko];
        half8 bb3 = *(const half8*)&wt[(48 + q) * SPS + ko];
        c0 = __builtin_amdgcn_mfma_f32_16x16x32_f16(a, bb0, c0, 0, 0, 0);
        c1 = __builtin_amdgcn_mfma_f32_16x16x32_f16(a, bb1, c1, 0, 0, 0);
        c2 = __builtin_amdgcn_mfma_f32_16x16x32_f16(a, bb2, c2, 0, 0, 0);
        c3 = __builtin_amdgcn_mfma_f32_16x16x32_f16(a, bb3, c3, 0, 0, 0);
    }

    float ss[4];
    #pragma unroll
    for (int r = 0; r < 4; r++) {
        c0[r] = (c0[r] > 0.f) ? c0[r] : 0.01f * c0[r];
        c1[r] = (c1[r] > 0.f) ? c1[r] : 0.01f * c1[r];
        c2[r] = (c2[r] > 0.f) ? c2[r] : 0.01f * c2[r];
        c3[r] = (c3[r] > 0.f) ? c3[r] : 0.01f * c3[r];
        ss[r] = c0[r]*c0[r] + c1[r]*c1[r] + c2[r]*c2[r] + c3[r]*c3[r];
        #pragma unroll
        for (int mm = 1; mm < 16; mm <<= 1) ss[r] += __shfl_xor(ss[r], mm);
        ss[r] = 1.f / fmaxf(sqrtf(ss[r]), 1e-12f);
    }
    #pragma unroll
    for (int r = 0; r < 4; r++) {
        int node_r = nb0 + wv * 16 + g * 4 + r;
        if (node_r >= n_nodes) continue;
        size_t row = (size_t)node_r * 64;
        h1out[row +      q] = (_Float16)(c0[r] * ss[r]);
        h1out[row + 16 + q] = (_Float16)(c1[r] * ss[r]);
        h1out[row + 32 + q] = (_Float16)(c2[r] * ss[r]);
        h1out[row + 48 + q] = (_Float16)(c3[r] * ss[r]);
    }
}

// ---------- inline layer2 (64->32) for one node ----------
__device__ __forceinline__ float layer2_row(
    const _Float16* __restrict__ h1,
    const int* __restrict__ row_ptr, const unsigned int* __restrict__ edges,
    const float* sW1, const float* sW2, const float* sb,
    int node, int lane)
{
    int es = row_ptr[node];
    int ee = row_ptr[node + 1];
    const float QS = 1.f / 16384.f;
    float g = 0.f;
    for (int base = es; base < ee; base += 64) {
        int cnt = min(64, ee - base);
        unsigned ev = (lane < cnt) ? edges[base + lane] : 0u;
        int j = 0;
        for (; j + 4 <= cnt; j += 4) {
            unsigned e0 = (unsigned)__shfl((int)ev, j);
            unsigned e1 = (unsigned)__shfl((int)ev, j + 1);
            unsigned e2 = (unsigned)__shfl((int)ev, j + 2);
            unsigned e3 = (unsigned)__shfl((int)ev, j + 3);
            float f0 = (float)h1[(size_t)(e0 >> 14) * 64 + lane];
            float f1 = (float)h1[(size_t)(e1 >> 14) * 64 + lane];
            float f2 = (float)h1[(size_t)(e2 >> 14) * 64 + lane];
            float f3 = (float)h1[(size_t)(e3 >> 14) * 64 + lane];
            g += (float)(e0 & 16383u) * QS * f0 + (float)(e1 & 16383u) * QS * f1
               + (float)(e2 & 16383u) * QS * f2 + (float)(e3 & 16383u) * QS * f3;
        }
        for (; j < cnt; j++) {
            unsigned e0 = (unsigned)__shfl((int)ev, j);
            float f0 = (float)h1[(size_t)(e0 >> 14) * 64 + lane];
            g += (float)(e0 & 16383u) * QS * f0;
        }
    }
    float f = (float)h1[(size_t)node * 64 + lane];
    float s = f + g;
    float p = f * g;
    int j = lane & 31;
    float acc = sb[j];
    #pragma unroll
    for (int k = 0; k < 64; k++) {
        float sk = __shfl(s, k);
        float pk = __shfl(p, k);
        acc += sk * sW1[k * 32 + j] + pk * sW2[k * 32 + j];
    }
    acc = (acc > 0.f) ? acc : 0.01f * acc;
    float sq = acc * acc;
    #pragma unroll
    for (int m = 1; m < 32; m <<= 1) sq += __shfl_xor(sq, m);
    return acc / fmaxf(sqrtf(sq), 1e-12f);
}

__global__ __launch_bounds__(256) void score_k(
    const float* __restrict__ uw, const float* __restrict__ ew,
    const _Float16* __restrict__ h1,
    const int* __restrict__ row_ptr, const unsigned int* __restrict__ edges,
    const float* __restrict__ W1b, const float* __restrict__ b1b,
    const float* __restrict__ W2b, const float* __restrict__ b2b,
    const int* __restrict__ uid, const int* __restrict__ pid,
    const int* __restrict__ nid, float* __restrict__ out)
{
    __shared__ float sW1[64 * 32];
    __shared__ float sW2[64 * 32];
    __shared__ float sb[32];
    for (int i = threadIdx.x; i < 64 * 32; i += 256) { sW1[i] = W1b[i]; sW2[i] = W2b[i]; }
    if (threadIdx.x < 32) sb[threadIdx.x] = b1b[threadIdx.x] + b2b[threadIdx.x];
    __syncthreads();

    int wave = threadIdx.x >> 6;
    int lane = threadIdx.x & 63;
    int i = blockIdx.x * 4 + wave;
    if (i >= BATCH_C) return;

    int un = uid[i];
    int pe = pid[i];
    int ne = nid[i];
    int pn = N_USERS + pe;
    int nn = N_USERS + ne;

    float acc01p, acc01n;
    {
        float u  = uw[(size_t)un * 64 + lane];
        float pv = ew[(size_t)pe * 64 + lane];
        float nv = ew[(size_t)ne * 64 + lane];
        acc01p = u * pv;
        acc01n = u * nv;
        float u1 = (float)h1[(size_t)un * 64 + lane];
        acc01p += u1 * (float)h1[(size_t)pn * 64 + lane];
        acc01n += u1 * (float)h1[(size_t)nn * 64 + lane];
    }

    float h2u = layer2_row(h1, row_ptr, edges, sW1, sW2, sb, un, lane);
    float h2p = layer2_row(h1, row_ptr, edges, sW1, sW2, sb, pn, lane);
    float h2n = layer2_row(h1, row_ptr, edges, sW1, sW2, sb, nn, lane);
    float p2 = h2u * h2p;
    float n2 = h2u * h2n;
    #pragma unroll
    for (int m = 1; m < 32; m <<= 1) { p2 += __shfl_xor(p2, m); n2 += __shfl_xor(n2, m); }

    #pragma unroll
    for (int m = 1; m < 64; m <<= 1) { acc01p += __shfl_xor(acc01p, m); acc01n += __shfl_xor(acc01n, m); }

    if (lane == 0) {
        out[i]           = acc01p + p2;
        out[BATCH_C + i] = acc01n + n2;
    }
}

extern "C" void kernel_launch(void* const* d_in, const int* in_sizes, int n_in,
                              void* d_out, int out_size, void* d_ws, size_t ws_size,
                              hipStream_t stream) {
    const float* uw   = (const float*)d_in[0];
    const float* ew   = (const float*)d_in[1];
    const float* W1a  = (const float*)d_in[2];
    const float* b1a  = (const float*)d_in[3];
    const float* W2a  = (const float*)d_in[4];
    const float* b2a  = (const float*)d_in[5];
    const float* W1b  = (const float*)d_in[6];
    const float* b1b  = (const float*)d_in[7];
    const float* W2b  = (const float*)d_in[8];
    const float* b2b  = (const float*)d_in[9];
    const float* values   = (const float*)d_in[10];
    const int*   target   = (const int*)d_in[11];
    const int*   neighbor = (const int*)d_in[12];
    const int*   uid  = (const int*)d_in[13];
    const int*   pid  = (const int*)d_in[14];
    const int*   nid  = (const int*)d_in[15];

    const int n_edges = in_sizes[10];

    char* ws = (char*)d_ws;
    int*  row_ptr    = (int*)ws;   ws += 801792;
    int*  cntarr     = (int*)ws;   ws += 704512;          // 448*391*4 = 700672
    int*  sgtot      = (int*)ws;   ws += 4096;
    int*  sgoff      = (int*)ws;   ws += 4096;
    int*  sgcur      = (int*)ws;   ws += 4096;
    unsigned int*   edges = (unsigned int*)ws;   ws += (size_t)N_EDGES_C * 4;      // 12.8 MB
    unsigned short* fb    = (unsigned short*)ws; ws += (size_t)N_NODES_C * 64 * 2; // 25.6 MB
    uint2*          tmp2  = (uint2*)ws;                   // aliased with h1
    _Float16*       h1    = (_Float16*)ws;                // region 25.69 MB

    const int layer_blocks = (N_NODES_C + 127) / 128;     // 1563
    const int conv_blocks  = (N_NODES_C * 64 + 255) / 256;
    const int nchunks      = (n_edges + CHUNK - 1) / CHUNK;   // 447

    // ----- zero sg totals (async memset instead of a kernel launch) -----
    hipMemsetAsync(sgtot, 0, (NSG + 1) * sizeof(int), stream);

    // ----- fused prep: edge sg-histogram (+cntarr, +sgtot) ∥ f16 feature table -----
    prep_k<<<nchunks + conv_blocks, 256, 0, stream>>>(uw, ew, fb, target,
                                                      cntarr, sgtot, n_edges, nchunks);

    // ----- edge sort + CSR build -----
    scan_k<<<1, 512, 0, stream>>>(sgtot, sgoff, sgcur);
    scatter_k<<<nchunks, 256, 0, stream>>>(target, neighbor, values, cntarr, sgcur, tmp2, n_edges);
    sort2_k<<<NSG, 512, 0, stream>>>(tmp2, sgoff, row_ptr, edges);

    // ----- layer 1 (quad-node pull + MFMA transform, f16; single dispatch) -----
    layer1_pull_k<<<layer_blocks, 512, 0, stream>>>(fb, row_ptr, edges,
                                                    W1a, b1a, W2a, b2a, h1, N_NODES_C);

    // ----- scoring (layer-2 aggregation + transform inline, ~12K nodes) -----
    score_k<<<BATCH_C / 4, 256, 0, stream>>>(uw, ew, h1, row_ptr, edges,
                                             W1b, b1b, W2b, b2b,
                                             uid, pid, nid, (float*)d_out);
}

// Round 11
// 335.153 us; speedup vs baseline: 1.8074x; 1.0348x over previous
//
#include <hip/hip_runtime.h>

#define N_USERS    50000
#define N_ENTITIES 150000
#define N_NODES_C  200000
#define BATCH_C    4096
#define N_EDGES_C  3200000

// edge sort params
#define CHUNK   7168            // edges per scatter block (LDS 57.3 KB buf)
#define SG_SH   9               // supergroup = 512 nodes
#define NSG     391             // ceil(200000/512)
#define S2CAP   12288           // sort2 LDS edge cap (mean 8192, sigma~90)

typedef __attribute__((ext_vector_type(2))) _Float16 h2;
typedef __attribute__((ext_vector_type(8))) _Float16 half8;
typedef __attribute__((ext_vector_type(2))) __fp16 fp16x2_s;   // builtin return type
typedef __attribute__((ext_vector_type(4))) float float4v;

// Workspace (~67 MB; proven safe < 76.8 MB):
//   row_ptr : int [200001+pad]      0.80 MB
//   cntarr  : int [448*391]         0.70 MB   (per-chunk per-sg counts, from prep_k)
//   sgtot   : int [512]             2 KB      (global per-sg totals; memset+atomics)
//   sgoff   : int [512]             2 KB      (supergroup global starts)
//   sgcur   : int [512]             2 KB      (allocation cursor per sg)
//   edges   : uint [3.2M]          12.8 MB    (nb<<14 | f16bits(val), node-sorted CSR)
//   fb16    : ushort[200000*64]    25.6 MB    (f16 node features)
//   region  : 25.69 MB — tmp2 (uint2 sg-sorted edges) then h1 (f16 layer-1 out)
// Edge word: val in [0,1) => f16 bit pattern < 0x4000 fits in 14 bits.
//   Unpack is v_and + v_lshl_or (2 ops) vs and+cvt+mul+cvt (4-5 ops).
// Lessons: (r6) scattered 4B placement = 16x write amplification -> LDS staging;
// (r7) >4 gather streams spill to scratch -> 4 streams max; (r9) don't split
// near-exact-fit dispatches; (r10) cross-session clock variance ~13% -> use
// layer1 dur as internal reference.

__device__ __forceinline__ h2 u2h(unsigned u) {
    union { unsigned u; h2 h; } x; x.u = u; return x.h;
}
__device__ __forceinline__ unsigned pk2h(float a, float b) {
    union { fp16x2_s h; unsigned u; } x;
    x.h = __builtin_amdgcn_cvt_pkrtz(a, b);
    return x.u;
}
__device__ __forceinline__ float val_f32(unsigned e) {   // low-14-bit f16 -> f32
    union { unsigned short s; _Float16 h; } x;
    x.s = (unsigned short)(e & 0x3FFFu);
    return (float)x.h;
}

// ---------- fused prep: blocks [0,nchunks) = per-chunk sg histogram;
//            blocks [nchunks, nchunks+CONVB) = f32->f16 convert, 8 elems/thread ----------
#define CONVB 6250              // 200000*64 / (256*8)
__global__ __launch_bounds__(256) void prep_k(const float* __restrict__ uw,
                                              const float* __restrict__ ew,
                                              unsigned short* __restrict__ fb,
                                              const int* __restrict__ target,
                                              int* __restrict__ cntarr,
                                              int* __restrict__ sgtot,
                                              int n_edges, int nchunks)
{
    __shared__ int cnt[NSG];
    int bid = blockIdx.x;
    if (bid < nchunks) {
        int base = bid * CHUNK;
        int ccount = min(CHUNK, n_edges - base);
        for (int i = threadIdx.x; i < NSG; i += 256) cnt[i] = 0;
        __syncthreads();
        for (int i = threadIdx.x; i < ccount; i += 256)
            atomicAdd(&cnt[target[base + i] >> SG_SH], 1);
        __syncthreads();
        for (int i = threadIdx.x; i < NSG; i += 256) {
            cntarr[bid * NSG + i] = cnt[i];
            if (cnt[i]) atomicAdd(&sgtot[i], cnt[i]);
        }
    } else {
        // 8 f32 -> 8 f16 per thread; split (3.2M) is 8-aligned so no straddle
        int base8 = ((bid - nchunks) * 256 + threadIdx.x) * 8;
        const int split = N_USERS * 64;
        const float* src = (base8 < split) ? (uw + base8) : (ew + (base8 - split));
        float4 a = *(const float4*)src;
        float4 b = *(const float4*)(src + 4);
        uint4 o;
        o.x = pk2h(a.x, a.y);
        o.y = pk2h(a.z, a.w);
        o.z = pk2h(b.x, b.y);
        o.w = pk2h(b.z, b.w);
        *(uint4*)(fb + base8) = o;
    }
}

// ---------- single small scan: sgoff + cursor init ----------
__global__ __launch_bounds__(512) void scan_k(const int* __restrict__ sgtot,
                                              int* __restrict__ sgoff,
                                              int* __restrict__ sgcur)
{
    __shared__ int part[512];
    int t = threadIdx.x;
    int v = (t < NSG) ? sgtot[t] : 0;
    part[t] = v;
    __syncthreads();
    for (int off = 1; off < 512; off <<= 1) {
        int w = (t >= off) ? part[t - off] : 0;
        __syncthreads();
        part[t] += w;
        __syncthreads();
    }
    if (t < NSG) { sgoff[t] = part[t] - v; sgcur[t] = part[t] - v; }
    if (t == NSG - 1) sgoff[NSG] = part[t];          // total = n_edges
}

// ---------- pass B: LDS sg-sort + cursor-allocated scatter to tmp2 ----------
// Histogram comes from cntarr (built by prep_k) — no target re-read in phase 1.
__global__ __launch_bounds__(256) void scatter_k(
    const int* __restrict__ target, const int* __restrict__ neighbor,
    const float* __restrict__ values, const int* __restrict__ cntarr,
    int* __restrict__ sgcur, uint2* __restrict__ tmp2, int n_edges)
{
    __shared__ uint2 buf[CHUNK];            // 57.3 KB
    __shared__ int cnt[NSG], off[NSG], pos[NSG], gbase[NSG];
    int c = blockIdx.x;
    int base = c * CHUNK;
    int ccount = min(CHUNK, n_edges - base);
    for (int i = threadIdx.x; i < NSG; i += 256) {
        int v = cntarr[c * NSG + i];
        cnt[i] = v;
        pos[i] = 0;
        gbase[i] = 0;
    }
    __syncthreads();
    // allocate this chunk's run for each sg on the global cursor
    for (int i = threadIdx.x; i < NSG; i += 256)
        if (cnt[i]) gbase[i] = atomicAdd(&sgcur[i], cnt[i]);
    if (threadIdx.x < 64) {                 // wave-0 exclusive scan of cnt
        int l = threadIdx.x;
        const int PER = (NSG + 63) / 64;    // 7
        int s0 = l * PER, s1 = min(s0 + PER, NSG);
        int sum = 0;
        for (int i = s0; i < s1; i++) sum += cnt[i];
        int run = sum;
        #pragma unroll
        for (int o = 1; o < 64; o <<= 1) { int v = __shfl_up(run, o); if (l >= o) run += v; }
        int excl = run - sum;
        for (int i = s0; i < s1; i++) { off[i] = excl; excl += cnt[i]; }
    }
    __syncthreads();
    for (int i = threadIdx.x; i < ccount; i += 256) {
        int t  = target[base + i];
        int sg = t >> SG_SH;
        // pack val as raw f16 bits (val in [0,1) -> fits 14 bits)
        _Float16 hv = (_Float16)values[base + i];
        unsigned short hb;
        __builtin_memcpy(&hb, &hv, 2);
        unsigned w = ((unsigned)neighbor[base + i] << 14) | (unsigned)(hb & 0x3FFFu);
        int p = off[sg] + atomicAdd(&pos[sg], 1);
        buf[p] = make_uint2(w, (unsigned)t);
    }
    __syncthreads();
    // buf is sg-sorted: run for sg occupies [off[sg], off[sg]+cnt[sg]).
    // Write each run to its cursor-allocated global slot (coalesced within run).
    for (int i = threadIdx.x; i < ccount; i += 256) {
        uint2 ed = buf[i];
        int sg = (int)(ed.y >> SG_SH);
        tmp2[(size_t)(gbase[sg] + (i - off[sg]))] = ed;
    }
}

// ---------- stage 2: per-supergroup node-level CSR build (single tmp2 read) ----------
__global__ __launch_bounds__(512) void sort2_k(
    const uint2* __restrict__ tmp2, const int* __restrict__ sgoff,
    int* __restrict__ row_ptr, unsigned* __restrict__ edges)
{
    __shared__ unsigned ebuf[S2CAP];        // 49.2 KB
    __shared__ unsigned short tbuf[S2CAP];  // 24.6 KB
    __shared__ int cnt[512];
    __shared__ int cur[512];
    __shared__ int rp[513];
    int s = blockIdx.x;
    int node0 = s << SG_SH;
    int nn = min(512, N_NODES_C - node0);
    int sgstart = sgoff[s];
    int sgcnt = sgoff[s + 1] - sgstart;
    cnt[threadIdx.x] = 0;
    cur[threadIdx.x] = 0;
    __syncthreads();
    // pass 1: count per node + buffer segment in LDS (coalesced single read)
    for (int e = threadIdx.x; e < sgcnt; e += 512) {
        uint2 ed = tmp2[(size_t)sgstart + e];
        int tl = (int)(ed.y & 511u);
        atomicAdd(&cnt[tl], 1);
        if (e < S2CAP) { ebuf[e] = ed.x; tbuf[e] = (unsigned short)tl; }
    }
    __syncthreads();
    if (threadIdx.x < 64) {                 // wave-0 exclusive scan of cnt[512]
        int l = threadIdx.x;
        int s0 = l * 8;
        int vals[8];
        int sum = 0;
        for (int i = 0; i < 8; i++) { vals[i] = cnt[s0 + i]; sum += vals[i]; }
        int run = sum;
        #pragma unroll
        for (int o = 1; o < 64; o <<= 1) { int v = __shfl_up(run, o); if (l >= o) run += v; }
        int excl = run - sum;
        for (int i = 0; i < 8; i++) { rp[s0 + i] = excl; excl += vals[i]; }
        if (l == 63) rp[512] = excl;
    }
    __syncthreads();
    for (int i = threadIdx.x; i < nn; i += 512) row_ptr[node0 + i] = sgstart + rp[i];
    if (s == NSG - 1 && threadIdx.x == 0) row_ptr[N_NODES_C] = sgstart + sgcnt;
    // pass 2: place from LDS
    int lim = min(sgcnt, S2CAP);
    for (int e = threadIdx.x; e < lim; e += 512) {
        int tl = tbuf[e];
        int old = atomicAdd(&cur[tl], 1);
        edges[sgstart + rp[tl] + old] = ebuf[e];
    }
    // rare overflow: re-read tmp2 for e >= S2CAP
    for (int e = S2CAP + threadIdx.x; e < sgcnt; e += 512) {
        uint2 ed = tmp2[(size_t)sgstart + e];
        int tl = (int)(ed.y & 511u);
        int old = atomicAdd(&cur[tl], 1);
        edges[sgstart + rp[tl] + old] = ed.x;
    }
}

// ---------- layer 1: quad-node gather pull (f16 pk_fma) + MFMA f16 transform ----------
// SPS=136 REQUIRED: each row holds 128 f16 k-values (64 sum + 64 product path).
// 4 streams is the proven ILP ceiling (r7). ONE dispatch (r9).
// val unpack: bits | bits<<16 -> h2 (2 VALU, no cvt chain).
#define SPS 136
__global__ __launch_bounds__(512, 6) void layer1_pull_k(
    const unsigned short* __restrict__ fb,
    const int* __restrict__ row_ptr, const unsigned int* __restrict__ edges,
    const float* __restrict__ W1, const float* __restrict__ b1,
    const float* __restrict__ W2, const float* __restrict__ b2,
    _Float16* __restrict__ h1out, int n_nodes)
{
    __shared__ __align__(16) short wt[64 * SPS];    // 17.4 KB
    __shared__ __align__(16) short sp[128 * SPS];   // 34.8 KB
    __shared__ float sbias[64];

    for (int idx = threadIdx.x; idx < 64 * 64; idx += 512) {
        int kp = idx >> 6;
        int n  = idx & 63;
        int k0 = kp * 2, k1 = k0 + 1;
        float w0 = (k0 < 64) ? W1[k0 * 64 + n] : W2[(k0 - 64) * 64 + n];
        float w1 = (k1 < 64) ? W1[k1 * 64 + n] : W2[(k1 - 64) * 64 + n];
        *(unsigned*)&wt[n * SPS + k0] = pk2h(w0, w1);
    }
    if (threadIdx.x < 64) sbias[threadIdx.x] = b1[threadIdx.x] + b2[threadIdx.x];
    __syncthreads();

    int wv   = threadIdx.x >> 6;
    int lane = threadIdx.x & 63;
    int g    = lane >> 4;
    int q    = lane & 15;
    const uint2* fb2 = (const uint2*)fb;

    int nb0 = blockIdx.x * 128;

    for (int i = 0; i < 16; i += 4) {
        int mA = wv * 16 + i;
        int nodeBase = nb0 + mA;

        int es0 = 0, ee0 = 0, es1 = 0, ee1 = 0, es2 = 0, ee2 = 0, es3 = 0, ee3 = 0;
        if (nodeBase     < n_nodes) { es0 = row_ptr[nodeBase];     ee0 = row_ptr[nodeBase + 1]; }
        if (nodeBase + 1 < n_nodes) { es1 = row_ptr[nodeBase + 1]; ee1 = row_ptr[nodeBase + 2]; }
        if (nodeBase + 2 < n_nodes) { es2 = row_ptr[nodeBase + 2]; ee2 = row_ptr[nodeBase + 3]; }
        if (nodeBase + 3 < n_nodes) { es3 = row_ptr[nodeBase + 3]; ee3 = row_ptr[nodeBase + 4]; }

        h2 aLo0 = (h2){0, 0}, aHi0 = (h2){0, 0};
        h2 aLo1 = (h2){0, 0}, aHi1 = (h2){0, 0};
        h2 aLo2 = (h2){0, 0}, aHi2 = (h2){0, 0};
        h2 aLo3 = (h2){0, 0}, aHi3 = (h2){0, 0};

        int b0 = es0, b1c = es1, b2c = es2, b3c = es3;
        while (b0 < ee0 || b1c < ee1 || b2c < ee2 || b3c < ee3) {
            int c0 = ee0 - b0;  c0 = c0 < 0 ? 0 : (c0 > 64 ? 64 : c0);
            int c1 = ee1 - b1c; c1 = c1 < 0 ? 0 : (c1 > 64 ? 64 : c1);
            int c2 = ee2 - b2c; c2 = c2 < 0 ? 0 : (c2 > 64 ? 64 : c2);
            int c3 = ee3 - b3c; c3 = c3 < 0 ? 0 : (c3 > 64 ? 64 : c3);
            unsigned ev0 = (lane < c0) ? edges[b0 + lane]  : 0u;
            unsigned ev1 = (lane < c1) ? edges[b1c + lane] : 0u;
            unsigned ev2 = (lane < c2) ? edges[b2c + lane] : 0u;
            unsigned ev3 = (lane < c3) ? edges[b3c + lane] : 0u;
            int jm0 = (c0 + 3) >> 2;
            int jm1 = (c1 + 3) >> 2;
            int jm2 = (c2 + 3) >> 2;
            int jm3 = (c3 + 3) >> 2;
            int jm = max(max(jm0, jm1), max(jm2, jm3));
            #pragma unroll 4
            for (int j = 0; j < jm; j++) {
                // lanes beyond a stream's count loaded 0 -> shfl yields w=0 -> v=0
                unsigned w0 = (unsigned)__shfl((int)ev0, j * 4 + g);
                unsigned w1 = (unsigned)__shfl((int)ev1, j * 4 + g);
                unsigned w2 = (unsigned)__shfl((int)ev2, j * 4 + g);
                unsigned w3 = (unsigned)__shfl((int)ev3, j * 4 + g);
                uint2 d0 = fb2[(size_t)(w0 >> 14) * 16 + q];
                uint2 d1 = fb2[(size_t)(w1 >> 14) * 16 + q];
                uint2 d2 = fb2[(size_t)(w2 >> 14) * 16 + q];
                uint2 d3 = fb2[(size_t)(w3 >> 14) * 16 + q];
                unsigned vb0 = w0 & 0x3FFFu;
                unsigned vb1 = w1 & 0x3FFFu;
                unsigned vb2 = w2 & 0x3FFFu;
                unsigned vb3 = w3 & 0x3FFFu;
                h2 vv0 = u2h(vb0 | (vb0 << 16));
                h2 vv1 = u2h(vb1 | (vb1 << 16));
                h2 vv2 = u2h(vb2 | (vb2 << 16));
                h2 vv3 = u2h(vb3 | (vb3 << 16));
                aLo0 += u2h(d0.x) * vv0;  aHi0 += u2h(d0.y) * vv0;
                aLo1 += u2h(d1.x) * vv1;  aHi1 += u2h(d1.y) * vv1;
                aLo2 += u2h(d2.x) * vv2;  aHi2 += u2h(d2.y) * vv2;
                aLo3 += u2h(d3.x) * vv3;  aHi3 += u2h(d3.y) * vv3;
            }
            b0 += 64; b1c += 64; b2c += 64; b3c += 64;
        }

        float ac[4][4];
        ac[0][0] = (float)aLo0.x; ac[0][1] = (float)aLo0.y; ac[0][2] = (float)aHi0.x; ac[0][3] = (float)aHi0.y;
        ac[1][0] = (float)aLo1.x; ac[1][1] = (float)aLo1.y; ac[1][2] = (float)aHi1.x; ac[1][3] = (float)aHi1.y;
        ac[2][0] = (float)aLo2.x; ac[2][1] = (float)aLo2.y; ac[2][2] = (float)aHi2.x; ac[2][3] = (float)aHi2.y;
        ac[3][0] = (float)aLo3.x; ac[3][1] = (float)aLo3.y; ac[3][2] = (float)aHi3.x; ac[3][3] = (float)aHi3.y;
        // reduce across the 4 lane-groups (bits 4,5 of lane id) in f32
        #pragma unroll
        for (int s = 0; s < 4; s++)
            #pragma unroll
            for (int c = 0; c < 4; c++) {
                ac[s][c] += __shfl_xor(ac[s][c], 16);
                ac[s][c] += __shfl_xor(ac[s][c], 32);
            }

        // epilogue: g pairs -> (row-pair, sum/product path); all 4 groups busy
        int hseg = g >> 1;
        int prod = g & 1;
        int r0 = mA + (hseg << 1);
        int r1 = r0 + 1;
        int nd0 = nb0 + r0, nd1 = nb0 + r1;
        uint2 d0 = make_uint2(0u, 0u), d1 = make_uint2(0u, 0u);
        if (nd0 < n_nodes) d0 = fb2[(size_t)nd0 * 16 + q];
        if (nd1 < n_nodes) d1 = fb2[(size_t)nd1 * 16 + q];
        float a00 = hseg ? ac[2][0] : ac[0][0];
        float a01 = hseg ? ac[2][1] : ac[0][1];
        float a02 = hseg ? ac[2][2] : ac[0][2];
        float a03 = hseg ? ac[2][3] : ac[0][3];
        float a10 = hseg ? ac[3][0] : ac[1][0];
        float a11 = hseg ? ac[3][1] : ac[1][1];
        float a12 = hseg ? ac[3][2] : ac[1][2];
        float a13 = hseg ? ac[3][3] : ac[1][3];
        h2 s0l = u2h(d0.x), s0h = u2h(d0.y);
        h2 s1l = u2h(d1.x), s1h = u2h(d1.y);
        float f00 = (float)s0l.x, f01 = (float)s0l.y, f02 = (float)s0h.x, f03 = (float)s0h.y;
        float f10 = (float)s1l.x, f11 = (float)s1l.y, f12 = (float)s1h.x, f13 = (float)s1h.y;
        float x00 = prod ? f00 * a00 : f00 + a00;
        float x01 = prod ? f01 * a01 : f01 + a01;
        float x02 = prod ? f02 * a02 : f02 + a02;
        float x03 = prod ? f03 * a03 : f03 + a03;
        float x10 = prod ? f10 * a10 : f10 + a10;
        float x11 = prod ? f11 * a11 : f11 + a11;
        float x12 = prod ? f12 * a12 : f12 + a12;
        float x13 = prod ? f13 * a13 : f13 + a13;
        uint2 pk;
        pk.x = pk2h(x00, x01);
        pk.y = pk2h(x02, x03);
        *(uint2*)&sp[r0 * SPS + prod * 64 + q * 4] = pk;
        pk.x = pk2h(x10, x11);
        pk.y = pk2h(x12, x13);
        *(uint2*)&sp[r1 * SPS + prod * 64 + q * 4] = pk;
    }

    // sp rows are wave-private: drain this wave's LDS writes only (no block barrier)
    __builtin_amdgcn_wave_barrier();
    asm volatile("s_waitcnt lgkmcnt(0)" ::: "memory");
    __builtin_amdgcn_wave_barrier();

    float4v c0, c1, c2, c3;
    {
        float bv0 = sbias[q];
        float bv1 = sbias[16 + q];
        float bv2 = sbias[32 + q];
        float bv3 = sbias[48 + q];
        c0 = (float4v){bv0, bv0, bv0, bv0};
        c1 = (float4v){bv1, bv1, bv1, bv1};
        c2 = (float4v){bv2, bv2, bv2, bv2};
        c3 = (float4v){bv3, bv3, bv3, bv3};
    }
    #pragma unroll
    for (int kk = 0; kk < 4; kk++) {
        int ko = kk * 32 + g * 8;
        half8 a   = *(const half8*)&sp[(wv * 16 + q) * SPS + ko];
        half8 bb0 = *(const half8*)&wt[(q)      * SPS + ko];
        half8 bb1 = *(const half8*)&wt[(16 + q) * SPS + ko];
        half8 bb2 = *(const half8*)&wt[(32 + q) * SPS + ko];
        half8 bb3 = *(const half8*)&wt[(48 + q) * SPS + ko];
        c0 = __builtin_amdgcn_mfma_f32_16x16x32_f16(a, bb0, c0, 0, 0, 0);
        c1 = __builtin_amdgcn_mfma_f32_16x16x32_f16(a, bb1, c1, 0, 0, 0);
        c2 = __builtin_amdgcn_mfma_f32_16x16x32_f16(a, bb2, c2, 0, 0, 0);
        c3 = __builtin_amdgcn_mfma_f32_16x16x32_f16(a, bb3, c3, 0, 0, 0);
    }

    float ss[4];
    #pragma unroll
    for (int r = 0; r < 4; r++) {
        c0[r] = (c0[r] > 0.f) ? c0[r] : 0.01f * c0[r];
        c1[r] = (c1[r] > 0.f) ? c1[r] : 0.01f * c1[r];
        c2[r] = (c2[r] > 0.f) ? c2[r] : 0.01f * c2[r];
        c3[r] = (c3[r] > 0.f) ? c3[r] : 0.01f * c3[r];
        ss[r] = c0[r]*c0[r] + c1[r]*c1[r] + c2[r]*c2[r] + c3[r]*c3[r];
        #pragma unroll
        for (int mm = 1; mm < 16; mm <<= 1) ss[r] += __shfl_xor(ss[r], mm);
        ss[r] = 1.f / fmaxf(sqrtf(ss[r]), 1e-12f);
    }
    #pragma unroll
    for (int r = 0; r < 4; r++) {
        int node_r = nb0 + wv * 16 + g * 4 + r;
        if (node_r >= n_nodes) continue;
        size_t row = (size_t)node_r * 64;
        h1out[row +      q] = (_Float16)(c0[r] * ss[r]);
        h1out[row + 16 + q] = (_Float16)(c1[r] * ss[r]);
        h1out[row + 32 + q] = (_Float16)(c2[r] * ss[r]);
        h1out[row + 48 + q] = (_Float16)(c3[r] * ss[r]);
    }
}

// ---------- inline layer2 (64->32) for one node ----------
__device__ __forceinline__ float layer2_row(
    const _Float16* __restrict__ h1,
    const int* __restrict__ row_ptr, const unsigned int* __restrict__ edges,
    const float* sW1, const float* sW2, const float* sb,
    int node, int lane)
{
    int es = row_ptr[node];
    int ee = row_ptr[node + 1];
    float g = 0.f;
    for (int base = es; base < ee; base += 64) {
        int cnt = min(64, ee - base);
        unsigned ev = (lane < cnt) ? edges[base + lane] : 0u;
        int j = 0;
        for (; j + 4 <= cnt; j += 4) {
            unsigned e0 = (unsigned)__shfl((int)ev, j);
            unsigned e1 = (unsigned)__shfl((int)ev, j + 1);
            unsigned e2 = (unsigned)__shfl((int)ev, j + 2);
            unsigned e3 = (unsigned)__shfl((int)ev, j + 3);
            float f0 = (float)h1[(size_t)(e0 >> 14) * 64 + lane];
            float f1 = (float)h1[(size_t)(e1 >> 14) * 64 + lane];
            float f2 = (float)h1[(size_t)(e2 >> 14) * 64 + lane];
            float f3 = (float)h1[(size_t)(e3 >> 14) * 64 + lane];
            g += val_f32(e0) * f0 + val_f32(e1) * f1
               + val_f32(e2) * f2 + val_f32(e3) * f3;
        }
        for (; j < cnt; j++) {
            unsigned e0 = (unsigned)__shfl((int)ev, j);
            float f0 = (float)h1[(size_t)(e0 >> 14) * 64 + lane];
            g += val_f32(e0) * f0;
        }
    }
    float f = (float)h1[(size_t)node * 64 + lane];
    float s = f + g;
    float p = f * g;
    int j = lane & 31;
    float acc = sb[j];
    #pragma unroll
    for (int k = 0; k < 64; k++) {
        float sk = __shfl(s, k);
        float pk = __shfl(p, k);
        acc += sk * sW1[k * 32 + j] + pk * sW2[k * 32 + j];
    }
    acc = (acc > 0.f) ? acc : 0.01f * acc;
    float sq = acc * acc;
    #pragma unroll
    for (int m = 1; m < 32; m <<= 1) sq += __shfl_xor(sq, m);
    return acc / fmaxf(sqrtf(sq), 1e-12f);
}

__global__ __launch_bounds__(256) void score_k(
    const float* __restrict__ uw, const float* __restrict__ ew,
    const _Float16* __restrict__ h1,
    const int* __restrict__ row_ptr, const unsigned int* __restrict__ edges,
    const float* __restrict__ W1b, const float* __restrict__ b1b,
    const float* __restrict__ W2b, const float* __restrict__ b2b,
    const int* __restrict__ uid, const int* __restrict__ pid,
    const int* __restrict__ nid, float* __restrict__ out)
{
    __shared__ float sW1[64 * 32];
    __shared__ float sW2[64 * 32];
    __shared__ float sb[32];
    for (int i = threadIdx.x; i < 64 * 32; i += 256) { sW1[i] = W1b[i]; sW2[i] = W2b[i]; }
    if (threadIdx.x < 32) sb[threadIdx.x] = b1b[threadIdx.x] + b2b[threadIdx.x];
    __syncthreads();

    int wave = threadIdx.x >> 6;
    int lane = threadIdx.x & 63;
    int i = blockIdx.x * 4 + wave;
    if (i >= BATCH_C) return;

    int un = uid[i];
    int pe = pid[i];
    int ne = nid[i];
    int pn = N_USERS + pe;
    int nn = N_USERS + ne;

    float acc01p, acc01n;
    {
        float u  = uw[(size_t)un * 64 + lane];
        float pv = ew[(size_t)pe * 64 + lane];
        float nv = ew[(size_t)ne * 64 + lane];
        acc01p = u * pv;
        acc01n = u * nv;
        float u1 = (float)h1[(size_t)un * 64 + lane];
        acc01p += u1 * (float)h1[(size_t)pn * 64 + lane];
        acc01n += u1 * (float)h1[(size_t)nn * 64 + lane];
    }

    float h2u = layer2_row(h1, row_ptr, edges, sW1, sW2, sb, un, lane);
    float h2p = layer2_row(h1, row_ptr, edges, sW1, sW2, sb, pn, lane);
    float h2n = layer2_row(h1, row_ptr, edges, sW1, sW2, sb, nn, lane);
    float p2 = h2u * h2p;
    float n2 = h2u * h2n;
    #pragma unroll
    for (int m = 1; m < 32; m <<= 1) { p2 += __shfl_xor(p2, m); n2 += __shfl_xor(n2, m); }

    #pragma unroll
    for (int m = 1; m < 64; m <<= 1) { acc01p += __shfl_xor(acc01p, m); acc01n += __shfl_xor(acc01n, m); }

    if (lane == 0) {
        out[i]           = acc01p + p2;
        out[BATCH_C + i] = acc01n + n2;
    }
}

extern "C" void kernel_launch(void* const* d_in, const int* in_sizes, int n_in,
                              void* d_out, int out_size, void* d_ws, size_t ws_size,
                              hipStream_t stream) {
    const float* uw   = (const float*)d_in[0];
    const float* ew   = (const float*)d_in[1];
    const float* W1a  = (const float*)d_in[2];
    const float* b1a  = (const float*)d_in[3];
    const float* W2a  = (const float*)d_in[4];
    const float* b2a  = (const float*)d_in[5];
    const float* W1b  = (const float*)d_in[6];
    const float* b1b  = (const float*)d_in[7];
    const float* W2b  = (const float*)d_in[8];
    const float* b2b  = (const float*)d_in[9];
    const float* values   = (const float*)d_in[10];
    const int*   target   = (const int*)d_in[11];
    const int*   neighbor = (const int*)d_in[12];
    const int*   uid  = (const int*)d_in[13];
    const int*   pid  = (const int*)d_in[14];
    const int*   nid  = (const int*)d_in[15];

    const int n_edges = in_sizes[10];

    char* ws = (char*)d_ws;
    int*  row_ptr    = (int*)ws;   ws += 801792;
    int*  cntarr     = (int*)ws;   ws += 704512;          // 448*391*4 = 700672
    int*  sgtot      = (int*)ws;   ws += 4096;
    int*  sgoff      = (int*)ws;   ws += 4096;
    int*  sgcur      = (int*)ws;   ws += 4096;
    unsigned int*   edges = (unsigned int*)ws;   ws += (size_t)N_EDGES_C * 4;      // 12.8 MB
    unsigned short* fb    = (unsigned short*)ws; ws += (size_t)N_NODES_C * 64 * 2; // 25.6 MB
    uint2*          tmp2  = (uint2*)ws;                   // aliased with h1
    _Float16*       h1    = (_Float16*)ws;                // region 25.69 MB

    const int layer_blocks = (N_NODES_C + 127) / 128;     // 1563
    const int nchunks      = (n_edges + CHUNK - 1) / CHUNK;   // 447

    // ----- zero sg totals (async memset instead of a kernel launch) -----
    hipMemsetAsync(sgtot, 0, (NSG + 1) * sizeof(int), stream);

    // ----- fused prep: edge sg-histogram (+cntarr, +sgtot) ∥ f16 feature table -----
    prep_k<<<nchunks + CONVB, 256, 0, stream>>>(uw, ew, fb, target,
                                                cntarr, sgtot, n_edges, nchunks);

    // ----- edge sort + CSR build -----
    scan_k<<<1, 512, 0, stream>>>(sgtot, sgoff, sgcur);
    scatter_k<<<nchunks, 256, 0, stream>>>(target, neighbor, values, cntarr, sgcur, tmp2, n_edges);
    sort2_k<<<NSG, 512, 0, stream>>>(tmp2, sgoff, row_ptr, edges);

    // ----- layer 1 (quad-node pull + MFMA transform, f16; single dispatch) -----
    layer1_pull_k<<<layer_blocks, 512, 0, stream>>>(fb, row_ptr, edges,
                                                    W1a, b1a, W2a, b2a, h1, N_NODES_C);

    // ----- scoring (layer-2 aggregation + transform inline, ~12K nodes) -----
    score_k<<<BATCH_C / 4, 256, 0, stream>>>(uw, ew, h1, row_ptr, edges,
                                             W1b, b1b, W2b, b2b,
                                             uid, pid, nid, (float*)d_out);
}

// Round 13
// 328.288 us; speedup vs baseline: 1.8452x; 1.0209x over previous
//
#include <hip/hip_runtime.h>

#define N_USERS    50000
#define N_ENTITIES 150000
#define N_NODES_C  200000
#define BATCH_C    4096
#define N_EDGES_C  3200000

// edge sort params
#define CHUNK   7168            // edges per scatter block (LDS 57.3 KB buf)
#define SG_SH   9               // supergroup = 512 nodes
#define NSG     391             // ceil(200000/512)
#define S2CAP   12288           // sort2 LDS edge cap (mean 8192, sigma~90)

typedef __attribute__((ext_vector_type(2))) _Float16 h2;
typedef __attribute__((ext_vector_type(8))) _Float16 half8;
typedef __attribute__((ext_vector_type(2))) __fp16 fp16x2_s;   // builtin return type
typedef __attribute__((ext_vector_type(4))) float float4v;

// Workspace (~67 MB; proven safe < 76.8 MB):
//   row_ptr : int [200001+pad]      0.80 MB
//   cntarr  : int [448*391]         0.70 MB   (per-chunk per-sg counts, from prep_k)
//   sgtot   : int [512]             2 KB      (global per-sg totals; memset+atomics)
//   sgoff   : int [512]             2 KB      (supergroup global starts)
//   sgcur   : int [512]             2 KB      (allocation cursor per sg)
//   edges   : uint [3.2M]          12.8 MB    (nb<<14 | f16bits(val), node-sorted CSR)
//   fb16    : ushort[200000*64]    25.6 MB    (f16 node features)
//   region  : 25.69 MB — tmp2 (uint2 sg-sorted edges) then h1 (f16 layer-1 out)
// Edge word: val in [0,1) => f16 bit pattern < 0x4000 fits in 14 bits.
// Lessons: (r6) scattered 4B global stores dirty a full 64B line each (16x
// write amplification) -> ALL global writes must be coalesced runs; sort2 now
// scatters in LDS and streams out linearly. (r7) >4 gather streams spill ->
// 4 streams max. (r9) don't split near-exact-fit dispatches. (r10/r11)
// cross-session compare via layer1 reference; edge-word f16 repack = -13%.

__device__ __forceinline__ h2 u2h(unsigned u) {
    union { unsigned u; h2 h; } x; x.u = u; return x.h;
}
__device__ __forceinline__ unsigned pk2h(float a, float b) {
    union { fp16x2_s h; unsigned u; } x;
    x.h = __builtin_amdgcn_cvt_pkrtz(a, b);
    return x.u;
}
__device__ __forceinline__ float val_f32(unsigned e) {   // low-14-bit f16 -> f32
    union { unsigned short s; _Float16 h; } x;
    x.s = (unsigned short)(e & 0x3FFFu);
    return (float)x.h;
}

// ---------- fused prep: blocks [0,nchunks) = per-chunk sg histogram;
//            blocks [nchunks, nchunks+CONVB) = f32->f16 convert, 8 elems/thread ----------
#define CONVB 6250              // 200000*64 / (256*8)
__global__ __launch_bounds__(256) void prep_k(const float* __restrict__ uw,
                                              const float* __restrict__ ew,
                                              unsigned short* __restrict__ fb,
                                              const int* __restrict__ target,
                                              int* __restrict__ cntarr,
                                              int* __restrict__ sgtot,
                                              int n_edges, int nchunks)
{
    __shared__ int cnt[NSG];
    int bid = blockIdx.x;
    if (bid < nchunks) {
        int base = bid * CHUNK;
        int ccount = min(CHUNK, n_edges - base);
        for (int i = threadIdx.x; i < NSG; i += 256) cnt[i] = 0;
        __syncthreads();
        for (int i = threadIdx.x; i < ccount; i += 256)
            atomicAdd(&cnt[target[base + i] >> SG_SH], 1);
        __syncthreads();
        for (int i = threadIdx.x; i < NSG; i += 256) {
            cntarr[bid * NSG + i] = cnt[i];
            if (cnt[i]) atomicAdd(&sgtot[i], cnt[i]);
        }
    } else {
        // 8 f32 -> 8 f16 per thread; split (3.2M) is 8-aligned so no straddle
        int base8 = ((bid - nchunks) * 256 + threadIdx.x) * 8;
        const int split = N_USERS * 64;
        const float* src = (base8 < split) ? (uw + base8) : (ew + (base8 - split));
        float4 a = *(const float4*)src;
        float4 b = *(const float4*)(src + 4);
        uint4 o;
        o.x = pk2h(a.x, a.y);
        o.y = pk2h(a.z, a.w);
        o.z = pk2h(b.x, b.y);
        o.w = pk2h(b.z, b.w);
        *(uint4*)(fb + base8) = o;
    }
}

// ---------- single small scan: sgoff + cursor init ----------
__global__ __launch_bounds__(512) void scan_k(const int* __restrict__ sgtot,
                                              int* __restrict__ sgoff,
                                              int* __restrict__ sgcur)
{
    __shared__ int part[512];
    int t = threadIdx.x;
    int v = (t < NSG) ? sgtot[t] : 0;
    part[t] = v;
    __syncthreads();
    for (int off = 1; off < 512; off <<= 1) {
        int w = (t >= off) ? part[t - off] : 0;
        __syncthreads();
        part[t] += w;
        __syncthreads();
    }
    if (t < NSG) { sgoff[t] = part[t] - v; sgcur[t] = part[t] - v; }
    if (t == NSG - 1) sgoff[NSG] = part[t];          // total = n_edges
}

// ---------- pass B: LDS sg-sort + cursor-allocated scatter to tmp2 ----------
// Histogram comes from cntarr (built by prep_k) — no target re-read in phase 1.
__global__ __launch_bounds__(256) void scatter_k(
    const int* __restrict__ target, const int* __restrict__ neighbor,
    const float* __restrict__ values, const int* __restrict__ cntarr,
    int* __restrict__ sgcur, uint2* __restrict__ tmp2, int n_edges)
{
    __shared__ uint2 buf[CHUNK];            // 57.3 KB
    __shared__ int cnt[NSG], off[NSG], pos[NSG], gbase[NSG];
    int c = blockIdx.x;
    int base = c * CHUNK;
    int ccount = min(CHUNK, n_edges - base);
    for (int i = threadIdx.x; i < NSG; i += 256) {
        int v = cntarr[c * NSG + i];
        cnt[i] = v;
        pos[i] = 0;
        gbase[i] = 0;
    }
    __syncthreads();
    // allocate this chunk's run for each sg on the global cursor
    for (int i = threadIdx.x; i < NSG; i += 256)
        if (cnt[i]) gbase[i] = atomicAdd(&sgcur[i], cnt[i]);
    if (threadIdx.x < 64) {                 // wave-0 exclusive scan of cnt
        int l = threadIdx.x;
        const int PER = (NSG + 63) / 64;    // 7
        int s0 = l * PER, s1 = min(s0 + PER, NSG);
        int sum = 0;
        for (int i = s0; i < s1; i++) sum += cnt[i];
        int run = sum;
        #pragma unroll
        for (int o = 1; o < 64; o <<= 1) { int v = __shfl_up(run, o); if (l >= o) run += v; }
        int excl = run - sum;
        for (int i = s0; i < s1; i++) { off[i] = excl; excl += cnt[i]; }
    }
    __syncthreads();
    for (int i = threadIdx.x; i < ccount; i += 256) {
        int t  = target[base + i];
        int sg = t >> SG_SH;
        // pack val as raw f16 bits (val in [0,1) -> fits 14 bits)
        _Float16 hv = (_Float16)values[base + i];
        unsigned short hb;
        __builtin_memcpy(&hb, &hv, 2);
        unsigned w = ((unsigned)neighbor[base + i] << 14) | (unsigned)(hb & 0x3FFFu);
        int p = off[sg] + atomicAdd(&pos[sg], 1);
        buf[p] = make_uint2(w, (unsigned)t);
    }
    __syncthreads();
    // buf is sg-sorted: run for sg occupies [off[sg], off[sg]+cnt[sg]).
    // Write each run to its cursor-allocated global slot (coalesced within run).
    for (int i = threadIdx.x; i < ccount; i += 256) {
        uint2 ed = buf[i];
        int sg = (int)(ed.y >> SG_SH);
        tmp2[(size_t)(gbase[sg] + (i - off[sg]))] = ed;
    }
}

// ---------- stage 2: node-level CSR build, LDS scatter-sort + COALESCED writeout ----------
// r11 lesson applied: the old pass-2 scattered 4B global stores (64 lines/wave
// dirty -> ~200MB write traffic for a 12.8MB write). Now: count -> scan ->
// re-read segment (L2-hot) -> scatter into LDS sorted[] -> stream out linearly.
__global__ __launch_bounds__(512) void sort2_k(
    const uint2* __restrict__ tmp2, const int* __restrict__ sgoff,
    int* __restrict__ row_ptr, unsigned* __restrict__ edges)
{
    __shared__ unsigned sorted[S2CAP];      // 49.2 KB
    __shared__ int cnt[512];
    __shared__ int cur[512];
    __shared__ int rp[513];
    int s = blockIdx.x;
    int node0 = s << SG_SH;
    int nn = min(512, N_NODES_C - node0);
    int sgstart = sgoff[s];
    int sgcnt = sgoff[s + 1] - sgstart;
    cnt[threadIdx.x] = 0;
    cur[threadIdx.x] = 0;
    __syncthreads();
    // pass 1: count per node (coalesced segment read)
    for (int e = threadIdx.x; e < sgcnt; e += 512)
        atomicAdd(&cnt[tmp2[(size_t)sgstart + e].y & 511u], 1);
    __syncthreads();
    if (threadIdx.x < 64) {                 // wave-0 exclusive scan of cnt[512]
        int l = threadIdx.x;
        int s0 = l * 8;
        int vals[8];
        int sum = 0;
        for (int i = 0; i < 8; i++) { vals[i] = cnt[s0 + i]; sum += vals[i]; }
        int run = sum;
        #pragma unroll
        for (int o = 1; o < 64; o <<= 1) { int v = __shfl_up(run, o); if (l >= o) run += v; }
        int excl = run - sum;
        for (int i = 0; i < 8; i++) { rp[s0 + i] = excl; excl += vals[i]; }
        if (l == 63) rp[512] = excl;
    }
    __syncthreads();
    for (int i = threadIdx.x; i < nn; i += 512) row_ptr[node0 + i] = sgstart + rp[i];
    if (s == NSG - 1 && threadIdx.x == 0) row_ptr[N_NODES_C] = sgstart + sgcnt;
    // pass 2: re-read segment (L2-hot, 64KB) and scatter into LDS sorted order
    for (int e = threadIdx.x; e < sgcnt; e += 512) {
        uint2 ed = tmp2[(size_t)sgstart + e];
        int tl = (int)(ed.y & 511u);
        int d  = rp[tl] + atomicAdd(&cur[tl], 1);
        if (d < S2CAP) sorted[d] = ed.x;
        else           edges[sgstart + d] = ed.x;   // overflow: never in practice
    }
    __syncthreads();
    // pass 3: coalesced linear writeout (full 64B lines)
    int lim = min(sgcnt, S2CAP);
    for (int e = threadIdx.x; e < lim; e += 512)
        edges[sgstart + e] = sorted[e];
}

// ---------- layer 1: quad-node gather pull (f16 pk_fma) + MFMA f16 transform ----------
// SPS=136 REQUIRED: each row holds 128 f16 k-values (64 sum + 64 product path).
// 4 streams is the proven ILP ceiling (r7). ONE dispatch (r9).
// val unpack: bits | bits<<16 -> h2 (2 VALU, no cvt chain).
#define SPS 136
__global__ __launch_bounds__(512, 6) void layer1_pull_k(
    const unsigned short* __restrict__ fb,
    const int* __restrict__ row_ptr, const unsigned int* __restrict__ edges,
    const float* __restrict__ W1, const float* __restrict__ b1,
    const float* __restrict__ W2, const float* __restrict__ b2,
    _Float16* __restrict__ h1out, int n_nodes)
{
    __shared__ __align__(16) short wt[64 * SPS];    // 17.4 KB
    __shared__ __align__(16) short sp[128 * SPS];   // 34.8 KB
    __shared__ float sbias[64];

    for (int idx = threadIdx.x; idx < 64 * 64; idx += 512) {
        int kp = idx >> 6;
        int n  = idx & 63;
        int k0 = kp * 2, k1 = k0 + 1;
        float w0 = (k0 < 64) ? W1[k0 * 64 + n] : W2[(k0 - 64) * 64 + n];
        float w1 = (k1 < 64) ? W1[k1 * 64 + n] : W2[(k1 - 64) * 64 + n];
        *(unsigned*)&wt[n * SPS + k0] = pk2h(w0, w1);
    }
    if (threadIdx.x < 64) sbias[threadIdx.x] = b1[threadIdx.x] + b2[threadIdx.x];
    __syncthreads();

    int wv   = threadIdx.x >> 6;
    int lane = threadIdx.x & 63;
    int g    = lane >> 4;
    int q    = lane & 15;
    const uint2* fb2 = (const uint2*)fb;

    int nb0 = blockIdx.x * 128;

    for (int i = 0; i < 16; i += 4) {
        int mA = wv * 16 + i;
        int nodeBase = nb0 + mA;

        int es0 = 0, ee0 = 0, es1 = 0, ee1 = 0, es2 = 0, ee2 = 0, es3 = 0, ee3 = 0;
        if (nodeBase     < n_nodes) { es0 = row_ptr[nodeBase];     ee0 = row_ptr[nodeBase + 1]; }
        if (nodeBase + 1 < n_nodes) { es1 = row_ptr[nodeBase + 1]; ee1 = row_ptr[nodeBase + 2]; }
        if (nodeBase + 2 < n_nodes) { es2 = row_ptr[nodeBase + 2]; ee2 = row_ptr[nodeBase + 3]; }
        if (nodeBase + 3 < n_nodes) { es3 = row_ptr[nodeBase + 3]; ee3 = row_ptr[nodeBase + 4]; }

        h2 aLo0 = (h2){0, 0}, aHi0 = (h2){0, 0};
        h2 aLo1 = (h2){0, 0}, aHi1 = (h2){0, 0};
        h2 aLo2 = (h2){0, 0}, aHi2 = (h2){0, 0};
        h2 aLo3 = (h2){0, 0}, aHi3 = (h2){0, 0};

        int b0 = es0, b1c = es1, b2c = es2, b3c = es3;
        while (b0 < ee0 || b1c < ee1 || b2c < ee2 || b3c < ee3) {
            int c0 = ee0 - b0;  c0 = c0 < 0 ? 0 : (c0 > 64 ? 64 : c0);
            int c1 = ee1 - b1c; c1 = c1 < 0 ? 0 : (c1 > 64 ? 64 : c1);
            int c2 = ee2 - b2c; c2 = c2 < 0 ? 0 : (c2 > 64 ? 64 : c2);
            int c3 = ee3 - b3c; c3 = c3 < 0 ? 0 : (c3 > 64 ? 64 : c3);
            unsigned ev0 = (lane < c0) ? edges[b0 + lane]  : 0u;
            unsigned ev1 = (lane < c1) ? edges[b1c + lane] : 0u;
            unsigned ev2 = (lane < c2) ? edges[b2c + lane] : 0u;
            unsigned ev3 = (lane < c3) ? edges[b3c + lane] : 0u;
            int jm0 = (c0 + 3) >> 2;
            int jm1 = (c1 + 3) >> 2;
            int jm2 = (c2 + 3) >> 2;
            int jm3 = (c3 + 3) >> 2;
            int jm = max(max(jm0, jm1), max(jm2, jm3));
            #pragma unroll 4
            for (int j = 0; j < jm; j++) {
                // lanes beyond a stream's count loaded 0 -> shfl yields w=0 -> v=0
                unsigned w0 = (unsigned)__shfl((int)ev0, j * 4 + g);
                unsigned w1 = (unsigned)__shfl((int)ev1, j * 4 + g);
                unsigned w2 = (unsigned)__shfl((int)ev2, j * 4 + g);
                unsigned w3 = (unsigned)__shfl((int)ev3, j * 4 + g);
                uint2 d0 = fb2[(size_t)(w0 >> 14) * 16 + q];
                uint2 d1 = fb2[(size_t)(w1 >> 14) * 16 + q];
                uint2 d2 = fb2[(size_t)(w2 >> 14) * 16 + q];
                uint2 d3 = fb2[(size_t)(w3 >> 14) * 16 + q];
                unsigned vb0 = w0 & 0x3FFFu;
                unsigned vb1 = w1 & 0x3FFFu;
                unsigned vb2 = w2 & 0x3FFFu;
                unsigned vb3 = w3 & 0x3FFFu;
                h2 vv0 = u2h(vb0 | (vb0 << 16));
                h2 vv1 = u2h(vb1 | (vb1 << 16));
                h2 vv2 = u2h(vb2 | (vb2 << 16));
                h2 vv3 = u2h(vb3 | (vb3 << 16));
                aLo0 += u2h(d0.x) * vv0;  aHi0 += u2h(d0.y) * vv0;
                aLo1 += u2h(d1.x) * vv1;  aHi1 += u2h(d1.y) * vv1;
                aLo2 += u2h(d2.x) * vv2;  aHi2 += u2h(d2.y) * vv2;
                aLo3 += u2h(d3.x) * vv3;  aHi3 += u2h(d3.y) * vv3;
            }
            b0 += 64; b1c += 64; b2c += 64; b3c += 64;
        }

        float ac[4][4];
        ac[0][0] = (float)aLo0.x; ac[0][1] = (float)aLo0.y; ac[0][2] = (float)aHi0.x; ac[0][3] = (float)aHi0.y;
        ac[1][0] = (float)aLo1.x; ac[1][1] = (float)aLo1.y; ac[1][2] = (float)aHi1.x; ac[1][3] = (float)aHi1.y;
        ac[2][0] = (float)aLo2.x; ac[2][1] = (float)aLo2.y; ac[2][2] = (float)aHi2.x; ac[2][3] = (float)aHi2.y;
        ac[3][0] = (float)aLo3.x; ac[3][1] = (float)aLo3.y; ac[3][2] = (float)aHi3.x; ac[3][3] = (float)aHi3.y;
        // reduce across the 4 lane-groups (bits 4,5 of lane id) in f32
        #pragma unroll
        for (int s = 0; s < 4; s++)
            #pragma unroll
            for (int c = 0; c < 4; c++) {
                ac[s][c] += __shfl_xor(ac[s][c], 16);
                ac[s][c] += __shfl_xor(ac[s][c], 32);
            }

        // epilogue: g pairs -> (row-pair, sum/product path); all 4 groups busy
        int hseg = g >> 1;
        int prod = g & 1;
        int r0 = mA + (hseg << 1);
        int r1 = r0 + 1;
        int nd0 = nb0 + r0, nd1 = nb0 + r1;
        uint2 d0 = make_uint2(0u, 0u), d1 = make_uint2(0u, 0u);
        if (nd0 < n_nodes) d0 = fb2[(size_t)nd0 * 16 + q];
        if (nd1 < n_nodes) d1 = fb2[(size_t)nd1 * 16 + q];
        float a00 = hseg ? ac[2][0] : ac[0][0];
        float a01 = hseg ? ac[2][1] : ac[0][1];
        float a02 = hseg ? ac[2][2] : ac[0][2];
        float a03 = hseg ? ac[2][3] : ac[0][3];
        float a10 = hseg ? ac[3][0] : ac[1][0];
        float a11 = hseg ? ac[3][1] : ac[1][1];
        float a12 = hseg ? ac[3][2] : ac[1][2];
        float a13 = hseg ? ac[3][3] : ac[1][3];
        h2 s0l = u2h(d0.x), s0h = u2h(d0.y);
        h2 s1l = u2h(d1.x), s1h = u2h(d1.y);
        float f00 = (float)s0l.x, f01 = (float)s0l.y, f02 = (float)s0h.x, f03 = (float)s0h.y;
        float f10 = (float)s1l.x, f11 = (float)s1l.y, f12 = (float)s1h.x, f13 = (float)s1h.y;
        float x00 = prod ? f00 * a00 : f00 + a00;
        float x01 = prod ? f01 * a01 : f01 + a01;
        float x02 = prod ? f02 * a02 : f02 + a02;
        float x03 = prod ? f03 * a03 : f03 + a03;
        float x10 = prod ? f10 * a10 : f10 + a10;
        float x11 = prod ? f11 * a11 : f11 + a11;
        float x12 = prod ? f12 * a12 : f12 + a12;
        float x13 = prod ? f13 * a13 : f13 + a13;
        uint2 pk;
        pk.x = pk2h(x00, x01);
        pk.y = pk2h(x02, x03);
        *(uint2*)&sp[r0 * SPS + prod * 64 + q * 4] = pk;
        pk.x = pk2h(x10, x11);
        pk.y = pk2h(x12, x13);
        *(uint2*)&sp[r1 * SPS + prod * 64 + q * 4] = pk;
    }

    // sp rows are wave-private: drain this wave's LDS writes only (no block barrier)
    __builtin_amdgcn_wave_barrier();
    asm volatile("s_waitcnt lgkmcnt(0)" ::: "memory");
    __builtin_amdgcn_wave_barrier();

    float4v c0, c1, c2, c3;
    {
        float bv0 = sbias[q];
        float bv1 = sbias[16 + q];
        float bv2 = sbias[32 + q];
        float bv3 = sbias[48 + q];
        c0 = (float4v){bv0, bv0, bv0, bv0};
        c1 = (float4v){bv1, bv1, bv1, bv1};
        c2 = (float4v){bv2, bv2, bv2, bv2};
        c3 = (float4v){bv3, bv3, bv3, bv3};
    }
    #pragma unroll
    for (int kk = 0; kk < 4; kk++) {
        int ko = kk * 32 + g * 8;
        half8 a   = *(const half8*)&sp[(wv * 16 + q) * SPS + ko];
        half8 bb0 = *(const half8*)&wt[(q)      * SPS + ko];
        half8 bb1 = *(const half8*)&wt[(16 + q) * SPS + ko];
        half8 bb2 = *(const half8*)&wt[(32 + q) * SPS + ko];
        half8 bb3 = *(const half8*)&wt[(48 + q) * SPS + ko];
        c0 = __builtin_amdgcn_mfma_f32_16x16x32_f16(a, bb0, c0, 0, 0, 0);
        c1 = __builtin_amdgcn_mfma_f32_16x16x32_f16(a, bb1, c1, 0, 0, 0);
        c2 = __builtin_amdgcn_mfma_f32_16x16x32_f16(a, bb2, c2, 0, 0, 0);
        c3 = __builtin_amdgcn_mfma_f32_16x16x32_f16(a, bb3, c3, 0, 0, 0);
    }

    float ss[4];
    #pragma unroll
    for (int r = 0; r < 4; r++) {
        c0[r] = (c0[r] > 0.f) ? c0[r] : 0.01f * c0[r];
        c1[r] = (c1[r] > 0.f) ? c1[r] : 0.01f * c1[r];
        c2[r] = (c2[r] > 0.f) ? c2[r] : 0.01f * c2[r];
        c3[r] = (c3[r] > 0.f) ? c3[r] : 0.01f * c3[r];
        ss[r] = c0[r]*c0[r] + c1[r]*c1[r] + c2[r]*c2[r] + c3[r]*c3[r];
        #pragma unroll
        for (int mm = 1; mm < 16; mm <<= 1) ss[r] += __shfl_xor(ss[r], mm);
        ss[r] = 1.f / fmaxf(sqrtf(ss[r]), 1e-12f);
    }
    #pragma unroll
    for (int r = 0; r < 4; r++) {
        int node_r = nb0 + wv * 16 + g * 4 + r;
        if (node_r >= n_nodes) continue;
        size_t row = (size_t)node_r * 64;
        h1out[row +      q] = (_Float16)(c0[r] * ss[r]);
        h1out[row + 16 + q] = (_Float16)(c1[r] * ss[r]);
        h1out[row + 32 + q] = (_Float16)(c2[r] * ss[r]);
        h1out[row + 48 + q] = (_Float16)(c3[r] * ss[r]);
    }
}

// ---------- inline layer2 (64->32) for one node ----------
__device__ __forceinline__ float layer2_row(
    const _Float16* __restrict__ h1,
    const int* __restrict__ row_ptr, const unsigned int* __restrict__ edges,
    const float* sW1, const float* sW2, const float* sb,
    int node, int lane)
{
    int es = row_ptr[node];
    int ee = row_ptr[node + 1];
    float g = 0.f;
    for (int base = es; base < ee; base += 64) {
        int cnt = min(64, ee - base);
        unsigned ev = (lane < cnt) ? edges[base + lane] : 0u;
        int j = 0;
        for (; j + 4 <= cnt; j += 4) {
            unsigned e0 = (unsigned)__shfl((int)ev, j);
            unsigned e1 = (unsigned)__shfl((int)ev, j + 1);
            unsigned e2 = (unsigned)__shfl((int)ev, j + 2);
            unsigned e3 = (unsigned)__shfl((int)ev, j + 3);
            float f0 = (float)h1[(size_t)(e0 >> 14) * 64 + lane];
            float f1 = (float)h1[(size_t)(e1 >> 14) * 64 + lane];
            float f2 = (float)h1[(size_t)(e2 >> 14) * 64 + lane];
            float f3 = (float)h1[(size_t)(e3 >> 14) * 64 + lane];
            g += val_f32(e0) * f0 + val_f32(e1) * f1
               + val_f32(e2) * f2 + val_f32(e3) * f3;
        }
        for (; j < cnt; j++) {
            unsigned e0 = (unsigned)__shfl((int)ev, j);
            float f0 = (float)h1[(size_t)(e0 >> 14) * 64 + lane];
            g += val_f32(e0) * f0;
        }
    }
    float f = (float)h1[(size_t)node * 64 + lane];
    float s = f + g;
    float p = f * g;
    int j = lane & 31;
    float acc = sb[j];
    #pragma unroll
    for (int k = 0; k < 64; k++) {
        float sk = __shfl(s, k);
        float pk = __shfl(p, k);
        acc += sk * sW1[k * 32 + j] + pk * sW2[k * 32 + j];
    }
    acc = (acc > 0.f) ? acc : 0.01f * acc;
    float sq = acc * acc;
    #pragma unroll
    for (int m = 1; m < 32; m <<= 1) sq += __shfl_xor(sq, m);
    return acc / fmaxf(sqrtf(sq), 1e-12f);
}

__global__ __launch_bounds__(256) void score_k(
    const float* __restrict__ uw, const float* __restrict__ ew,
    const _Float16* __restrict__ h1,
    const int* __restrict__ row_ptr, const unsigned int* __restrict__ edges,
    const float* __restrict__ W1b, const float* __restrict__ b1b,
    const float* __restrict__ W2b, const float* __restrict__ b2b,
    const int* __restrict__ uid, const int* __restrict__ pid,
    const int* __restrict__ nid, float* __restrict__ out)
{
    __shared__ float sW1[64 * 32];
    __shared__ float sW2[64 * 32];
    __shared__ float sb[32];
    for (int i = threadIdx.x; i < 64 * 32; i += 256) { sW1[i] = W1b[i]; sW2[i] = W2b[i]; }
    if (threadIdx.x < 32) sb[threadIdx.x] = b1b[threadIdx.x] + b2b[threadIdx.x];
    __syncthreads();

    int wave = threadIdx.x >> 6;
    int lane = threadIdx.x & 63;
    int i = blockIdx.x * 4 + wave;
    if (i >= BATCH_C) return;

    int un = uid[i];
    int pe = pid[i];
    int ne = nid[i];
    int pn = N_USERS + pe;
    int nn = N_USERS + ne;

    float acc01p, acc01n;
    {
        float u  = uw[(size_t)un * 64 + lane];
        float pv = ew[(size_t)pe * 64 + lane];
        float nv = ew[(size_t)ne * 64 + lane];
        acc01p = u * pv;
        acc01n = u * nv;
        float u1 = (float)h1[(size_t)un * 64 + lane];
        acc01p += u1 * (float)h1[(size_t)pn * 64 + lane];
        acc01n += u1 * (float)h1[(size_t)nn * 64 + lane];
    }

    float h2u = layer2_row(h1, row_ptr, edges, sW1, sW2, sb, un, lane);
    float h2p = layer2_row(h1, row_ptr, edges, sW1, sW2, sb, pn, lane);
    float h2n = layer2_row(h1, row_ptr, edges, sW1, sW2, sb, nn, lane);
    float p2 = h2u * h2p;
    float n2 = h2u * h2n;
    #pragma unroll
    for (int m = 1; m < 32; m <<= 1) { p2 += __shfl_xor(p2, m); n2 += __shfl_xor(n2, m); }

    #pragma unroll
    for (int m = 1; m < 64; m <<= 1) { acc01p += __shfl_xor(acc01p, m); acc01n += __shfl_xor(acc01n, m); }

    if (lane == 0) {
        out[i]           = acc01p + p2;
        out[BATCH_C + i] = acc01n + n2;
    }
}

extern "C" void kernel_launch(void* const* d_in, const int* in_sizes, int n_in,
                              void* d_out, int out_size, void* d_ws, size_t ws_size,
                              hipStream_t stream) {
    const float* uw   = (const float*)d_in[0];
    const float* ew   = (const float*)d_in[1];
    const float* W1a  = (const float*)d_in[2];
    const float* b1a  = (const float*)d_in[3];
    const float* W2a  = (const float*)d_in[4];
    const float* b2a  = (const float*)d_in[5];
    const float* W1b  = (const float*)d_in[6];
    const float* b1b  = (const float*)d_in[7];
    const float* W2b  = (const float*)d_in[8];
    const float* b2b  = (const float*)d_in[9];
    const float* values   = (const float*)d_in[10];
    const int*   target   = (const int*)d_in[11];
    const int*   neighbor = (const int*)d_in[12];
    const int*   uid  = (const int*)d_in[13];
    const int*   pid  = (const int*)d_in[14];
    const int*   nid  = (const int*)d_in[15];

    const int n_edges = in_sizes[10];

    char* ws = (char*)d_ws;
    int*  row_ptr    = (int*)ws;   ws += 801792;
    int*  cntarr     = (int*)ws;   ws += 704512;          // 448*391*4 = 700672
    int*  sgtot      = (int*)ws;   ws += 4096;
    int*  sgoff      = (int*)ws;   ws += 4096;
    int*  sgcur      = (int*)ws;   ws += 4096;
    unsigned int*   edges = (unsigned int*)ws;   ws += (size_t)N_EDGES_C * 4;      // 12.8 MB
    unsigned short* fb    = (unsigned short*)ws; ws += (size_t)N_NODES_C * 64 * 2; // 25.6 MB
    uint2*          tmp2  = (uint2*)ws;                   // aliased with h1
    _Float16*       h1    = (_Float16*)ws;                // region 25.69 MB

    const int layer_blocks = (N_NODES_C + 127) / 128;     // 1563
    const int nchunks      = (n_edges + CHUNK - 1) / CHUNK;   // 447

    // ----- zero sg totals (async memset instead of a kernel launch) -----
    hipMemsetAsync(sgtot, 0, (NSG + 1) * sizeof(int), stream);

    // ----- fused prep: edge sg-histogram (+cntarr, +sgtot) ∥ f16 feature table -----
    prep_k<<<nchunks + CONVB, 256, 0, stream>>>(uw, ew, fb, target,
                                                cntarr, sgtot, n_edges, nchunks);

    // ----- edge sort + CSR build -----
    scan_k<<<1, 512, 0, stream>>>(sgtot, sgoff, sgcur);
    scatter_k<<<nchunks, 256, 0, stream>>>(target, neighbor, values, cntarr, sgcur, tmp2, n_edges);
    sort2_k<<<NSG, 512, 0, stream>>>(tmp2, sgoff, row_ptr, edges);

    // ----- layer 1 (quad-node pull + MFMA transform, f16; single dispatch) -----
    layer1_pull_k<<<layer_blocks, 512, 0, stream>>>(fb, row_ptr, edges,
                                                    W1a, b1a, W2a, b2a, h1, N_NODES_C);

    // ----- scoring (layer-2 aggregation + transform inline, ~12K nodes) -----
    score_k<<<BATCH_C / 4, 256, 0, stream>>>(uw, ew, h1, row_ptr, edges,
                                             W1b, b1b, W2b, b2b,
                                             uid, pid, nid, (float*)d_out);
}

// Round 14
// 314.901 us; speedup vs baseline: 1.9237x; 1.0425x over previous
//
#include <hip/hip_runtime.h>

#define N_USERS    50000
#define N_ENTITIES 150000
#define N_NODES_C  200000
#define BATCH_C    4096
#define N_EDGES_C  3200000

// edge sort params
#define CHUNK   7168            // edges per scatter block (LDS 57.3 KB buf)
#define SG_SH   9               // supergroup = 512 nodes
#define NSG     391             // ceil(200000/512)
#define S2CAP   12288           // sort2 LDS edge cap (mean 8192, sigma~90)

typedef __attribute__((ext_vector_type(2))) _Float16 h2;
typedef __attribute__((ext_vector_type(8))) _Float16 half8;
typedef __attribute__((ext_vector_type(2))) __fp16 fp16x2_s;   // builtin return type
typedef __attribute__((ext_vector_type(4))) float float4v;

// Workspace (~67 MB; proven safe < 76.8 MB):
//   row_ptr : int [200001+pad]      0.80 MB
//   cntarr  : int [448*391]         0.70 MB   (per-chunk per-sg counts, from prep_k)
//   sgtot   : int [1024]            4 KB      (per-sg totals; memset+atomics)
//   sgcur   : int [1024]            4 KB      (cursors, zeroed by same memset)
//   edges   : uint [3.2M]          12.8 MB    (nb<<14 | f16bits(val), node-sorted CSR)
//   fb16    : ushort[200000*64]    25.6 MB    (f16 node features)
//   region  : 25.69 MB — tmp2 (uint2 sg-sorted edges) then h1 (f16 layer-1 out)
// Lessons: (r4/r13) 1-block kernels are whole-GPU bubbles -> sg prefix scan is
// recomputed in-block by scatter/sort2 (391 ints, ~us) instead of a scan_k
// launch. (r6) scattered 4B global stores amplify 16x -> coalesced runs only.
// (r7) >4 gather streams spill -> 4 max. (r9) don't split near-fit dispatches.
// (r10/r11) layer1 dur = cross-session reference clock; f16 edge repack -13%.

__device__ __forceinline__ h2 u2h(unsigned u) {
    union { unsigned u; h2 h; } x; x.u = u; return x.h;
}
__device__ __forceinline__ unsigned pk2h(float a, float b) {
    union { fp16x2_s h; unsigned u; } x;
    x.h = __builtin_amdgcn_cvt_pkrtz(a, b);
    return x.u;
}
__device__ __forceinline__ float val_f32(unsigned e) {   // low-14-bit f16 -> f32
    union { unsigned short s; _Float16 h; } x;
    x.s = (unsigned short)(e & 0x3FFFu);
    return (float)x.h;
}

// ---------- fused prep: blocks [0,nchunks) = per-chunk sg histogram;
//            blocks [nchunks, nchunks+CONVB) = f32->f16 convert, 8 elems/thread ----------
#define CONVB 6250              // 200000*64 / (256*8)
__global__ __launch_bounds__(256) void prep_k(const float* __restrict__ uw,
                                              const float* __restrict__ ew,
                                              unsigned short* __restrict__ fb,
                                              const int* __restrict__ target,
                                              int* __restrict__ cntarr,
                                              int* __restrict__ sgtot,
                                              int n_edges, int nchunks)
{
    __shared__ int cnt[NSG];
    int bid = blockIdx.x;
    if (bid < nchunks) {
        int base = bid * CHUNK;
        int ccount = min(CHUNK, n_edges - base);
        for (int i = threadIdx.x; i < NSG; i += 256) cnt[i] = 0;
        __syncthreads();
        for (int i = threadIdx.x; i < ccount; i += 256)
            atomicAdd(&cnt[target[base + i] >> SG_SH], 1);
        __syncthreads();
        for (int i = threadIdx.x; i < NSG; i += 256) {
            cntarr[bid * NSG + i] = cnt[i];
            if (cnt[i]) atomicAdd(&sgtot[i], cnt[i]);
        }
    } else {
        // 8 f32 -> 8 f16 per thread; split (3.2M) is 8-aligned so no straddle
        int base8 = ((bid - nchunks) * 256 + threadIdx.x) * 8;
        const int split = N_USERS * 64;
        const float* src = (base8 < split) ? (uw + base8) : (ew + (base8 - split));
        float4 a = *(const float4*)src;
        float4 b = *(const float4*)(src + 4);
        uint4 o;
        o.x = pk2h(a.x, a.y);
        o.y = pk2h(a.z, a.w);
        o.z = pk2h(b.x, b.y);
        o.w = pk2h(b.z, b.w);
        *(uint4*)(fb + base8) = o;
    }
}

// ---------- pass B: LDS sg-sort + cursor-allocated scatter to tmp2 ----------
// In-block sg prefix scan (no scan_k kernel); histogram from cntarr.
__global__ __launch_bounds__(256) void scatter_k(
    const int* __restrict__ target, const int* __restrict__ neighbor,
    const float* __restrict__ values, const int* __restrict__ cntarr,
    const int* __restrict__ sgtot, int* __restrict__ sgcur,
    uint2* __restrict__ tmp2, int n_edges)
{
    __shared__ uint2 buf[CHUNK];            // 57.3 KB
    __shared__ int cnt[NSG], off[NSG], pos[NSG], gbase[NSG];
    __shared__ int stot[NSG], soff[NSG];
    int c = blockIdx.x;
    int base = c * CHUNK;
    int ccount = min(CHUNK, n_edges - base);
    for (int i = threadIdx.x; i < NSG; i += 256) {
        cnt[i]  = cntarr[c * NSG + i];
        stot[i] = sgtot[i];
        pos[i] = 0;
    }
    __syncthreads();
    if (threadIdx.x < 64) {                 // wave-0: scan stot->soff, cnt->off
        int l = threadIdx.x;
        const int PER = (NSG + 63) / 64;    // 7
        int s0 = l * PER, s1 = min(s0 + PER, NSG);
        // exclusive scan of stot into soff
        int sum = 0;
        for (int i = s0; i < s1; i++) sum += stot[i];
        int run = sum;
        #pragma unroll
        for (int o = 1; o < 64; o <<= 1) { int v = __shfl_up(run, o); if (l >= o) run += v; }
        int excl = run - sum;
        for (int i = s0; i < s1; i++) { soff[i] = excl; excl += stot[i]; }
        // exclusive scan of cnt into off
        sum = 0;
        for (int i = s0; i < s1; i++) sum += cnt[i];
        run = sum;
        #pragma unroll
        for (int o = 1; o < 64; o <<= 1) { int v = __shfl_up(run, o); if (l >= o) run += v; }
        excl = run - sum;
        for (int i = s0; i < s1; i++) { off[i] = excl; excl += cnt[i]; }
    }
    __syncthreads();
    // allocate this chunk's run for each sg on the global cursor
    for (int i = threadIdx.x; i < NSG; i += 256)
        gbase[i] = cnt[i] ? soff[i] + atomicAdd(&sgcur[i], cnt[i]) : 0;
    for (int i = threadIdx.x; i < ccount; i += 256) {
        int t  = target[base + i];
        int sg = t >> SG_SH;
        // pack val as raw f16 bits (val in [0,1) -> fits 14 bits)
        _Float16 hv = (_Float16)values[base + i];
        unsigned short hb;
        __builtin_memcpy(&hb, &hv, 2);
        unsigned w = ((unsigned)neighbor[base + i] << 14) | (unsigned)(hb & 0x3FFFu);
        int p = off[sg] + atomicAdd(&pos[sg], 1);
        buf[p] = make_uint2(w, (unsigned)t);
    }
    __syncthreads();
    // buf is sg-sorted: run for sg occupies [off[sg], off[sg]+cnt[sg]).
    // Write each run to its cursor-allocated global slot (coalesced within run).
    for (int i = threadIdx.x; i < ccount; i += 256) {
        uint2 ed = buf[i];
        int sg = (int)(ed.y >> SG_SH);
        tmp2[(size_t)(gbase[sg] + (i - off[sg]))] = ed;
    }
}

// ---------- stage 2: node-level CSR build, LDS scatter-sort + COALESCED writeout ----------
// In-block sg prefix scan; count -> scan -> L2-hot re-read -> LDS sorted[] ->
// linear stream-out (r6/r11: all global writes coalesced).
__global__ __launch_bounds__(512) void sort2_k(
    const uint2* __restrict__ tmp2, const int* __restrict__ sgtot,
    int* __restrict__ row_ptr, unsigned* __restrict__ edges)
{
    __shared__ unsigned sorted[S2CAP];      // 49.2 KB
    __shared__ int cnt[512];
    __shared__ int cur[512];
    __shared__ int rp[513];
    __shared__ int stot[NSG], soff[NSG];
    int s = blockIdx.x;
    int node0 = s << SG_SH;
    int nn = min(512, N_NODES_C - node0);
    cnt[threadIdx.x] = 0;
    cur[threadIdx.x] = 0;
    for (int i = threadIdx.x; i < NSG; i += 512) stot[i] = sgtot[i];
    __syncthreads();
    if (threadIdx.x < 64) {                 // wave-0 exclusive scan stot->soff
        int l = threadIdx.x;
        const int PER = (NSG + 63) / 64;    // 7
        int s0 = l * PER, s1 = min(s0 + PER, NSG);
        int sum = 0;
        for (int i = s0; i < s1; i++) sum += stot[i];
        int run = sum;
        #pragma unroll
        for (int o = 1; o < 64; o <<= 1) { int v = __shfl_up(run, o); if (l >= o) run += v; }
        int excl = run - sum;
        for (int i = s0; i < s1; i++) { soff[i] = excl; excl += stot[i]; }
    }
    __syncthreads();
    int sgstart = soff[s];
    int sgcnt   = stot[s];
    // pass 1: count per node (coalesced segment read)
    for (int e = threadIdx.x; e < sgcnt; e += 512)
        atomicAdd(&cnt[tmp2[(size_t)sgstart + e].y & 511u], 1);
    __syncthreads();
    if (threadIdx.x < 64) {                 // wave-0 exclusive scan of cnt[512]
        int l = threadIdx.x;
        int s0 = l * 8;
        int vals[8];
        int sum = 0;
        for (int i = 0; i < 8; i++) { vals[i] = cnt[s0 + i]; sum += vals[i]; }
        int run = sum;
        #pragma unroll
        for (int o = 1; o < 64; o <<= 1) { int v = __shfl_up(run, o); if (l >= o) run += v; }
        int excl = run - sum;
        for (int i = 0; i < 8; i++) { rp[s0 + i] = excl; excl += vals[i]; }
        if (l == 63) rp[512] = excl;
    }
    __syncthreads();
    for (int i = threadIdx.x; i < nn; i += 512) row_ptr[node0 + i] = sgstart + rp[i];
    if (s == NSG - 1 && threadIdx.x == 0) row_ptr[N_NODES_C] = sgstart + sgcnt;
    // pass 2: re-read segment (L2-hot, 64KB) and scatter into LDS sorted order
    for (int e = threadIdx.x; e < sgcnt; e += 512) {
        uint2 ed = tmp2[(size_t)sgstart + e];
        int tl = (int)(ed.y & 511u);
        int d  = rp[tl] + atomicAdd(&cur[tl], 1);
        if (d < S2CAP) sorted[d] = ed.x;
        else           edges[sgstart + d] = ed.x;   // overflow: never in practice
    }
    __syncthreads();
    // pass 3: coalesced linear writeout (full 64B lines)
    int lim = min(sgcnt, S2CAP);
    for (int e = threadIdx.x; e < lim; e += 512)
        edges[sgstart + e] = sorted[e];
}

// ---------- layer 1: quad-node gather pull (f16 pk_fma) + MFMA f16 transform ----------
// SPS=136 REQUIRED: each row holds 128 f16 k-values (64 sum + 64 product path).
// 4 streams is the proven ILP ceiling (r7). ONE dispatch (r9).
// val unpack: bits | bits<<16 -> h2 (2 VALU, no cvt chain).
#define SPS 136
__global__ __launch_bounds__(512, 6) void layer1_pull_k(
    const unsigned short* __restrict__ fb,
    const int* __restrict__ row_ptr, const unsigned int* __restrict__ edges,
    const float* __restrict__ W1, const float* __restrict__ b1,
    const float* __restrict__ W2, const float* __restrict__ b2,
    _Float16* __restrict__ h1out, int n_nodes)
{
    __shared__ __align__(16) short wt[64 * SPS];    // 17.4 KB
    __shared__ __align__(16) short sp[128 * SPS];   // 34.8 KB
    __shared__ float sbias[64];

    for (int idx = threadIdx.x; idx < 64 * 64; idx += 512) {
        int kp = idx >> 6;
        int n  = idx & 63;
        int k0 = kp * 2, k1 = k0 + 1;
        float w0 = (k0 < 64) ? W1[k0 * 64 + n] : W2[(k0 - 64) * 64 + n];
        float w1 = (k1 < 64) ? W1[k1 * 64 + n] : W2[(k1 - 64) * 64 + n];
        *(unsigned*)&wt[n * SPS + k0] = pk2h(w0, w1);
    }
    if (threadIdx.x < 64) sbias[threadIdx.x] = b1[threadIdx.x] + b2[threadIdx.x];
    __syncthreads();

    int wv   = threadIdx.x >> 6;
    int lane = threadIdx.x & 63;
    int g    = lane >> 4;
    int q    = lane & 15;
    const uint2* fb2 = (const uint2*)fb;

    int nb0 = blockIdx.x * 128;

    for (int i = 0; i < 16; i += 4) {
        int mA = wv * 16 + i;
        int nodeBase = nb0 + mA;

        int es0 = 0, ee0 = 0, es1 = 0, ee1 = 0, es2 = 0, ee2 = 0, es3 = 0, ee3 = 0;
        if (nodeBase     < n_nodes) { es0 = row_ptr[nodeBase];     ee0 = row_ptr[nodeBase + 1]; }
        if (nodeBase + 1 < n_nodes) { es1 = row_ptr[nodeBase + 1]; ee1 = row_ptr[nodeBase + 2]; }
        if (nodeBase + 2 < n_nodes) { es2 = row_ptr[nodeBase + 2]; ee2 = row_ptr[nodeBase + 3]; }
        if (nodeBase + 3 < n_nodes) { es3 = row_ptr[nodeBase + 3]; ee3 = row_ptr[nodeBase + 4]; }

        h2 aLo0 = (h2){0, 0}, aHi0 = (h2){0, 0};
        h2 aLo1 = (h2){0, 0}, aHi1 = (h2){0, 0};
        h2 aLo2 = (h2){0, 0}, aHi2 = (h2){0, 0};
        h2 aLo3 = (h2){0, 0}, aHi3 = (h2){0, 0};

        int b0 = es0, b1c = es1, b2c = es2, b3c = es3;
        while (b0 < ee0 || b1c < ee1 || b2c < ee2 || b3c < ee3) {
            int c0 = ee0 - b0;  c0 = c0 < 0 ? 0 : (c0 > 64 ? 64 : c0);
            int c1 = ee1 - b1c; c1 = c1 < 0 ? 0 : (c1 > 64 ? 64 : c1);
            int c2 = ee2 - b2c; c2 = c2 < 0 ? 0 : (c2 > 64 ? 64 : c2);
            int c3 = ee3 - b3c; c3 = c3 < 0 ? 0 : (c3 > 64 ? 64 : c3);
            unsigned ev0 = (lane < c0) ? edges[b0 + lane]  : 0u;
            unsigned ev1 = (lane < c1) ? edges[b1c + lane] : 0u;
            unsigned ev2 = (lane < c2) ? edges[b2c + lane] : 0u;
            unsigned ev3 = (lane < c3) ? edges[b3c + lane] : 0u;
            int jm0 = (c0 + 3) >> 2;
            int jm1 = (c1 + 3) >> 2;
            int jm2 = (c2 + 3) >> 2;
            int jm3 = (c3 + 3) >> 2;
            int jm = max(max(jm0, jm1), max(jm2, jm3));
            #pragma unroll 4
            for (int j = 0; j < jm; j++) {
                // lanes beyond a stream's count loaded 0 -> shfl yields w=0 -> v=0
                unsigned w0 = (unsigned)__shfl((int)ev0, j * 4 + g);
                unsigned w1 = (unsigned)__shfl((int)ev1, j * 4 + g);
                unsigned w2 = (unsigned)__shfl((int)ev2, j * 4 + g);
                unsigned w3 = (unsigned)__shfl((int)ev3, j * 4 + g);
                uint2 d0 = fb2[(size_t)(w0 >> 14) * 16 + q];
                uint2 d1 = fb2[(size_t)(w1 >> 14) * 16 + q];
                uint2 d2 = fb2[(size_t)(w2 >> 14) * 16 + q];
                uint2 d3 = fb2[(size_t)(w3 >> 14) * 16 + q];
                unsigned vb0 = w0 & 0x3FFFu;
                unsigned vb1 = w1 & 0x3FFFu;
                unsigned vb2 = w2 & 0x3FFFu;
                unsigned vb3 = w3 & 0x3FFFu;
                h2 vv0 = u2h(vb0 | (vb0 << 16));
                h2 vv1 = u2h(vb1 | (vb1 << 16));
                h2 vv2 = u2h(vb2 | (vb2 << 16));
                h2 vv3 = u2h(vb3 | (vb3 << 16));
                aLo0 += u2h(d0.x) * vv0;  aHi0 += u2h(d0.y) * vv0;
                aLo1 += u2h(d1.x) * vv1;  aHi1 += u2h(d1.y) * vv1;
                aLo2 += u2h(d2.x) * vv2;  aHi2 += u2h(d2.y) * vv2;
                aLo3 += u2h(d3.x) * vv3;  aHi3 += u2h(d3.y) * vv3;
            }
            b0 += 64; b1c += 64; b2c += 64; b3c += 64;
        }

        float ac[4][4];
        ac[0][0] = (float)aLo0.x; ac[0][1] = (float)aLo0.y; ac[0][2] = (float)aHi0.x; ac[0][3] = (float)aHi0.y;
        ac[1][0] = (float)aLo1.x; ac[1][1] = (float)aLo1.y; ac[1][2] = (float)aHi1.x; ac[1][3] = (float)aHi1.y;
        ac[2][0] = (float)aLo2.x; ac[2][1] = (float)aLo2.y; ac[2][2] = (float)aHi2.x; ac[2][3] = (float)aHi2.y;
        ac[3][0] = (float)aLo3.x; ac[3][1] = (float)aLo3.y; ac[3][2] = (float)aHi3.x; ac[3][3] = (float)aHi3.y;
        // reduce across the 4 lane-groups (bits 4,5 of lane id) in f32
        #pragma unroll
        for (int s = 0; s < 4; s++)
            #pragma unroll
            for (int c = 0; c < 4; c++) {
                ac[s][c] += __shfl_xor(ac[s][c], 16);
                ac[s][c] += __shfl_xor(ac[s][c], 32);
            }

        // epilogue: g pairs -> (row-pair, sum/product path); all 4 groups busy
        int hseg = g >> 1;
        int prod = g & 1;
        int r0 = mA + (hseg << 1);
        int r1 = r0 + 1;
        int nd0 = nb0 + r0, nd1 = nb0 + r1;
        uint2 d0 = make_uint2(0u, 0u), d1 = make_uint2(0u, 0u);
        if (nd0 < n_nodes) d0 = fb2[(size_t)nd0 * 16 + q];
        if (nd1 < n_nodes) d1 = fb2[(size_t)nd1 * 16 + q];
        float a00 = hseg ? ac[2][0] : ac[0][0];
        float a01 = hseg ? ac[2][1] : ac[0][1];
        float a02 = hseg ? ac[2][2] : ac[0][2];
        float a03 = hseg ? ac[2][3] : ac[0][3];
        float a10 = hseg ? ac[3][0] : ac[1][0];
        float a11 = hseg ? ac[3][1] : ac[1][1];
        float a12 = hseg ? ac[3][2] : ac[1][2];
        float a13 = hseg ? ac[3][3] : ac[1][3];
        h2 s0l = u2h(d0.x), s0h = u2h(d0.y);
        h2 s1l = u2h(d1.x), s1h = u2h(d1.y);
        float f00 = (float)s0l.x, f01 = (float)s0l.y, f02 = (float)s0h.x, f03 = (float)s0h.y;
        float f10 = (float)s1l.x, f11 = (float)s1l.y, f12 = (float)s1h.x, f13 = (float)s1h.y;
        float x00 = prod ? f00 * a00 : f00 + a00;
        float x01 = prod ? f01 * a01 : f01 + a01;
        float x02 = prod ? f02 * a02 : f02 + a02;
        float x03 = prod ? f03 * a03 : f03 + a03;
        float x10 = prod ? f10 * a10 : f10 + a10;
        float x11 = prod ? f11 * a11 : f11 + a11;
        float x12 = prod ? f12 * a12 : f12 + a12;
        float x13 = prod ? f13 * a13 : f13 + a13;
        uint2 pk;
        pk.x = pk2h(x00, x01);
        pk.y = pk2h(x02, x03);
        *(uint2*)&sp[r0 * SPS + prod * 64 + q * 4] = pk;
        pk.x = pk2h(x10, x11);
        pk.y = pk2h(x12, x13);
        *(uint2*)&sp[r1 * SPS + prod * 64 + q * 4] = pk;
    }

    // sp rows are wave-private: drain this wave's LDS writes only (no block barrier)
    __builtin_amdgcn_wave_barrier();
    asm volatile("s_waitcnt lgkmcnt(0)" ::: "memory");
    __builtin_amdgcn_wave_barrier();

    float4v c0, c1, c2, c3;
    {
        float bv0 = sbias[q];
        float bv1 = sbias[16 + q];
        float bv2 = sbias[32 + q];
        float bv3 = sbias[48 + q];
        c0 = (float4v){bv0, bv0, bv0, bv0};
        c1 = (float4v){bv1, bv1, bv1, bv1};
        c2 = (float4v){bv2, bv2, bv2, bv2};
        c3 = (float4v){bv3, bv3, bv3, bv3};
    }
    #pragma unroll
    for (int kk = 0; kk < 4; kk++) {
        int ko = kk * 32 + g * 8;
        half8 a   = *(const half8*)&sp[(wv * 16 + q) * SPS + ko];
        half8 bb0 = *(const half8*)&wt[(q)      * SPS + ko];
        half8 bb1 = *(const half8*)&wt[(16 + q) * SPS + ko];
        half8 bb2 = *(const half8*)&wt[(32 + q) * SPS + ko];
        half8 bb3 = *(const half8*)&wt[(48 + q) * SPS + ko];
        c0 = __builtin_amdgcn_mfma_f32_16x16x32_f16(a, bb0, c0, 0, 0, 0);
        c1 = __builtin_amdgcn_mfma_f32_16x16x32_f16(a, bb1, c1, 0, 0, 0);
        c2 = __builtin_amdgcn_mfma_f32_16x16x32_f16(a, bb2, c2, 0, 0, 0);
        c3 = __builtin_amdgcn_mfma_f32_16x16x32_f16(a, bb3, c3, 0, 0, 0);
    }

    float ss[4];
    #pragma unroll
    for (int r = 0; r < 4; r++) {
        c0[r] = (c0[r] > 0.f) ? c0[r] : 0.01f * c0[r];
        c1[r] = (c1[r] > 0.f) ? c1[r] : 0.01f * c1[r];
        c2[r] = (c2[r] > 0.f) ? c2[r] : 0.01f * c2[r];
        c3[r] = (c3[r] > 0.f) ? c3[r] : 0.01f * c3[r];
        ss[r] = c0[r]*c0[r] + c1[r]*c1[r] + c2[r]*c2[r] + c3[r]*c3[r];
        #pragma unroll
        for (int mm = 1; mm < 16; mm <<= 1) ss[r] += __shfl_xor(ss[r], mm);
        ss[r] = 1.f / fmaxf(sqrtf(ss[r]), 1e-12f);
    }
    #pragma unroll
    for (int r = 0; r < 4; r++) {
        int node_r = nb0 + wv * 16 + g * 4 + r;
        if (node_r >= n_nodes) continue;
        size_t row = (size_t)node_r * 64;
        h1out[row +      q] = (_Float16)(c0[r] * ss[r]);
        h1out[row + 16 + q] = (_Float16)(c1[r] * ss[r]);
        h1out[row + 32 + q] = (_Float16)(c2[r] * ss[r]);
        h1out[row + 48 + q] = (_Float16)(c3[r] * ss[r]);
    }
}

// ---------- layer2 for THREE nodes jointly (u,p,n): 3-stream gather MLP +
// half-split k-range matmul (lo lanes k<32, hi lanes k>=32, xor-combine) ----------
__device__ __forceinline__ void layer2_rows3(
    const _Float16* __restrict__ h1,
    const int* __restrict__ row_ptr, const unsigned int* __restrict__ edges,
    const float* sW1, const float* sW2, const float* sb,
    int n0, int n1, int n2, int lane,
    float& r0, float& r1, float& r2)
{
    int es0 = row_ptr[n0], ee0 = row_ptr[n0 + 1];
    int es1 = row_ptr[n1], ee1 = row_ptr[n1 + 1];
    int es2 = row_ptr[n2], ee2 = row_ptr[n2 + 1];
    float g0 = 0.f, g1 = 0.f, g2 = 0.f;
    int b0 = es0, b1 = es1, b2 = es2;
    while (b0 < ee0 || b1 < ee1 || b2 < ee2) {
        int c0 = ee0 - b0; c0 = c0 < 0 ? 0 : (c0 > 64 ? 64 : c0);
        int c1 = ee1 - b1; c1 = c1 < 0 ? 0 : (c1 > 64 ? 64 : c1);
        int c2 = ee2 - b2; c2 = c2 < 0 ? 0 : (c2 > 64 ? 64 : c2);
        unsigned ev0 = (lane < c0) ? edges[b0 + lane] : 0u;
        unsigned ev1 = (lane < c1) ? edges[b1 + lane] : 0u;
        unsigned ev2 = (lane < c2) ? edges[b2 + lane] : 0u;
        int jm = max(c0, max(c1, c2));
        for (int j = 0; j < jm; j++) {
            // exhausted streams broadcast 0 -> val 0 -> no-op
            unsigned e0 = (unsigned)__shfl((int)ev0, j);
            unsigned e1 = (unsigned)__shfl((int)ev1, j);
            unsigned e2 = (unsigned)__shfl((int)ev2, j);
            float f0 = (float)h1[(size_t)(e0 >> 14) * 64 + lane];
            float f1 = (float)h1[(size_t)(e1 >> 14) * 64 + lane];
            float f2 = (float)h1[(size_t)(e2 >> 14) * 64 + lane];
            g0 += val_f32(e0) * f0;
            g1 += val_f32(e1) * f1;
            g2 += val_f32(e2) * f2;
        }
        b0 += 64; b1 += 64; b2 += 64;
    }
    float fA = (float)h1[(size_t)n0 * 64 + lane];
    float fB = (float)h1[(size_t)n1 * 64 + lane];
    float fC = (float)h1[(size_t)n2 * 64 + lane];
    float sA = fA + g0, pA = fA * g0;
    float sB = fB + g1, pB = fB * g1;
    float sC = fC + g2, pC = fC * g2;
    int j  = lane & 31;
    int kb = (lane >> 5) << 5;              // 0 for lo half, 32 for hi half
    float aA = 0.f, aB = 0.f, aC = 0.f;
    #pragma unroll
    for (int k = 0; k < 32; k++) {
        int kk = kb + k;
        float w1v = sW1[kk * 32 + j];
        float w2v = sW2[kk * 32 + j];
        aA += __shfl(sA, kk) * w1v + __shfl(pA, kk) * w2v;
        aB += __shfl(sB, kk) * w1v + __shfl(pB, kk) * w2v;
        aC += __shfl(sC, kk) * w1v + __shfl(pC, kk) * w2v;
    }
    aA += __shfl_xor(aA, 32);
    aB += __shfl_xor(aB, 32);
    aC += __shfl_xor(aC, 32);
    float bj = sb[j];
    aA += bj; aB += bj; aC += bj;
    aA = (aA > 0.f) ? aA : 0.01f * aA;
    aB = (aB > 0.f) ? aB : 0.01f * aB;
    aC = (aC > 0.f) ? aC : 0.01f * aC;
    float qA = aA * aA, qB = aB * aB, qC = aC * aC;
    #pragma unroll
    for (int m = 1; m < 32; m <<= 1) {
        qA += __shfl_xor(qA, m);
        qB += __shfl_xor(qB, m);
        qC += __shfl_xor(qC, m);
    }
    r0 = aA / fmaxf(sqrtf(qA), 1e-12f);
    r1 = aB / fmaxf(sqrtf(qB), 1e-12f);
    r2 = aC / fmaxf(sqrtf(qC), 1e-12f);
}

__global__ __launch_bounds__(256) void score_k(
    const float* __restrict__ uw, const float* __restrict__ ew,
    const _Float16* __restrict__ h1,
    const int* __restrict__ row_ptr, const unsigned int* __restrict__ edges,
    const float* __restrict__ W1b, const float* __restrict__ b1b,
    const float* __restrict__ W2b, const float* __restrict__ b2b,
    const int* __restrict__ uid, const int* __restrict__ pid,
    const int* __restrict__ nid, float* __restrict__ out)
{
    __shared__ float sW1[64 * 32];
    __shared__ float sW2[64 * 32];
    __shared__ float sb[32];
    for (int i = threadIdx.x; i < 64 * 32; i += 256) { sW1[i] = W1b[i]; sW2[i] = W2b[i]; }
    if (threadIdx.x < 32) sb[threadIdx.x] = b1b[threadIdx.x] + b2b[threadIdx.x];
    __syncthreads();

    int wave = threadIdx.x >> 6;
    int lane = threadIdx.x & 63;
    int i = blockIdx.x * 4 + wave;
    if (i >= BATCH_C) return;

    int un = uid[i];
    int pe = pid[i];
    int ne = nid[i];
    int pn = N_USERS + pe;
    int nn = N_USERS + ne;

    float acc01p, acc01n;
    {
        float u  = uw[(size_t)un * 64 + lane];
        float pv = ew[(size_t)pe * 64 + lane];
        float nv = ew[(size_t)ne * 64 + lane];
        acc01p = u * pv;
        acc01n = u * nv;
        float u1 = (float)h1[(size_t)un * 64 + lane];
        acc01p += u1 * (float)h1[(size_t)pn * 64 + lane];
        acc01n += u1 * (float)h1[(size_t)nn * 64 + lane];
    }

    float h2u, h2p, h2n;
    layer2_rows3(h1, row_ptr, edges, sW1, sW2, sb, un, pn, nn, lane, h2u, h2p, h2n);
    float p2 = h2u * h2p;
    float n2 = h2u * h2n;
    #pragma unroll
    for (int m = 1; m < 32; m <<= 1) { p2 += __shfl_xor(p2, m); n2 += __shfl_xor(n2, m); }

    #pragma unroll
    for (int m = 1; m < 64; m <<= 1) { acc01p += __shfl_xor(acc01p, m); acc01n += __shfl_xor(acc01n, m); }

    if (lane == 0) {
        out[i]           = acc01p + p2;
        out[BATCH_C + i] = acc01n + n2;
    }
}

extern "C" void kernel_launch(void* const* d_in, const int* in_sizes, int n_in,
                              void* d_out, int out_size, void* d_ws, size_t ws_size,
                              hipStream_t stream) {
    const float* uw   = (const float*)d_in[0];
    const float* ew   = (const float*)d_in[1];
    const float* W1a  = (const float*)d_in[2];
    const float* b1a  = (const float*)d_in[3];
    const float* W2a  = (const float*)d_in[4];
    const float* b2a  = (const float*)d_in[5];
    const float* W1b  = (const float*)d_in[6];
    const float* b1b  = (const float*)d_in[7];
    const float* W2b  = (const float*)d_in[8];
    const float* b2b  = (const float*)d_in[9];
    const float* values   = (const float*)d_in[10];
    const int*   target   = (const int*)d_in[11];
    const int*   neighbor = (const int*)d_in[12];
    const int*   uid  = (const int*)d_in[13];
    const int*   pid  = (const int*)d_in[14];
    const int*   nid  = (const int*)d_in[15];

    const int n_edges = in_sizes[10];

    char* ws = (char*)d_ws;
    int*  row_ptr    = (int*)ws;   ws += 801792;
    int*  cntarr     = (int*)ws;   ws += 704512;          // 448*391*4 = 700672
    int*  sgtot      = (int*)ws;   ws += 4096;
    int*  sgcur      = (int*)ws;   ws += 4096;            // adjacent: one memset
    unsigned int*   edges = (unsigned int*)ws;   ws += (size_t)N_EDGES_C * 4;      // 12.8 MB
    unsigned short* fb    = (unsigned short*)ws; ws += (size_t)N_NODES_C * 64 * 2; // 25.6 MB
    uint2*          tmp2  = (uint2*)ws;                   // aliased with h1
    _Float16*       h1    = (_Float16*)ws;                // region 25.69 MB

    const int layer_blocks = (N_NODES_C + 127) / 128;     // 1563
    const int nchunks      = (n_edges + CHUNK - 1) / CHUNK;   // 447

    // ----- zero sg totals + cursors (single async memset, adjacent buffers) -----
    hipMemsetAsync(sgtot, 0, 8192, stream);

    // ----- fused prep: edge sg-histogram (+cntarr, +sgtot) ∥ f16 feature table -----
    prep_k<<<nchunks + CONVB, 256, 0, stream>>>(uw, ew, fb, target,
                                                cntarr, sgtot, n_edges, nchunks);

    // ----- edge sort + CSR build (sg scan recomputed in-block; no scan_k bubble) -----
    scatter_k<<<nchunks, 256, 0, stream>>>(target, neighbor, values, cntarr,
                                           sgtot, sgcur, tmp2, n_edges);
    sort2_k<<<NSG, 512, 0, stream>>>(tmp2, sgtot, row_ptr, edges);

    // ----- layer 1 (quad-node pull + MFMA transform, f16; single dispatch) -----
    layer1_pull_k<<<layer_blocks, 512, 0, stream>>>(fb, row_ptr, edges,
                                                    W1a, b1a, W2a, b2a, h1, N_NODES_C);

    // ----- scoring (fused 3-row layer-2 + transform, ~12K nodes) -----
    score_k<<<BATCH_C / 4, 256, 0, stream>>>(uw, ew, h1, row_ptr, edges,
                                             W1b, b1b, W2b, b2b,
                                             uid, pid, nid, (float*)d_out);
}

// Round 15
// 309.759 us; speedup vs baseline: 1.9556x; 1.0166x over previous
//
#include <hip/hip_runtime.h>

#define N_USERS    50000
#define N_ENTITIES 150000
#define N_NODES_C  200000
#define BATCH_C    4096
#define N_EDGES_C  3200000

// edge sort params
#define CHUNK   7168            // edges per scatter block (LDS 57.3 KB buf)
#define SG_SH   9               // supergroup = 512 nodes
#define NSG     391             // ceil(200000/512)
#define S2CAP   12288           // sort2 LDS edge cap (mean 8192, sigma~90)

typedef __attribute__((ext_vector_type(2))) _Float16 h2;
typedef __attribute__((ext_vector_type(8))) _Float16 half8;
typedef __attribute__((ext_vector_type(2))) __fp16 fp16x2_s;   // builtin return type
typedef __attribute__((ext_vector_type(4))) float float4v;

// Workspace (~67 MB; proven safe < 76.8 MB):
//   row_ptr : int [200001+pad]      0.80 MB
//   cntarr  : int [448*391]         0.70 MB   (per-chunk per-sg counts, from prep_k)
//   sgtot   : int [1024]            4 KB      (per-sg totals; memset+atomics)
//   sgcur   : int [1024]            4 KB      (cursors, zeroed by same memset)
//   wpk     : f16 [64][128]        16 KB      (packed W1||W2, B-fragments via L1)
//   edges   : uint [3.2M]          12.8 MB    (nb<<14 | f16bits(val), node-sorted CSR)
//   fb16    : ushort[200000*64]    25.6 MB    (f16 node features)
//   region  : 25.69 MB — tmp2 (uint2 sg-sorted edges) then h1 (f16 layer-1 out)
// Lessons: (r4/r13) 1-block kernels are whole-GPU bubbles -> in-block sg scan.
// (r6) scattered 4B global stores amplify 16x -> coalesced runs only.
// (r7) >4 gather streams spill -> 4 max. (r9) don't split near-fit dispatches.
// (r10/r11) layer1 dur = cross-session reference clock (±14% container clock).
// (r14) read-only tables identical across blocks (wt 17.4KB) belong in
// L1-cached GLOBAL, not LDS -> LDS 52.7->35.1 KB -> 4 blocks/CU (32-wave max).

__device__ __forceinline__ h2 u2h(unsigned u) {
    union { unsigned u; h2 h; } x; x.u = u; return x.h;
}
__device__ __forceinline__ unsigned pk2h(float a, float b) {
    union { fp16x2_s h; unsigned u; } x;
    x.h = __builtin_amdgcn_cvt_pkrtz(a, b);
    return x.u;
}
__device__ __forceinline__ float val_f32(unsigned e) {   // low-14-bit f16 -> f32
    union { unsigned short s; _Float16 h; } x;
    x.s = (unsigned short)(e & 0x3FFFu);
    return (float)x.h;
}

// ---------- fused prep: blocks [0,nchunks) = per-chunk sg histogram;
//   [nchunks, nchunks+CONVB) = f32->f16 convert; last block = weight pack ----------
#define CONVB 6250              // 200000*64 / (256*8)
__global__ __launch_bounds__(256) void prep_k(const float* __restrict__ uw,
                                              const float* __restrict__ ew,
                                              unsigned short* __restrict__ fb,
                                              const int* __restrict__ target,
                                              int* __restrict__ cntarr,
                                              int* __restrict__ sgtot,
                                              const float* __restrict__ W1,
                                              const float* __restrict__ W2,
                                              unsigned* __restrict__ wpk,
                                              int n_edges, int nchunks)
{
    __shared__ int cnt[NSG];
    int bid = blockIdx.x;
    if (bid < nchunks) {
        int base = bid * CHUNK;
        int ccount = min(CHUNK, n_edges - base);
        for (int i = threadIdx.x; i < NSG; i += 256) cnt[i] = 0;
        __syncthreads();
        for (int i = threadIdx.x; i < ccount; i += 256)
            atomicAdd(&cnt[target[base + i] >> SG_SH], 1);
        __syncthreads();
        for (int i = threadIdx.x; i < NSG; i += 256) {
            cntarr[bid * NSG + i] = cnt[i];
            if (cnt[i]) atomicAdd(&sgtot[i], cnt[i]);
        }
    } else if (bid < nchunks + CONVB) {
        // 8 f32 -> 8 f16 per thread; split (3.2M) is 8-aligned so no straddle
        int base8 = ((bid - nchunks) * 256 + threadIdx.x) * 8;
        const int split = N_USERS * 64;
        const float* src = (base8 < split) ? (uw + base8) : (ew + (base8 - split));
        float4 a = *(const float4*)src;
        float4 b = *(const float4*)(src + 4);
        uint4 o;
        o.x = pk2h(a.x, a.y);
        o.y = pk2h(a.z, a.w);
        o.z = pk2h(b.x, b.y);
        o.w = pk2h(b.z, b.w);
        *(uint4*)(fb + base8) = o;
    } else {
        // weight pack: wpk dword[n*64+kp] = f16pair(w(2kp,n), w(2kp+1,n)),
        // w(k,n) = k<64 ? W1[k][n] : W2[k-64][n]
        for (int idx = threadIdx.x; idx < 64 * 64; idx += 256) {
            int kp = idx >> 6;
            int n  = idx & 63;
            int k0 = kp * 2, k1 = k0 + 1;
            float w0 = (k0 < 64) ? W1[k0 * 64 + n] : W2[(k0 - 64) * 64 + n];
            float w1 = (k1 < 64) ? W1[k1 * 64 + n] : W2[(k1 - 64) * 64 + n];
            wpk[n * 64 + kp] = pk2h(w0, w1);
        }
    }
}

// ---------- pass B: LDS sg-sort + cursor-allocated scatter to tmp2 ----------
// In-block sg prefix scan (no scan_k kernel); histogram from cntarr.
__global__ __launch_bounds__(256) void scatter_k(
    const int* __restrict__ target, const int* __restrict__ neighbor,
    const float* __restrict__ values, const int* __restrict__ cntarr,
    const int* __restrict__ sgtot, int* __restrict__ sgcur,
    uint2* __restrict__ tmp2, int n_edges)
{
    __shared__ uint2 buf[CHUNK];            // 57.3 KB
    __shared__ int cnt[NSG], off[NSG], pos[NSG], gbase[NSG];
    __shared__ int stot[NSG], soff[NSG];
    int c = blockIdx.x;
    int base = c * CHUNK;
    int ccount = min(CHUNK, n_edges - base);
    for (int i = threadIdx.x; i < NSG; i += 256) {
        cnt[i]  = cntarr[c * NSG + i];
        stot[i] = sgtot[i];
        pos[i] = 0;
    }
    __syncthreads();
    if (threadIdx.x < 64) {                 // wave-0: scan stot->soff, cnt->off
        int l = threadIdx.x;
        const int PER = (NSG + 63) / 64;    // 7
        int s0 = l * PER, s1 = min(s0 + PER, NSG);
        int sum = 0;
        for (int i = s0; i < s1; i++) sum += stot[i];
        int run = sum;
        #pragma unroll
        for (int o = 1; o < 64; o <<= 1) { int v = __shfl_up(run, o); if (l >= o) run += v; }
        int excl = run - sum;
        for (int i = s0; i < s1; i++) { soff[i] = excl; excl += stot[i]; }
        sum = 0;
        for (int i = s0; i < s1; i++) sum += cnt[i];
        run = sum;
        #pragma unroll
        for (int o = 1; o < 64; o <<= 1) { int v = __shfl_up(run, o); if (l >= o) run += v; }
        excl = run - sum;
        for (int i = s0; i < s1; i++) { off[i] = excl; excl += cnt[i]; }
    }
    __syncthreads();
    // allocate this chunk's run for each sg on the global cursor
    for (int i = threadIdx.x; i < NSG; i += 256)
        gbase[i] = cnt[i] ? soff[i] + atomicAdd(&sgcur[i], cnt[i]) : 0;
    for (int i = threadIdx.x; i < ccount; i += 256) {
        int t  = target[base + i];
        int sg = t >> SG_SH;
        // pack val as raw f16 bits (val in [0,1) -> fits 14 bits)
        _Float16 hv = (_Float16)values[base + i];
        unsigned short hb;
        __builtin_memcpy(&hb, &hv, 2);
        unsigned w = ((unsigned)neighbor[base + i] << 14) | (unsigned)(hb & 0x3FFFu);
        int p = off[sg] + atomicAdd(&pos[sg], 1);
        buf[p] = make_uint2(w, (unsigned)t);
    }
    __syncthreads();
    // buf is sg-sorted: run for sg occupies [off[sg], off[sg]+cnt[sg]).
    for (int i = threadIdx.x; i < ccount; i += 256) {
        uint2 ed = buf[i];
        int sg = (int)(ed.y >> SG_SH);
        tmp2[(size_t)(gbase[sg] + (i - off[sg]))] = ed;
    }
}

// ---------- stage 2: node-level CSR build, LDS scatter-sort + COALESCED writeout ----------
__global__ __launch_bounds__(512) void sort2_k(
    const uint2* __restrict__ tmp2, const int* __restrict__ sgtot,
    int* __restrict__ row_ptr, unsigned* __restrict__ edges)
{
    __shared__ unsigned sorted[S2CAP];      // 49.2 KB
    __shared__ int cnt[512];
    __shared__ int cur[512];
    __shared__ int rp[513];
    __shared__ int stot[NSG], soff[NSG];
    int s = blockIdx.x;
    int node0 = s << SG_SH;
    int nn = min(512, N_NODES_C - node0);
    cnt[threadIdx.x] = 0;
    cur[threadIdx.x] = 0;
    for (int i = threadIdx.x; i < NSG; i += 512) stot[i] = sgtot[i];
    __syncthreads();
    if (threadIdx.x < 64) {                 // wave-0 exclusive scan stot->soff
        int l = threadIdx.x;
        const int PER = (NSG + 63) / 64;    // 7
        int s0 = l * PER, s1 = min(s0 + PER, NSG);
        int sum = 0;
        for (int i = s0; i < s1; i++) sum += stot[i];
        int run = sum;
        #pragma unroll
        for (int o = 1; o < 64; o <<= 1) { int v = __shfl_up(run, o); if (l >= o) run += v; }
        int excl = run - sum;
        for (int i = s0; i < s1; i++) { soff[i] = excl; excl += stot[i]; }
    }
    __syncthreads();
    int sgstart = soff[s];
    int sgcnt   = stot[s];
    // pass 1: count per node (coalesced segment read)
    for (int e = threadIdx.x; e < sgcnt; e += 512)
        atomicAdd(&cnt[tmp2[(size_t)sgstart + e].y & 511u], 1);
    __syncthreads();
    if (threadIdx.x < 64) {                 // wave-0 exclusive scan of cnt[512]
        int l = threadIdx.x;
        int s0 = l * 8;
        int vals[8];
        int sum = 0;
        for (int i = 0; i < 8; i++) { vals[i] = cnt[s0 + i]; sum += vals[i]; }
        int run = sum;
        #pragma unroll
        for (int o = 1; o < 64; o <<= 1) { int v = __shfl_up(run, o); if (l >= o) run += v; }
        int excl = run - sum;
        for (int i = 0; i < 8; i++) { rp[s0 + i] = excl; excl += vals[i]; }
        if (l == 63) rp[512] = excl;
    }
    __syncthreads();
    for (int i = threadIdx.x; i < nn; i += 512) row_ptr[node0 + i] = sgstart + rp[i];
    if (s == NSG - 1 && threadIdx.x == 0) row_ptr[N_NODES_C] = sgstart + sgcnt;
    // pass 2: re-read segment (L2-hot, 64KB) and scatter into LDS sorted order
    for (int e = threadIdx.x; e < sgcnt; e += 512) {
        uint2 ed = tmp2[(size_t)sgstart + e];
        int tl = (int)(ed.y & 511u);
        int d  = rp[tl] + atomicAdd(&cur[tl], 1);
        if (d < S2CAP) sorted[d] = ed.x;
        else           edges[sgstart + d] = ed.x;   // overflow: never in practice
    }
    __syncthreads();
    // pass 3: coalesced linear writeout (full 64B lines)
    int lim = min(sgcnt, S2CAP);
    for (int e = threadIdx.x; e < lim; e += 512)
        edges[sgstart + e] = sorted[e];
}

// ---------- layer 1: quad-node gather pull (f16 pk_fma) + MFMA f16 transform ----------
// SPS=136 REQUIRED: each row holds 128 f16 k-values (64 sum + 64 product path).
// 4 streams is the ILP ceiling (r7). ONE dispatch (r9). Weights come from the
// global wpk table via L1 (r14) -> LDS 35.1 KB -> 4 blocks/CU, 32 waves (max).
#define SPS 136
__global__ __launch_bounds__(512, 8) void layer1_pull_k(
    const unsigned short* __restrict__ fb,
    const int* __restrict__ row_ptr, const unsigned int* __restrict__ edges,
    const unsigned* __restrict__ wpk,
    const float* __restrict__ b1, const float* __restrict__ b2,
    _Float16* __restrict__ h1out, int n_nodes)
{
    __shared__ __align__(16) short sp[128 * SPS];   // 34.8 KB
    __shared__ float sbias[64];

    if (threadIdx.x < 64) sbias[threadIdx.x] = b1[threadIdx.x] + b2[threadIdx.x];
    __syncthreads();

    int wv   = threadIdx.x >> 6;
    int lane = threadIdx.x & 63;
    int g    = lane >> 4;
    int q    = lane & 15;
    const uint2* fb2 = (const uint2*)fb;
    const _Float16* wpk_h = (const _Float16*)wpk;   // [64][128] f16

    int nb0 = blockIdx.x * 128;

    for (int i = 0; i < 16; i += 4) {
        int mA = wv * 16 + i;
        int nodeBase = nb0 + mA;

        int es0 = 0, ee0 = 0, es1 = 0, ee1 = 0, es2 = 0, ee2 = 0, es3 = 0, ee3 = 0;
        if (nodeBase     < n_nodes) { es0 = row_ptr[nodeBase];     ee0 = row_ptr[nodeBase + 1]; }
        if (nodeBase + 1 < n_nodes) { es1 = row_ptr[nodeBase + 1]; ee1 = row_ptr[nodeBase + 2]; }
        if (nodeBase + 2 < n_nodes) { es2 = row_ptr[nodeBase + 2]; ee2 = row_ptr[nodeBase + 3]; }
        if (nodeBase + 3 < n_nodes) { es3 = row_ptr[nodeBase + 3]; ee3 = row_ptr[nodeBase + 4]; }

        h2 aLo0 = (h2){0, 0}, aHi0 = (h2){0, 0};
        h2 aLo1 = (h2){0, 0}, aHi1 = (h2){0, 0};
        h2 aLo2 = (h2){0, 0}, aHi2 = (h2){0, 0};
        h2 aLo3 = (h2){0, 0}, aHi3 = (h2){0, 0};

        int b0 = es0, b1c = es1, b2c = es2, b3c = es3;
        while (b0 < ee0 || b1c < ee1 || b2c < ee2 || b3c < ee3) {
            int c0 = ee0 - b0;  c0 = c0 < 0 ? 0 : (c0 > 64 ? 64 : c0);
            int c1 = ee1 - b1c; c1 = c1 < 0 ? 0 : (c1 > 64 ? 64 : c1);
            int c2 = ee2 - b2c; c2 = c2 < 0 ? 0 : (c2 > 64 ? 64 : c2);
            int c3 = ee3 - b3c; c3 = c3 < 0 ? 0 : (c3 > 64 ? 64 : c3);
            unsigned ev0 = (lane < c0) ? edges[b0 + lane]  : 0u;
            unsigned ev1 = (lane < c1) ? edges[b1c + lane] : 0u;
            unsigned ev2 = (lane < c2) ? edges[b2c + lane] : 0u;
            unsigned ev3 = (lane < c3) ? edges[b3c + lane] : 0u;
            int jm0 = (c0 + 3) >> 2;
            int jm1 = (c1 + 3) >> 2;
            int jm2 = (c2 + 3) >> 2;
            int jm3 = (c3 + 3) >> 2;
            int jm = max(max(jm0, jm1), max(jm2, jm3));
            #pragma unroll 4
            for (int j = 0; j < jm; j++) {
                // lanes beyond a stream's count loaded 0 -> shfl yields w=0 -> v=0
                unsigned w0 = (unsigned)__shfl((int)ev0, j * 4 + g);
                unsigned w1 = (unsigned)__shfl((int)ev1, j * 4 + g);
                unsigned w2 = (unsigned)__shfl((int)ev2, j * 4 + g);
                unsigned w3 = (unsigned)__shfl((int)ev3, j * 4 + g);
                uint2 d0 = fb2[(size_t)(w0 >> 14) * 16 + q];
                uint2 d1 = fb2[(size_t)(w1 >> 14) * 16 + q];
                uint2 d2 = fb2[(size_t)(w2 >> 14) * 16 + q];
                uint2 d3 = fb2[(size_t)(w3 >> 14) * 16 + q];
                unsigned vb0 = w0 & 0x3FFFu;
                unsigned vb1 = w1 & 0x3FFFu;
                unsigned vb2 = w2 & 0x3FFFu;
                unsigned vb3 = w3 & 0x3FFFu;
                h2 vv0 = u2h(vb0 | (vb0 << 16));
                h2 vv1 = u2h(vb1 | (vb1 << 16));
                h2 vv2 = u2h(vb2 | (vb2 << 16));
                h2 vv3 = u2h(vb3 | (vb3 << 16));
                aLo0 += u2h(d0.x) * vv0;  aHi0 += u2h(d0.y) * vv0;
                aLo1 += u2h(d1.x) * vv1;  aHi1 += u2h(d1.y) * vv1;
                aLo2 += u2h(d2.x) * vv2;  aHi2 += u2h(d2.y) * vv2;
                aLo3 += u2h(d3.x) * vv3;  aHi3 += u2h(d3.y) * vv3;
            }
            b0 += 64; b1c += 64; b2c += 64; b3c += 64;
        }

        float ac[4][4];
        ac[0][0] = (float)aLo0.x; ac[0][1] = (float)aLo0.y; ac[0][2] = (float)aHi0.x; ac[0][3] = (float)aHi0.y;
        ac[1][0] = (float)aLo1.x; ac[1][1] = (float)aLo1.y; ac[1][2] = (float)aHi1.x; ac[1][3] = (float)aHi1.y;
        ac[2][0] = (float)aLo2.x; ac[2][1] = (float)aLo2.y; ac[2][2] = (float)aHi2.x; ac[2][3] = (float)aHi2.y;
        ac[3][0] = (float)aLo3.x; ac[3][1] = (float)aLo3.y; ac[3][2] = (float)aHi3.x; ac[3][3] = (float)aHi3.y;
        // reduce across the 4 lane-groups (bits 4,5 of lane id) in f32
        #pragma unroll
        for (int s = 0; s < 4; s++)
            #pragma unroll
            for (int c = 0; c < 4; c++) {
                ac[s][c] += __shfl_xor(ac[s][c], 16);
                ac[s][c] += __shfl_xor(ac[s][c], 32);
            }

        // epilogue: g pairs -> (row-pair, sum/product path); all 4 groups busy
        int hseg = g >> 1;
        int prod = g & 1;
        int r0 = mA + (hseg << 1);
        int r1 = r0 + 1;
        int nd0 = nb0 + r0, nd1 = nb0 + r1;
        uint2 d0 = make_uint2(0u, 0u), d1 = make_uint2(0u, 0u);
        if (nd0 < n_nodes) d0 = fb2[(size_t)nd0 * 16 + q];
        if (nd1 < n_nodes) d1 = fb2[(size_t)nd1 * 16 + q];
        float a00 = hseg ? ac[2][0] : ac[0][0];
        float a01 = hseg ? ac[2][1] : ac[0][1];
        float a02 = hseg ? ac[2][2] : ac[0][2];
        float a03 = hseg ? ac[2][3] : ac[0][3];
        float a10 = hseg ? ac[3][0] : ac[1][0];
        float a11 = hseg ? ac[3][1] : ac[1][1];
        float a12 = hseg ? ac[3][2] : ac[1][2];
        float a13 = hseg ? ac[3][3] : ac[1][3];
        h2 s0l = u2h(d0.x), s0h = u2h(d0.y);
        h2 s1l = u2h(d1.x), s1h = u2h(d1.y);
        float f00 = (float)s0l.x, f01 = (float)s0l.y, f02 = (float)s0h.x, f03 = (float)s0h.y;
        float f10 = (float)s1l.x, f11 = (float)s1l.y, f12 = (float)s1h.x, f13 = (float)s1h.y;
        float x00 = prod ? f00 * a00 : f00 + a00;
        float x01 = prod ? f01 * a01 : f01 + a01;
        float x02 = prod ? f02 * a02 : f02 + a02;
        float x03 = prod ? f03 * a03 : f03 + a03;
        float x10 = prod ? f10 * a10 : f10 + a10;
        float x11 = prod ? f11 * a11 : f11 + a11;
        float x12 = prod ? f12 * a12 : f12 + a12;
        float x13 = prod ? f13 * a13 : f13 + a13;
        uint2 pk;
        pk.x = pk2h(x00, x01);
        pk.y = pk2h(x02, x03);
        *(uint2*)&sp[r0 * SPS + prod * 64 + q * 4] = pk;
        pk.x = pk2h(x10, x11);
        pk.y = pk2h(x12, x13);
        *(uint2*)&sp[r1 * SPS + prod * 64 + q * 4] = pk;
    }

    // sp rows are wave-private: drain this wave's LDS writes only (no block barrier)
    __builtin_amdgcn_wave_barrier();
    asm volatile("s_waitcnt lgkmcnt(0)" ::: "memory");
    __builtin_amdgcn_wave_barrier();

    float4v c0, c1, c2, c3;
    {
        float bv0 = sbias[q];
        float bv1 = sbias[16 + q];
        float bv2 = sbias[32 + q];
        float bv3 = sbias[48 + q];
        c0 = (float4v){bv0, bv0, bv0, bv0};
        c1 = (float4v){bv1, bv1, bv1, bv1};
        c2 = (float4v){bv2, bv2, bv2, bv2};
        c3 = (float4v){bv3, bv3, bv3, bv3};
    }
    #pragma unroll
    for (int kk = 0; kk < 4; kk++) {
        int ko = kk * 32 + g * 8;
        half8 a   = *(const half8*)&sp[(wv * 16 + q) * SPS + ko];
        half8 bb0 = *(const half8*)&wpk_h[(q)      * 128 + ko];
        half8 bb1 = *(const half8*)&wpk_h[(16 + q) * 128 + ko];
        half8 bb2 = *(const half8*)&wpk_h[(32 + q) * 128 + ko];
        half8 bb3 = *(const half8*)&wpk_h[(48 + q) * 128 + ko];
        c0 = __builtin_amdgcn_mfma_f32_16x16x32_f16(a, bb0, c0, 0, 0, 0);
        c1 = __builtin_amdgcn_mfma_f32_16x16x32_f16(a, bb1, c1, 0, 0, 0);
        c2 = __builtin_amdgcn_mfma_f32_16x16x32_f16(a, bb2, c2, 0, 0, 0);
        c3 = __builtin_amdgcn_mfma_f32_16x16x32_f16(a, bb3, c3, 0, 0, 0);
    }

    float ss[4];
    #pragma unroll
    for (int r = 0; r < 4; r++) {
        c0[r] = (c0[r] > 0.f) ? c0[r] : 0.01f * c0[r];
        c1[r] = (c1[r] > 0.f) ? c1[r] : 0.01f * c1[r];
        c2[r] = (c2[r] > 0.f) ? c2[r] : 0.01f * c2[r];
        c3[r] = (c3[r] > 0.f) ? c3[r] : 0.01f * c3[r];
        ss[r] = c0[r]*c0[r] + c1[r]*c1[r] + c2[r]*c2[r] + c3[r]*c3[r];
        #pragma unroll
        for (int mm = 1; mm < 16; mm <<= 1) ss[r] += __shfl_xor(ss[r], mm);
        ss[r] = 1.f / fmaxf(sqrtf(ss[r]), 1e-12f);
    }
    #pragma unroll
    for (int r = 0; r < 4; r++) {
        int node_r = nb0 + wv * 16 + g * 4 + r;
        if (node_r >= n_nodes) continue;
        size_t row = (size_t)node_r * 64;
        h1out[row +      q] = (_Float16)(c0[r] * ss[r]);
        h1out[row + 16 + q] = (_Float16)(c1[r] * ss[r]);
        h1out[row + 32 + q] = (_Float16)(c2[r] * ss[r]);
        h1out[row + 48 + q] = (_Float16)(c3[r] * ss[r]);
    }
}

// ---------- layer2 for THREE nodes jointly (u,p,n): 3-stream gather MLP +
// half-split k-range matmul (lo lanes k<32, hi lanes k>=32, xor-combine) ----------
__device__ __forceinline__ void layer2_rows3(
    const _Float16* __restrict__ h1,
    const int* __restrict__ row_ptr, const unsigned int* __restrict__ edges,
    const float* sW1, const float* sW2, const float* sb,
    int n0, int n1, int n2, int lane,
    float& r0, float& r1, float& r2)
{
    int es0 = row_ptr[n0], ee0 = row_ptr[n0 + 1];
    int es1 = row_ptr[n1], ee1 = row_ptr[n1 + 1];
    int es2 = row_ptr[n2], ee2 = row_ptr[n2 + 1];
    float g0 = 0.f, g1 = 0.f, g2 = 0.f;
    int b0 = es0, b1 = es1, b2 = es2;
    while (b0 < ee0 || b1 < ee1 || b2 < ee2) {
        int c0 = ee0 - b0; c0 = c0 < 0 ? 0 : (c0 > 64 ? 64 : c0);
        int c1 = ee1 - b1; c1 = c1 < 0 ? 0 : (c1 > 64 ? 64 : c1);
        int c2 = ee2 - b2; c2 = c2 < 0 ? 0 : (c2 > 64 ? 64 : c2);
        unsigned ev0 = (lane < c0) ? edges[b0 + lane] : 0u;
        unsigned ev1 = (lane < c1) ? edges[b1 + lane] : 0u;
        unsigned ev2 = (lane < c2) ? edges[b2 + lane] : 0u;
        int jm = max(c0, max(c1, c2));
        for (int j = 0; j < jm; j++) {
            // exhausted streams broadcast 0 -> val 0 -> no-op
            unsigned e0 = (unsigned)__shfl((int)ev0, j);
            unsigned e1 = (unsigned)__shfl((int)ev1, j);
            unsigned e2 = (unsigned)__shfl((int)ev2, j);
            float f0 = (float)h1[(size_t)(e0 >> 14) * 64 + lane];
            float f1 = (float)h1[(size_t)(e1 >> 14) * 64 + lane];
            float f2 = (float)h1[(size_t)(e2 >> 14) * 64 + lane];
            g0 += val_f32(e0) * f0;
            g1 += val_f32(e1) * f1;
            g2 += val_f32(e2) * f2;
        }
        b0 += 64; b1 += 64; b2 += 64;
    }
    float fA = (float)h1[(size_t)n0 * 64 + lane];
    float fB = (float)h1[(size_t)n1 * 64 + lane];
    float fC = (float)h1[(size_t)n2 * 64 + lane];
    float sA = fA + g0, pA = fA * g0;
    float sB = fB + g1, pB = fB * g1;
    float sC = fC + g2, pC = fC * g2;
    int j  = lane & 31;
    int kb = (lane >> 5) << 5;              // 0 for lo half, 32 for hi half
    float aA = 0.f, aB = 0.f, aC = 0.f;
    #pragma unroll
    for (int k = 0; k < 32; k++) {
        int kk = kb + k;
        float w1v = sW1[kk * 32 + j];
        float w2v = sW2[kk * 32 + j];
        aA += __shfl(sA, kk) * w1v + __shfl(pA, kk) * w2v;
        aB += __shfl(sB, kk) * w1v + __shfl(pB, kk) * w2v;
        aC += __shfl(sC, kk) * w1v + __shfl(pC, kk) * w2v;
    }
    aA += __shfl_xor(aA, 32);
    aB += __shfl_xor(aB, 32);
    aC += __shfl_xor(aC, 32);
    float bj = sb[j];
    aA += bj; aB += bj; aC += bj;
    aA = (aA > 0.f) ? aA : 0.01f * aA;
    aB = (aB > 0.f) ? aB : 0.01f * aB;
    aC = (aC > 0.f) ? aC : 0.01f * aC;
    float qA = aA * aA, qB = aB * aB, qC = aC * aC;
    #pragma unroll
    for (int m = 1; m < 32; m <<= 1) {
        qA += __shfl_xor(qA, m);
        qB += __shfl_xor(qB, m);
        qC += __shfl_xor(qC, m);
    }
    r0 = aA / fmaxf(sqrtf(qA), 1e-12f);
    r1 = aB / fmaxf(sqrtf(qB), 1e-12f);
    r2 = aC / fmaxf(sqrtf(qC), 1e-12f);
}

__global__ __launch_bounds__(256) void score_k(
    const float* __restrict__ uw, const float* __restrict__ ew,
    const _Float16* __restrict__ h1,
    const int* __restrict__ row_ptr, const unsigned int* __restrict__ edges,
    const float* __restrict__ W1b, const float* __restrict__ b1b,
    const float* __restrict__ W2b, const float* __restrict__ b2b,
    const int* __restrict__ uid, const int* __restrict__ pid,
    const int* __restrict__ nid, float* __restrict__ out)
{
    __shared__ float sW1[64 * 32];
    __shared__ float sW2[64 * 32];
    __shared__ float sb[32];
    for (int i = threadIdx.x; i < 64 * 32; i += 256) { sW1[i] = W1b[i]; sW2[i] = W2b[i]; }
    if (threadIdx.x < 32) sb[threadIdx.x] = b1b[threadIdx.x] + b2b[threadIdx.x];
    __syncthreads();

    int wave = threadIdx.x >> 6;
    int lane = threadIdx.x & 63;
    int i = blockIdx.x * 4 + wave;
    if (i >= BATCH_C) return;

    int un = uid[i];
    int pe = pid[i];
    int ne = nid[i];
    int pn = N_USERS + pe;
    int nn = N_USERS + ne;

    float acc01p, acc01n;
    {
        float u  = uw[(size_t)un * 64 + lane];
        float pv = ew[(size_t)pe * 64 + lane];
        float nv = ew[(size_t)ne * 64 + lane];
        acc01p = u * pv;
        acc01n = u * nv;
        float u1 = (float)h1[(size_t)un * 64 + lane];
        acc01p += u1 * (float)h1[(size_t)pn * 64 + lane];
        acc01n += u1 * (float)h1[(size_t)nn * 64 + lane];
    }

    float h2u, h2p, h2n;
    layer2_rows3(h1, row_ptr, edges, sW1, sW2, sb, un, pn, nn, lane, h2u, h2p, h2n);
    float p2 = h2u * h2p;
    float n2 = h2u * h2n;
    #pragma unroll
    for (int m = 1; m < 32; m <<= 1) { p2 += __shfl_xor(p2, m); n2 += __shfl_xor(n2, m); }

    #pragma unroll
    for (int m = 1; m < 64; m <<= 1) { acc01p += __shfl_xor(acc01p, m); acc01n += __shfl_xor(acc01n, m); }

    if (lane == 0) {
        out[i]           = acc01p + p2;
        out[BATCH_C + i] = acc01n + n2;
    }
}

extern "C" void kernel_launch(void* const* d_in, const int* in_sizes, int n_in,
                              void* d_out, int out_size, void* d_ws, size_t ws_size,
                              hipStream_t stream) {
    const float* uw   = (const float*)d_in[0];
    const float* ew   = (const float*)d_in[1];
    const float* W1a  = (const float*)d_in[2];
    const float* b1a  = (const float*)d_in[3];
    const float* W2a  = (const float*)d_in[4];
    const float* b2a  = (const float*)d_in[5];
    const float* W1b  = (const float*)d_in[6];
    const float* b1b  = (const float*)d_in[7];
    const float* W2b  = (const float*)d_in[8];
    const float* b2b  = (const float*)d_in[9];
    const float* values   = (const float*)d_in[10];
    const int*   target   = (const int*)d_in[11];
    const int*   neighbor = (const int*)d_in[12];
    const int*   uid  = (const int*)d_in[13];
    const int*   pid  = (const int*)d_in[14];
    const int*   nid  = (const int*)d_in[15];

    const int n_edges = in_sizes[10];

    char* ws = (char*)d_ws;
    int*  row_ptr    = (int*)ws;   ws += 801792;
    int*  cntarr     = (int*)ws;   ws += 704512;          // 448*391*4 = 700672
    int*  sgtot      = (int*)ws;   ws += 4096;
    int*  sgcur      = (int*)ws;   ws += 4096;            // adjacent: one memset
    unsigned* wpk    = (unsigned*)ws; ws += 16384;        // packed W1||W2 f16 [64][128]
    unsigned int*   edges = (unsigned int*)ws;   ws += (size_t)N_EDGES_C * 4;      // 12.8 MB
    unsigned short* fb    = (unsigned short*)ws; ws += (size_t)N_NODES_C * 64 * 2; // 25.6 MB
    uint2*          tmp2  = (uint2*)ws;                   // aliased with h1
    _Float16*       h1    = (_Float16*)ws;                // region 25.69 MB

    const int layer_blocks = (N_NODES_C + 127) / 128;     // 1563
    const int nchunks      = (n_edges + CHUNK - 1) / CHUNK;   // 447

    // ----- zero sg totals + cursors (single async memset, adjacent buffers) -----
    hipMemsetAsync(sgtot, 0, 8192, stream);

    // ----- fused prep: sg-histogram ∥ f16 feature table ∥ weight pack -----
    prep_k<<<nchunks + CONVB + 1, 256, 0, stream>>>(uw, ew, fb, target,
                                                    cntarr, sgtot, W1a, W2a, wpk,
                                                    n_edges, nchunks);

    // ----- edge sort + CSR build (sg scan recomputed in-block; no scan_k bubble) -----
    scatter_k<<<nchunks, 256, 0, stream>>>(target, neighbor, values, cntarr,
                                           sgtot, sgcur, tmp2, n_edges);
    sort2_k<<<NSG, 512, 0, stream>>>(tmp2, sgtot, row_ptr, edges);

    // ----- layer 1 (quad-node pull + MFMA transform, f16; 4 blocks/CU) -----
    layer1_pull_k<<<layer_blocks, 512, 0, stream>>>(fb, row_ptr, edges,
                                                    wpk, b1a, b2a, h1, N_NODES_C);

    // ----- scoring (fused 3-row layer-2 + transform, ~12K nodes) -----
    score_k<<<BATCH_C / 4, 256, 0, stream>>>(uw, ew, h1, row_ptr, edges,
                                             W1b, b1b, W2b, b2b,
                                             uid, pid, nid, (float*)d_out);
}